// Round 1
// baseline (181.458 us; speedup 1.0000x reference)
//
#include <hip/hip_runtime.h>
#include <hip/hip_bf16.h>

#define S_LEN 2048
#define D_DIM 1024
#define NH    16
#define NEG_BIG (-1.0e30f)

// epilogue modes for gemm_bt
#define EPI_NORMROPE   1   // RMSNorm + RoPE, store bf16 row-major (K)
#define EPI_VMIX_T     2   // v-mix with v1, store bf16 TRANSPOSED (V -> Vt_g[d][s])
#define EPI_F32        3   // plain f32 row-major store (out-proj)
#define EPI_NORMROPE_Q 4   // like NORMROPE but pre-scaled by 0.125*log2e (Q)

typedef __attribute__((ext_vector_type(8))) short bf16x8;
typedef __attribute__((ext_vector_type(4))) float f32x4;
typedef const __attribute__((address_space(1))) unsigned char gu8_t;
typedef __attribute__((address_space(3))) unsigned char lu8_t;

__device__ __forceinline__ float bf2f(unsigned short h) {
    union { unsigned int u; float f; } v; v.u = ((unsigned int)h) << 16; return v.f;
}
__device__ __forceinline__ unsigned short f2b(float f) {   // RNE f32->bf16 raw bits
    union { float f; unsigned int u; } v; v.f = f;
    unsigned int u = v.u;
    return (unsigned short)((u + 0x7FFFu + ((u >> 16) & 1u)) >> 16);
}
__device__ __forceinline__ unsigned short f2b_trunc(float f) {  // trunc (p>=0 only)
    union { float f; unsigned int u; } v; v.f = f;
    return (unsigned short)(v.u >> 16);
}

// one-shot f32 -> bf16 conversion of x + 4 weights (externals measured f32, r4-r10).
__global__ __launch_bounds__(256)
void to_bf16(const float* __restrict__ x,  const float* __restrict__ wq,
             const float* __restrict__ wk, const float* __restrict__ wv,
             const float* __restrict__ wo,
             unsigned short* __restrict__ xb,  unsigned short* __restrict__ wqb,
             unsigned short* __restrict__ wkb, unsigned short* __restrict__ wvb,
             unsigned short* __restrict__ wob)
{
    const int z = blockIdx.y;
    const float* s; unsigned short* d; int n;
    switch (z) {
        case 0: s = x;  d = xb;  n = S_LEN * D_DIM; break;
        case 1: s = wq; d = wqb; n = D_DIM * D_DIM; break;
        case 2: s = wk; d = wkb; n = D_DIM * D_DIM; break;
        case 3: s = wv; d = wvb; n = D_DIM * D_DIM; break;
        default: s = wo; d = wob; n = D_DIM * D_DIM; break;
    }
    int i8 = blockIdx.x * 256 + threadIdx.x;
    if (i8 * 8 >= n) return;
    const float* sp = s + (size_t)i8 * 8;
    float4 lo = *(const float4*)sp, hi = *(const float4*)(sp + 4);
    uint4 p;
    p.x = f2b(lo.x) | ((unsigned)f2b(lo.y) << 16);
    p.y = f2b(lo.z) | ((unsigned)f2b(lo.w) << 16);
    p.z = f2b(hi.x) | ((unsigned)f2b(hi.y) << 16);
    p.w = f2b(hi.z) | ((unsigned)f2b(hi.w) << 16);
    *(uint4*)(d + (size_t)i8 * 8) = p;
}

// C = A[M,K] * B[N,K]^T, bf16 inputs, global_load_lds(16B) staging into
// unpadded [128][32] LDS (m97 contract). Epilogue per 'epi' (wave-uniform).
__global__ __launch_bounds__(256, 3)
void gemm_bt(const unsigned short* __restrict__ A,
             const unsigned short* __restrict__ B0, const unsigned short* __restrict__ B1,
             const unsigned short* __restrict__ B2,
             void* __restrict__ C0, void* __restrict__ C1, void* __restrict__ C2,
             const float* __restrict__ vmix, const float* __restrict__ lam,
             int epiPack)
{
    const int which = blockIdx.z;
    const unsigned short* Bp = (which == 0) ? B0 : ((which == 1) ? B1 : B2);
    void* C = (which == 0) ? C0 : ((which == 1) ? C1 : C2);
    const int epi = (epiPack >> (8 * which)) & 0xff;
    const int tn = blockIdx.x * 128;
    const int tm = blockIdx.y * 128;

    __shared__ unsigned short Asl[128 * 32];   // unpadded: global_load_lds contract
    __shared__ unsigned short Bsl[128 * 32];

    const int t    = threadIdx.x;
    const int lane = t & 63;
    const int wave = t >> 6;
    const int wm   = (wave >> 1) * 64;
    const int wn   = (wave & 1) * 64;
    const int lrow = lane & 15;
    const int quad = lane >> 4;
    const int srow = lane >> 2;
    const int scol = (lane & 3) * 8;

    f32x4 acc[4][4];
    #pragma unroll
    for (int i = 0; i < 4; ++i)
        #pragma unroll
        for (int j = 0; j < 4; ++j) {
            f32x4 z = {0.f, 0.f, 0.f, 0.f};
            acc[i][j] = z;
        }

    for (int k0 = 0; k0 < D_DIM; k0 += 32) {
        #pragma unroll
        for (int rep = 0; rep < 2; ++rep) {
            int grp = wave * 2 + rep;               // 0..7 (16 rows each)
            int row = grp * 16 + srow;
            __builtin_amdgcn_global_load_lds(
                (gu8_t*)(A + (size_t)(tm + row) * D_DIM + k0 + scol),
                (lu8_t*)&Asl[grp * 512], 16, 0, 0);
            __builtin_amdgcn_global_load_lds(
                (gu8_t*)(Bp + (size_t)(tn + row) * D_DIM + k0 + scol),
                (lu8_t*)&Bsl[grp * 512], 16, 0, 0);
        }
        __syncthreads();
        bf16x8 af[4], bfr[4];
        #pragma unroll
        for (int i = 0; i < 4; ++i)
            af[i] = *(const bf16x8*)(&Asl[(wm + i * 16 + lrow) * 32 + quad * 8]);
        #pragma unroll
        for (int j = 0; j < 4; ++j)
            bfr[j] = *(const bf16x8*)(&Bsl[(wn + j * 16 + lrow) * 32 + quad * 8]);
        #pragma unroll
        for (int i = 0; i < 4; ++i)
            #pragma unroll
            for (int j = 0; j < 4; ++j)
                acc[i][j] = __builtin_amdgcn_mfma_f32_16x16x32_bf16(af[i], bfr[j], acc[i][j], 0, 0, 0);
        __syncthreads();
    }

    if (epi == EPI_NORMROPE || epi == EPI_NORMROPE_Q) {
        // wave covers cols [tn+wn, tn+wn+64) = one head. RoPE pair (i, i+32) = (j, j+2).
        // Q variant folds 0.125*log2e into rms: rope is linear, scale commutes;
        // attention scores then land directly in the log2 domain (see attn_mfma).
        const float post = (epi == EPI_NORMROPE_Q) ? 0.18033688011112042f : 1.0f;
        #pragma unroll
        for (int i = 0; i < 4; ++i) {
            #pragma unroll
            for (int r = 0; r < 4; ++r) {
                int row = tm + wm + i * 16 + quad * 4 + r;   // seq position (m89/m91 C-map)
                float v0 = acc[i][0][r], v1 = acc[i][1][r];
                float v2 = acc[i][2][r], v3 = acc[i][3][r];
                float ss = v0 * v0 + v1 * v1 + v2 * v2 + v3 * v3;
                ss += __shfl_xor(ss, 1); ss += __shfl_xor(ss, 2);
                ss += __shfl_xor(ss, 4); ss += __shfl_xor(ss, 8);   // 16-lane group = full head
                float rms = rsqrtf(ss * (1.f / 64.f) + 1.1920929e-7f) * post;
                v0 *= rms; v1 *= rms; v2 *= rms; v3 *= rms;
                float fs = (float)row;
                float a0 = fs * exp2f(-0.41524101186092030f * (float)lrow);        // 10000^(-2i/64)
                float a1 = fs * exp2f(-0.41524101186092030f * (float)(16 + lrow));
                float s0, c0, s1, c1;
                __sincosf(a0, &s0, &c0);
                __sincosf(a1, &s1, &c1);
                unsigned short* Cb = (unsigned short*)C;
                size_t base = (size_t)row * D_DIM + tn + wn + lrow;
                Cb[base]      = f2b(v0 * c0 + v2 * s0);
                Cb[base + 16] = f2b(v1 * c1 + v3 * s1);
                Cb[base + 32] = f2b(-v0 * s0 + v2 * c0);
                Cb[base + 48] = f2b(-v1 * s1 + v3 * c1);
            }
        }
    } else if (epi == EPI_VMIX_T) {
        float lamf = *lam;
        #pragma unroll
        for (int i = 0; i < 4; ++i) {
            int cm0 = tm + wm + i * 16 + quad * 4;
            #pragma unroll
            for (int j = 0; j < 4; ++j) {
                int cn = tn + wn + j * 16 + lrow;
                ushort4 pk;
                float vals[4];
                #pragma unroll
                for (int r = 0; r < 4; ++r) {
                    size_t idx = (size_t)(cm0 + r) * D_DIM + cn;
                    vals[r] = (1.f - lamf) * acc[i][j][r] + lamf * vmix[idx];
                }
                pk.x = f2b(vals[0]); pk.y = f2b(vals[1]);
                pk.z = f2b(vals[2]); pk.w = f2b(vals[3]);
                *(ushort4*)((unsigned short*)C + (size_t)cn * S_LEN + cm0) = pk;
            }
        }
    } else {   // EPI_F32
        #pragma unroll
        for (int i = 0; i < 4; ++i) {
            int cm0 = tm + wm + i * 16 + quad * 4;
            #pragma unroll
            for (int j = 0; j < 4; ++j) {
                int cn = tn + wn + j * 16 + lrow;
                #pragma unroll
                for (int r = 0; r < 4; ++r)
                    ((float*)C)[(size_t)(cm0 + r) * D_DIM + cn] = acc[i][j][r];
            }
        }
    }
}

// MFMA flash attention, KEY-SPLIT version.
// Static-max softmax in the log2 domain (Q pre-scaled by 0.125*log2e) makes
// partials over key chunks PURELY ADDITIVE: no running max, no rescale.
// Each block = (qt, chunk, head): processes key tiles [c*cs, min((c+1)*cs, qt+1))
// with cs = ceil((qt+1)/4), so max 8 iterations/block (was 32 -> critical-path
// balance fix: old grid was fully resident and bounded by the qt=31 block).
// Writes unnormalized f32 O-partials + per-row l-partials; attn_combine sums.
__global__ __launch_bounds__(256, 3)
void attn_mfma(const unsigned short* Qb,
               const unsigned short* __restrict__ Kb,
               const unsigned short* __restrict__ Vtg,
               float* __restrict__ Opart, float* __restrict__ Lpart)
{
    const int bx = blockIdx.x;            // 0..127
    const int qt = 31 - (bx >> 2);        // big tiles dispatch first
    const int c  = bx & 3;
    const int cs = (qt + 4) >> 2;         // ceil((qt+1)/4)
    const int jlo = c * cs;
    if (jlo > qt) return;                 // empty chunk
    const int jhi = min(jlo + cs - 1, qt);
    const int h  = blockIdx.y;
    const int t  = threadIdx.x;
    const int w  = t >> 6;
    const int l  = t & 63;
    const int l15  = l & 15;
    const int quad = l >> 4;
    const int hco  = h * 64;
    const int slot = (qt * 4 + c) * NH + h;

    __shared__ unsigned short Ks[2][64][72];    // double-buffered
    __shared__ unsigned short Vt[2][64][72];    // Vt[buf][d][key]
    __shared__ unsigned short Ps[4][16][72];    // per-wave P tile (wave-private)

    const unsigned short* qrow = Qb + (size_t)(qt * 64 + w * 16 + l15) * D_DIM + hco;
    bf16x8 qf0 = *(const bf16x8*)(qrow + quad * 8);
    bf16x8 qf1 = *(const bf16x8*)(qrow + 32 + quad * 8);

    f32x4 oac[4];
    #pragma unroll
    for (int nt = 0; nt < 4; ++nt) { f32x4 z = {0.f,0.f,0.f,0.f}; oac[nt] = z; }
    float l_lane[4] = {0.f, 0.f, 0.f, 0.f};

    const int rr = t >> 2;          // staging row (K: key row; Vt: d row)
    const int dc = (t & 3) * 16;    // 16-col group

    const unsigned short* kbase = Kb  + (size_t)rr * D_DIM + hco + dc;
    const unsigned short* vbase = Vtg + (size_t)(hco + rr) * S_LEN + dc;

    uint4 ka0, ka1, va0, va1;
    {
        const unsigned short* kp = kbase + (size_t)jlo * 64 * D_DIM;
        const unsigned short* vp = vbase + (size_t)jlo * 64;
        ka0 = *(const uint4*)kp;  ka1 = *(const uint4*)(kp + 8);
        va0 = *(const uint4*)vp;  va1 = *(const uint4*)(vp + 8);
    }

    const int row_base = qt * 64 + w * 16 + quad * 4;   // C-layout row = quad*4 + reg
    const float C2 = -11.541560327111707f;              // -8 * log2(e)

    for (int j = jlo; j <= jhi; ++j) {
        const int buf = (j - jlo) & 1;
        // write this tile's LDS from prefetched regs (vmcnt wait auto-inserted)
        *(uint4*)&Ks[buf][rr][dc]     = ka0;
        *(uint4*)&Ks[buf][rr][dc + 8] = ka1;
        *(uint4*)&Vt[buf][rr][dc]     = va0;
        *(uint4*)&Vt[buf][rr][dc + 8] = va1;
        __syncthreads();                       // ONE barrier per iteration
        if (j < jhi) {                         // prefetch next tile into regs
            const unsigned short* kp = kbase + (size_t)(j + 1) * 64 * D_DIM;
            const unsigned short* vp = vbase + (size_t)(j + 1) * 64;
            ka0 = *(const uint4*)kp;  ka1 = *(const uint4*)(kp + 8);
            va0 = *(const uint4*)vp;  va1 = *(const uint4*)(vp + 8);
        }

        // S = Q K^T (16 rows x 64 keys) — already in log2 domain (Q pre-scaled)
        f32x4 sac[4];
        #pragma unroll
        for (int nt = 0; nt < 4; ++nt) {
            f32x4 z = {0.f,0.f,0.f,0.f};
            bf16x8 kf0 = *(const bf16x8*)&Ks[buf][nt * 16 + l15][quad * 8];
            z = __builtin_amdgcn_mfma_f32_16x16x32_bf16(qf0, kf0, z, 0, 0, 0);
            bf16x8 kf1 = *(const bf16x8*)&Ks[buf][nt * 16 + l15][32 + quad * 8];
            z = __builtin_amdgcn_mfma_f32_16x16x32_bf16(qf1, kf1, z, 0, 0, 0);
            sac[nt] = z;
        }

        if (j < qt) {
            // bulk: no masking needed
            #pragma unroll
            for (int nt = 0; nt < 4; ++nt) {
                #pragma unroll
                for (int r = 0; r < 4; ++r) {
                    float pe = exp2f(sac[nt][r] + C2);
                    l_lane[r] += pe;
                    Ps[w][quad * 4 + r][nt * 16 + l15] = f2b_trunc(pe);
                }
            }
        } else {
            // diagonal tile: causal mask (only reachable in the last chunk)
            #pragma unroll
            for (int nt = 0; nt < 4; ++nt) {
                int key_g = j * 64 + nt * 16 + l15;
                #pragma unroll
                for (int r = 0; r < 4; ++r) {
                    float s = sac[nt][r] + C2;
                    if (key_g > row_base + r) s = NEG_BIG;
                    float pe = exp2f(s);
                    l_lane[r] += pe;
                    Ps[w][quad * 4 + r][nt * 16 + l15] = f2b_trunc(pe);
                }
            }
        }

        // P: C-layout -> A-layout via per-wave LDS, then PV
        bf16x8 pf0 = *(const bf16x8*)&Ps[w][l15][quad * 8];
        bf16x8 pf1 = *(const bf16x8*)&Ps[w][l15][32 + quad * 8];
        #pragma unroll
        for (int nt = 0; nt < 4; ++nt) {
            bf16x8 vf0 = *(const bf16x8*)&Vt[buf][nt * 16 + l15][quad * 8];
            oac[nt] = __builtin_amdgcn_mfma_f32_16x16x32_bf16(pf0, vf0, oac[nt], 0, 0, 0);
            bf16x8 vf1 = *(const bf16x8*)&Vt[buf][nt * 16 + l15][32 + quad * 8];
            oac[nt] = __builtin_amdgcn_mfma_f32_16x16x32_bf16(pf1, vf1, oac[nt], 0, 0, 0);
        }
    }

    // write partials: per-row l (reduced over 16-lane group) + unnormalized O
    float* Op = Opart + (size_t)slot * 4096;
    #pragma unroll
    for (int r = 0; r < 4; ++r) {
        float lr = l_lane[r];
        #pragma unroll
        for (int d = 1; d < 16; d <<= 1) lr += __shfl_xor(lr, d);
        if (l15 == 0) Lpart[(size_t)slot * 64 + w * 16 + quad * 4 + r] = lr;
    }
    #pragma unroll
    for (int nt = 0; nt < 4; ++nt)
        #pragma unroll
        for (int r = 0; r < 4; ++r)
            Op[(size_t)(w * 16 + quad * 4 + r) * 64 + nt * 16 + l15] = oac[nt][r];
}

// sum <=4 key-chunk partials, normalize, cast to bf16.
// grid (32 qt, 16 h), 256 threads: thread = (row 0..63, 16-col group).
__global__ __launch_bounds__(256)
void attn_combine(const float* __restrict__ Opart, const float* __restrict__ Lpart,
                  unsigned short* __restrict__ Ob)
{
    const int qt  = blockIdx.x;
    const int h   = blockIdx.y;
    const int t   = threadIdx.x;
    const int row = t >> 2;
    const int c0  = (t & 3) * 16;
    const int cs  = (qt + 4) >> 2;
    float acc[16];
    #pragma unroll
    for (int i = 0; i < 16; ++i) acc[i] = 0.f;
    float lsum = 0.f;
    for (int c = 0; c < 4; ++c) {
        if (c * cs > qt) break;                       // no more nonempty chunks
        const size_t slot = (size_t)((qt * 4 + c) * NH + h);
        const float* Op = Opart + slot * 4096 + (size_t)row * 64 + c0;
        #pragma unroll
        for (int g = 0; g < 4; ++g) {
            float4 a = *(const float4*)(Op + g * 4);
            acc[g * 4 + 0] += a.x; acc[g * 4 + 1] += a.y;
            acc[g * 4 + 2] += a.z; acc[g * 4 + 3] += a.w;
        }
        lsum += Lpart[slot * 64 + row];
    }
    const float inv = 1.f / lsum;   // > 0: diagonal key always contributes
    unsigned int pk[8];
    #pragma unroll
    for (int i = 0; i < 8; ++i)
        pk[i] = f2b(acc[2 * i] * inv) | ((unsigned)f2b(acc[2 * i + 1] * inv) << 16);
    unsigned short* dst = Ob + (size_t)(qt * 64 + row) * D_DIM + h * 64 + c0;
    *(uint4*)dst       = make_uint4(pk[0], pk[1], pk[2], pk[3]);
    *(uint4*)(dst + 8) = make_uint4(pk[4], pk[5], pk[6], pk[7]);
}

// v1 passthrough (f32), 16B chunks.
__global__ __launch_bounds__(256)
void copy_v1(const uint4* __restrict__ src, uint4* __restrict__ dst) {
    int i = blockIdx.x * 256 + threadIdx.x;
    dst[i] = src[i];
}

extern "C" void kernel_launch(void* const* d_in, const int* in_sizes, int n_in,
                              void* d_out, int out_size, void* d_ws, size_t ws_size,
                              hipStream_t stream)
{
    const float* x    = (const float*)d_in[0];
    const float* v1   = (const float*)d_in[1];
    const float* Wq   = (const float*)d_in[2];
    const float* Wk   = (const float*)d_in[3];
    const float* Wv   = (const float*)d_in[4];
    const float* Wout = (const float*)d_in[5];
    const float* lam  = (const float*)d_in[6];
    float* out = (float*)d_out;

    const size_t SD = (size_t)S_LEN * D_DIM;
    const size_t DD = (size_t)D_DIM * D_DIM;
    unsigned short* Qb  = (unsigned short*)d_ws;         // internal bf16, 4 MB
    unsigned short* Kb  = Qb + SD;                       // 4 MB
    unsigned short* Vtg = Kb + SD;                       // V transposed [D_DIM][S_LEN], 4 MB
    unsigned short* Ab  = Qb;                            // alias (attn output after combine)
    float* Opart = (float*)(Vtg + SD);                   // 2048 slots * 16 KB = 32 MB
    float* Lpart = Opart + (size_t)2048 * 4096;          // 512 KB

    // bf16 scratch in d_out (16 MB f32): y slot holds Wq/Wk/Wv copies (6 MB,
    // overwritten by out-proj), v1 slot holds xb+Woutb (6 MB, overwritten by copy_v1).
    unsigned short* Wqb   = (unsigned short*)d_out;            // 2 MB
    unsigned short* Wkb   = Wqb + DD;                          // 2 MB
    unsigned short* Wvb   = Wkb + DD;                          // 2 MB
    unsigned short* xb    = (unsigned short*)(out + SD);       // 4 MB
    unsigned short* Woutb = xb + SD;                           // 2 MB

    to_bf16<<<dim3(1024, 5), 256, 0, stream>>>(
        x, Wq, Wk, Wv, Wout, xb, Wqb, Wkb, Wvb, Woutb);

    // Q/K/V projections; Q gets pre-scaled RMSNorm+RoPE, K plain, V v-mix + transpose.
    gemm_bt<<<dim3(D_DIM / 128, S_LEN / 128, 3), 256, 0, stream>>>(
        xb, Wqb, Wkb, Wvb, Qb, Kb, Vtg, v1, lam,
        EPI_NORMROPE_Q | (EPI_NORMROPE << 8) | (EPI_VMIX_T << 16));

    // key-split flash attention: 4 chunks per (qt, h), partials + combine
    attn_mfma<<<dim3(128, NH), 256, 0, stream>>>(Qb, Kb, Vtg, Opart, Lpart);
    attn_combine<<<dim3(S_LEN / 64, NH), 256, 0, stream>>>(Opart, Lpart, Ab);

    // output projection -> y slot, f32
    gemm_bt<<<dim3(D_DIM / 128, S_LEN / 128, 1), 256, 0, stream>>>(
        Ab, Woutb, Woutb, Woutb, d_out, d_out, d_out, nullptr, lam, EPI_F32);

    copy_v1<<<dim3((unsigned)(SD / 4 / 256)), 256, 0, stream>>>(
        (const uint4*)v1, (uint4*)(out + SD));
}

// Round 2
// 178.911 us; speedup vs baseline: 1.0142x; 1.0142x over previous
//
#include <hip/hip_runtime.h>
#include <hip/hip_bf16.h>

#define S_LEN 2048
#define D_DIM 1024
#define NH    16
#define NEG_BIG (-1.0e30f)

// epilogue modes for gemm_bt
#define EPI_NORMROPE   1   // RMSNorm + RoPE, store bf16 row-major (K)
#define EPI_VMIX_T     2   // v-mix with v1, store bf16 TRANSPOSED (V -> Vt_g[d][s])
#define EPI_F32        3   // plain f32 row-major store (out-proj)
#define EPI_NORMROPE_Q 4   // like NORMROPE but pre-scaled by 0.125*log2e (Q)
#define EPI_F32A       5   // f32 atomicAdd (split-K out-proj; y pre-zeroed)

typedef __attribute__((ext_vector_type(8))) short bf16x8;
typedef __attribute__((ext_vector_type(4))) float f32x4;
typedef const __attribute__((address_space(1))) unsigned char gu8_t;
typedef __attribute__((address_space(3))) unsigned char lu8_t;

__device__ __forceinline__ float bf2f(unsigned short h) {
    union { unsigned int u; float f; } v; v.u = ((unsigned int)h) << 16; return v.f;
}
__device__ __forceinline__ unsigned short f2b(float f) {   // RNE f32->bf16 raw bits
    union { float f; unsigned int u; } v; v.f = f;
    unsigned int u = v.u;
    return (unsigned short)((u + 0x7FFFu + ((u >> 16) & 1u)) >> 16);
}
__device__ __forceinline__ unsigned short f2b_trunc(float f) {  // trunc (p>=0 only)
    union { float f; unsigned int u; } v; v.f = f;
    return (unsigned short)(v.u >> 16);
}

// one-shot f32 -> bf16 conversion of x + 4 weights (externals measured f32, r4-r10).
__global__ __launch_bounds__(256)
void to_bf16(const float* __restrict__ x,  const float* __restrict__ wq,
             const float* __restrict__ wk, const float* __restrict__ wv,
             const float* __restrict__ wo,
             unsigned short* __restrict__ xb,  unsigned short* __restrict__ wqb,
             unsigned short* __restrict__ wkb, unsigned short* __restrict__ wvb,
             unsigned short* __restrict__ wob)
{
    const int z = blockIdx.y;
    const float* s; unsigned short* d; int n;
    switch (z) {
        case 0: s = x;  d = xb;  n = S_LEN * D_DIM; break;
        case 1: s = wq; d = wqb; n = D_DIM * D_DIM; break;
        case 2: s = wk; d = wkb; n = D_DIM * D_DIM; break;
        case 3: s = wv; d = wvb; n = D_DIM * D_DIM; break;
        default: s = wo; d = wob; n = D_DIM * D_DIM; break;
    }
    int i8 = blockIdx.x * 256 + threadIdx.x;
    if (i8 * 8 >= n) return;
    const float* sp = s + (size_t)i8 * 8;
    float4 lo = *(const float4*)sp, hi = *(const float4*)(sp + 4);
    uint4 p;
    p.x = f2b(lo.x) | ((unsigned)f2b(lo.y) << 16);
    p.y = f2b(lo.z) | ((unsigned)f2b(lo.w) << 16);
    p.z = f2b(hi.x) | ((unsigned)f2b(hi.y) << 16);
    p.w = f2b(hi.z) | ((unsigned)f2b(hi.w) << 16);
    *(uint4*)(d + (size_t)i8 * 8) = p;
}

// C = A[M,K] * B[N,K]^T, bf16 inputs, global_load_lds(16B) staging into
// unpadded [128][32] LDS (m97 contract). Epilogue per 'epi' (wave-uniform).
// splitK: blockIdx.z selects a K-half instead of a (B,C,epi) triple; epilogue
// must then be EPI_F32A (atomicAdd into pre-zeroed C0).
__global__ __launch_bounds__(256, 3)
void gemm_bt(const unsigned short* __restrict__ A,
             const unsigned short* __restrict__ B0, const unsigned short* __restrict__ B1,
             const unsigned short* __restrict__ B2,
             void* __restrict__ C0, void* __restrict__ C1, void* __restrict__ C2,
             const float* __restrict__ vmix, const float* __restrict__ lam,
             int epiPack, int splitK)
{
    const int which = blockIdx.z;
    const unsigned short* Bp;
    void* C;
    int epi, kLo, kHi;
    if (splitK) {
        Bp = B0; C = C0; epi = epiPack & 0xff;
        kLo = which * (D_DIM / 2); kHi = kLo + D_DIM / 2;
    } else {
        Bp = (which == 0) ? B0 : ((which == 1) ? B1 : B2);
        C  = (which == 0) ? C0 : ((which == 1) ? C1 : C2);
        epi = (epiPack >> (8 * which)) & 0xff;
        kLo = 0; kHi = D_DIM;
    }
    const int tn = blockIdx.x * 128;
    const int tm = blockIdx.y * 128;

    __shared__ unsigned short Asl[128 * 32];   // unpadded: global_load_lds contract
    __shared__ unsigned short Bsl[128 * 32];

    const int t    = threadIdx.x;
    const int lane = t & 63;
    const int wave = t >> 6;
    const int wm   = (wave >> 1) * 64;
    const int wn   = (wave & 1) * 64;
    const int lrow = lane & 15;
    const int quad = lane >> 4;
    const int srow = lane >> 2;
    const int scol = (lane & 3) * 8;

    f32x4 acc[4][4];
    #pragma unroll
    for (int i = 0; i < 4; ++i)
        #pragma unroll
        for (int j = 0; j < 4; ++j) {
            f32x4 z = {0.f, 0.f, 0.f, 0.f};
            acc[i][j] = z;
        }

    for (int k0 = kLo; k0 < kHi; k0 += 32) {
        #pragma unroll
        for (int rep = 0; rep < 2; ++rep) {
            int grp = wave * 2 + rep;               // 0..7 (16 rows each)
            int row = grp * 16 + srow;
            __builtin_amdgcn_global_load_lds(
                (gu8_t*)(A + (size_t)(tm + row) * D_DIM + k0 + scol),
                (lu8_t*)&Asl[grp * 512], 16, 0, 0);
            __builtin_amdgcn_global_load_lds(
                (gu8_t*)(Bp + (size_t)(tn + row) * D_DIM + k0 + scol),
                (lu8_t*)&Bsl[grp * 512], 16, 0, 0);
        }
        __syncthreads();
        bf16x8 af[4], bfr[4];
        #pragma unroll
        for (int i = 0; i < 4; ++i)
            af[i] = *(const bf16x8*)(&Asl[(wm + i * 16 + lrow) * 32 + quad * 8]);
        #pragma unroll
        for (int j = 0; j < 4; ++j)
            bfr[j] = *(const bf16x8*)(&Bsl[(wn + j * 16 + lrow) * 32 + quad * 8]);
        #pragma unroll
        for (int i = 0; i < 4; ++i)
            #pragma unroll
            for (int j = 0; j < 4; ++j)
                acc[i][j] = __builtin_amdgcn_mfma_f32_16x16x32_bf16(af[i], bfr[j], acc[i][j], 0, 0, 0);
        __syncthreads();
    }

    if (epi == EPI_NORMROPE || epi == EPI_NORMROPE_Q) {
        // wave covers cols [tn+wn, tn+wn+64) = one head. RoPE pair (i, i+32) = (j, j+2).
        // Q variant folds 0.125*log2e into rms: rope is linear, scale commutes;
        // attention scores then land directly in the log2 domain (see attn_mfma).
        const float post = (epi == EPI_NORMROPE_Q) ? 0.18033688011112042f : 1.0f;
        #pragma unroll
        for (int i = 0; i < 4; ++i) {
            #pragma unroll
            for (int r = 0; r < 4; ++r) {
                int row = tm + wm + i * 16 + quad * 4 + r;   // seq position (m89/m91 C-map)
                float v0 = acc[i][0][r], v1 = acc[i][1][r];
                float v2 = acc[i][2][r], v3 = acc[i][3][r];
                float ss = v0 * v0 + v1 * v1 + v2 * v2 + v3 * v3;
                ss += __shfl_xor(ss, 1); ss += __shfl_xor(ss, 2);
                ss += __shfl_xor(ss, 4); ss += __shfl_xor(ss, 8);   // 16-lane group = full head
                float rms = rsqrtf(ss * (1.f / 64.f) + 1.1920929e-7f) * post;
                v0 *= rms; v1 *= rms; v2 *= rms; v3 *= rms;
                float fs = (float)row;
                float a0 = fs * exp2f(-0.41524101186092030f * (float)lrow);        // 10000^(-2i/64)
                float a1 = fs * exp2f(-0.41524101186092030f * (float)(16 + lrow));
                float s0, c0, s1, c1;
                __sincosf(a0, &s0, &c0);
                __sincosf(a1, &s1, &c1);
                unsigned short* Cb = (unsigned short*)C;
                size_t base = (size_t)row * D_DIM + tn + wn + lrow;
                Cb[base]      = f2b(v0 * c0 + v2 * s0);
                Cb[base + 16] = f2b(v1 * c1 + v3 * s1);
                Cb[base + 32] = f2b(-v0 * s0 + v2 * c0);
                Cb[base + 48] = f2b(-v1 * s1 + v3 * c1);
            }
        }
    } else if (epi == EPI_VMIX_T) {
        float lamf = *lam;
        #pragma unroll
        for (int i = 0; i < 4; ++i) {
            int cm0 = tm + wm + i * 16 + quad * 4;
            #pragma unroll
            for (int j = 0; j < 4; ++j) {
                int cn = tn + wn + j * 16 + lrow;
                ushort4 pk;
                float vals[4];
                #pragma unroll
                for (int r = 0; r < 4; ++r) {
                    size_t idx = (size_t)(cm0 + r) * D_DIM + cn;
                    vals[r] = (1.f - lamf) * acc[i][j][r] + lamf * vmix[idx];
                }
                pk.x = f2b(vals[0]); pk.y = f2b(vals[1]);
                pk.z = f2b(vals[2]); pk.w = f2b(vals[3]);
                *(ushort4*)((unsigned short*)C + (size_t)cn * S_LEN + cm0) = pk;
            }
        }
    } else if (epi == EPI_F32A) {
        #pragma unroll
        for (int i = 0; i < 4; ++i) {
            int cm0 = tm + wm + i * 16 + quad * 4;
            #pragma unroll
            for (int j = 0; j < 4; ++j) {
                int cn = tn + wn + j * 16 + lrow;
                #pragma unroll
                for (int r = 0; r < 4; ++r)
                    atomicAdd(&((float*)C)[(size_t)(cm0 + r) * D_DIM + cn], acc[i][j][r]);
            }
        }
    } else {   // EPI_F32
        #pragma unroll
        for (int i = 0; i < 4; ++i) {
            int cm0 = tm + wm + i * 16 + quad * 4;
            #pragma unroll
            for (int j = 0; j < 4; ++j) {
                int cn = tn + wn + j * 16 + lrow;
                #pragma unroll
                for (int r = 0; r < 4; ++r)
                    ((float*)C)[(size_t)(cm0 + r) * D_DIM + cn] = acc[i][j][r];
            }
        }
    }
}

// MFMA flash attention, key-split with SWAPPED-OPERAND QK^T.
// Computing mfma(K, Q) yields S^T with layout (q = lane&15, key = quad*4+reg):
// the 4 P-values per (lane, nt) are CONTIGUOUS keys -> one packed ds_write_b64
// (was 16 scalar b16 writes), and the l-sum is one scalar per lane.
// Static-max softmax in log2 domain (Q pre-scaled by 0.125*log2e) keeps
// key-chunk partials purely additive: no running max, no rescale.
// Chunks are FIXED 8 key-tiles: block = (qt, c, h), tiles [8c, min(8c+8, qt+1)).
// 1280 uniform blocks (<=8 iters each) at 3 blocks/CU -> balanced.
__global__ __launch_bounds__(256, 3)
void attn_mfma(const unsigned short* Qb,
               const unsigned short* __restrict__ Kb,
               const unsigned short* __restrict__ Vtg,
               float* __restrict__ Opart, float* __restrict__ Lpart)
{
    const int bx = blockIdx.x;            // 0..79, big qt first
    int qt, c;
    if (bx < 32)      { qt = 31 - (bx >> 2);            c = bx & 3;  }  // qt 31..24: 4 chunks
    else if (bx < 56) { int i = bx - 32; qt = 23 - i/3; c = i % 3;   }  // qt 23..16: 3 chunks
    else if (bx < 72) { int i = bx - 56; qt = 15 - (i>>1); c = i & 1;}  // qt 15..8 : 2 chunks
    else              { qt = 7 - (bx - 72);             c = 0;       }  // qt 7..0  : 1 chunk
    const int jlo = c * 8;
    const int jhi = min(jlo + 7, qt);
    const int h  = blockIdx.y;
    const int t  = threadIdx.x;
    const int w  = t >> 6;
    const int l  = t & 63;
    const int l15  = l & 15;
    const int quad = l >> 4;
    const int hco  = h * 64;
    const int slot = (qt * 4 + c) * NH + h;

    __shared__ unsigned short Ks[2][64][72];    // double-buffered
    __shared__ unsigned short Vt[2][64][72];    // Vt[buf][d][key]
    __shared__ unsigned short Ps[4][16][72];    // per-wave P tile [q][key]

    const unsigned short* qrow = Qb + (size_t)(qt * 64 + w * 16 + l15) * D_DIM + hco;
    bf16x8 qf0 = *(const bf16x8*)(qrow + quad * 8);
    bf16x8 qf1 = *(const bf16x8*)(qrow + 32 + quad * 8);

    f32x4 oac[4];
    #pragma unroll
    for (int nt = 0; nt < 4; ++nt) { f32x4 z = {0.f,0.f,0.f,0.f}; oac[nt] = z; }
    float lsum = 0.f;                    // per-lane: keys {nt*16+quad*4+r}, q = l15

    const int rr = t >> 2;          // staging row (K: key row; Vt: d row)
    const int dc = (t & 3) * 16;    // 16-col group

    const unsigned short* kbase = Kb  + (size_t)rr * D_DIM + hco + dc;
    const unsigned short* vbase = Vtg + (size_t)(hco + rr) * S_LEN + dc;

    uint4 ka0, ka1, va0, va1;
    {
        const unsigned short* kp = kbase + (size_t)jlo * 64 * D_DIM;
        const unsigned short* vp = vbase + (size_t)jlo * 64;
        ka0 = *(const uint4*)kp;  ka1 = *(const uint4*)(kp + 8);
        va0 = *(const uint4*)vp;  va1 = *(const uint4*)(vp + 8);
    }

    const int q_g = qt * 64 + w * 16 + l15;             // this lane's query row
    const float C2 = -11.541560327111707f;              // -8 * log2(e)

    for (int j = jlo; j <= jhi; ++j) {
        const int buf = (j - jlo) & 1;
        // write this tile's LDS from prefetched regs (vmcnt wait auto-inserted)
        *(uint4*)&Ks[buf][rr][dc]     = ka0;
        *(uint4*)&Ks[buf][rr][dc + 8] = ka1;
        *(uint4*)&Vt[buf][rr][dc]     = va0;
        *(uint4*)&Vt[buf][rr][dc + 8] = va1;
        __syncthreads();                       // ONE barrier per iteration
        if (j < jhi) {                         // prefetch next tile into regs
            const unsigned short* kp = kbase + (size_t)(j + 1) * 64 * D_DIM;
            const unsigned short* vp = vbase + (size_t)(j + 1) * 64;
            ka0 = *(const uint4*)kp;  ka1 = *(const uint4*)(kp + 8);
            va0 = *(const uint4*)vp;  va1 = *(const uint4*)(vp + 8);
        }

        // S^T = K Q^T (64 keys x 16 q-rows): A = K-frag, B = Q-frag.
        // Output: key = nt*16 + quad*4 + reg, q = l15.
        f32x4 sac[4];
        #pragma unroll
        for (int nt = 0; nt < 4; ++nt) {
            f32x4 z = {0.f,0.f,0.f,0.f};
            bf16x8 kf0 = *(const bf16x8*)&Ks[buf][nt * 16 + l15][quad * 8];
            z = __builtin_amdgcn_mfma_f32_16x16x32_bf16(kf0, qf0, z, 0, 0, 0);
            bf16x8 kf1 = *(const bf16x8*)&Ks[buf][nt * 16 + l15][32 + quad * 8];
            z = __builtin_amdgcn_mfma_f32_16x16x32_bf16(kf1, qf1, z, 0, 0, 0);
            sac[nt] = z;
        }

        if (j < qt) {
            // bulk: no masking needed
            #pragma unroll
            for (int nt = 0; nt < 4; ++nt) {
                float pe0 = exp2f(sac[nt][0] + C2);
                float pe1 = exp2f(sac[nt][1] + C2);
                float pe2 = exp2f(sac[nt][2] + C2);
                float pe3 = exp2f(sac[nt][3] + C2);
                lsum += (pe0 + pe1) + (pe2 + pe3);
                ushort4 pk;
                pk.x = f2b_trunc(pe0); pk.y = f2b_trunc(pe1);
                pk.z = f2b_trunc(pe2); pk.w = f2b_trunc(pe3);
                *(ushort4*)&Ps[w][l15][nt * 16 + quad * 4] = pk;
            }
        } else {
            // diagonal tile: causal mask on key index (reg-indexed now)
            #pragma unroll
            for (int nt = 0; nt < 4; ++nt) {
                int key0 = j * 64 + nt * 16 + quad * 4;
                float pe[4];
                #pragma unroll
                for (int r = 0; r < 4; ++r) {
                    float s = sac[nt][r] + C2;
                    if (key0 + r > q_g) s = NEG_BIG;
                    pe[r] = exp2f(s);
                    lsum += pe[r];
                }
                ushort4 pk;
                pk.x = f2b_trunc(pe[0]); pk.y = f2b_trunc(pe[1]);
                pk.z = f2b_trunc(pe[2]); pk.w = f2b_trunc(pe[3]);
                *(ushort4*)&Ps[w][l15][nt * 16 + quad * 4] = pk;
            }
        }

        // P is already [q][key] in LDS; read A-frag directly, then PV
        bf16x8 pf0 = *(const bf16x8*)&Ps[w][l15][quad * 8];
        bf16x8 pf1 = *(const bf16x8*)&Ps[w][l15][32 + quad * 8];
        #pragma unroll
        for (int nt = 0; nt < 4; ++nt) {
            bf16x8 vf0 = *(const bf16x8*)&Vt[buf][nt * 16 + l15][quad * 8];
            oac[nt] = __builtin_amdgcn_mfma_f32_16x16x32_bf16(pf0, vf0, oac[nt], 0, 0, 0);
            bf16x8 vf1 = *(const bf16x8*)&Vt[buf][nt * 16 + l15][32 + quad * 8];
            oac[nt] = __builtin_amdgcn_mfma_f32_16x16x32_bf16(pf1, vf1, oac[nt], 0, 0, 0);
        }
    }

    // partials: l per q-row (reduce lane-scalar across quads) + unnormalized O
    float lr = lsum;
    lr += __shfl_xor(lr, 16);
    lr += __shfl_xor(lr, 32);            // all quads now hold l[q = l15]
    if (l < 16)
        Lpart[(size_t)slot * 64 + w * 16 + l15] = lr;
    float* Op = Opart + (size_t)slot * 4096;
    #pragma unroll
    for (int nt = 0; nt < 4; ++nt)
        #pragma unroll
        for (int r = 0; r < 4; ++r)
            Op[(size_t)(w * 16 + quad * 4 + r) * 64 + nt * 16 + l15] = oac[nt][r];
}

// sum <=4 key-chunk partials, normalize, cast to bf16. Also zeroes the f32 y
// region (needed by the split-K atomic out-projection that follows).
// grid (32 qt, 16 h), 256 threads: thread = (row 0..63, 16-col group).
__global__ __launch_bounds__(256)
void attn_combine(const float* __restrict__ Opart, const float* __restrict__ Lpart,
                  unsigned short* __restrict__ Ob, float* __restrict__ yzero)
{
    const int qt  = blockIdx.x;
    const int h   = blockIdx.y;
    const int t   = threadIdx.x;
    const int row = t >> 2;
    const int c0  = (t & 3) * 16;
    float acc[16];
    #pragma unroll
    for (int i = 0; i < 16; ++i) acc[i] = 0.f;
    float lsum = 0.f;
    for (int c = 0; c < 4; ++c) {
        if (c * 8 > qt) break;                        // chunks are 8 key-tiles each
        const size_t slot = (size_t)((qt * 4 + c) * NH + h);
        const float* Op = Opart + slot * 4096 + (size_t)row * 64 + c0;
        #pragma unroll
        for (int g = 0; g < 4; ++g) {
            float4 a = *(const float4*)(Op + g * 4);
            acc[g * 4 + 0] += a.x; acc[g * 4 + 1] += a.y;
            acc[g * 4 + 2] += a.z; acc[g * 4 + 3] += a.w;
        }
        lsum += Lpart[slot * 64 + row];
    }
    const float inv = 1.f / lsum;   // > 0: diagonal key always contributes
    unsigned int pk[8];
    #pragma unroll
    for (int i = 0; i < 8; ++i)
        pk[i] = f2b(acc[2 * i] * inv) | ((unsigned)f2b(acc[2 * i + 1] * inv) << 16);
    unsigned short* dst = Ob + (size_t)(qt * 64 + row) * D_DIM + h * 64 + c0;
    *(uint4*)dst       = make_uint4(pk[0], pk[1], pk[2], pk[3]);
    *(uint4*)(dst + 8) = make_uint4(pk[4], pk[5], pk[6], pk[7]);

    // zero 16 floats of y (2M floats / 131072 threads)
    const int flat = (h * 32 + qt) * 256 + t;
    float4 z4 = {0.f, 0.f, 0.f, 0.f};
    float4* yz = (float4*)(yzero + (size_t)flat * 16);
    yz[0] = z4; yz[1] = z4; yz[2] = z4; yz[3] = z4;
}

// v1 passthrough (f32), 16B chunks.
__global__ __launch_bounds__(256)
void copy_v1(const uint4* __restrict__ src, uint4* __restrict__ dst) {
    int i = blockIdx.x * 256 + threadIdx.x;
    dst[i] = src[i];
}

extern "C" void kernel_launch(void* const* d_in, const int* in_sizes, int n_in,
                              void* d_out, int out_size, void* d_ws, size_t ws_size,
                              hipStream_t stream)
{
    const float* x    = (const float*)d_in[0];
    const float* v1   = (const float*)d_in[1];
    const float* Wq   = (const float*)d_in[2];
    const float* Wk   = (const float*)d_in[3];
    const float* Wv   = (const float*)d_in[4];
    const float* Wout = (const float*)d_in[5];
    const float* lam  = (const float*)d_in[6];
    float* out = (float*)d_out;

    const size_t SD = (size_t)S_LEN * D_DIM;
    const size_t DD = (size_t)D_DIM * D_DIM;
    unsigned short* Qb  = (unsigned short*)d_ws;         // internal bf16, 4 MB
    unsigned short* Kb  = Qb + SD;                       // 4 MB
    unsigned short* Vtg = Kb + SD;                       // V transposed [D_DIM][S_LEN], 4 MB
    unsigned short* Ab  = Qb;                            // alias (attn output after combine)
    float* Opart = (float*)(Vtg + SD);                   // 2048 slots * 16 KB = 32 MB
    float* Lpart = Opart + (size_t)2048 * 4096;          // 512 KB

    // bf16 scratch in d_out (16 MB f32): y slot holds Wq/Wk/Wv copies (6 MB,
    // overwritten by out-proj), v1 slot holds xb+Woutb (6 MB, overwritten by copy_v1).
    unsigned short* Wqb   = (unsigned short*)d_out;            // 2 MB
    unsigned short* Wkb   = Wqb + DD;                          // 2 MB
    unsigned short* Wvb   = Wkb + DD;                          // 2 MB
    unsigned short* xb    = (unsigned short*)(out + SD);       // 4 MB
    unsigned short* Woutb = xb + SD;                           // 2 MB

    to_bf16<<<dim3(1024, 5), 256, 0, stream>>>(
        x, Wq, Wk, Wv, Wout, xb, Wqb, Wkb, Wvb, Woutb);

    // Q/K/V projections; Q gets pre-scaled RMSNorm+RoPE, K plain, V v-mix + transpose.
    gemm_bt<<<dim3(D_DIM / 128, S_LEN / 128, 3), 256, 0, stream>>>(
        xb, Wqb, Wkb, Wvb, Qb, Kb, Vtg, v1, lam,
        EPI_NORMROPE_Q | (EPI_NORMROPE << 8) | (EPI_VMIX_T << 16), 0);

    // key-split flash attention: fixed 8-tile chunks, partials + combine
    attn_mfma<<<dim3(80, NH), 256, 0, stream>>>(Qb, Kb, Vtg, Opart, Lpart);
    attn_combine<<<dim3(S_LEN / 64, NH), 256, 0, stream>>>(Opart, Lpart, Ab, out);

    // output projection, split-K=2 (256 blocks), atomic f32 into zeroed y
    gemm_bt<<<dim3(D_DIM / 128, S_LEN / 128, 2), 256, 0, stream>>>(
        Ab, Woutb, Woutb, Woutb, d_out, d_out, d_out, nullptr, lam, EPI_F32A, 1);

    copy_v1<<<dim3((unsigned)(SD / 4 / 256)), 256, 0, stream>>>(
        (const uint4*)v1, (uint4*)(out + SD));
}

// Round 3
// 175.973 us; speedup vs baseline: 1.0312x; 1.0167x over previous
//
#include <hip/hip_runtime.h>
#include <hip/hip_bf16.h>

#define S_LEN 2048
#define D_DIM 1024
#define NH    16
#define NEG_BIG (-1.0e30f)

// epilogue modes
#define EPI_NORMROPE   1   // RMSNorm + RoPE, store bf16 row-major (K)
#define EPI_VMIX_T     2   // v-mix with v1, store bf16 TRANSPOSED (V -> Vt_g[d][s])
#define EPI_F32        3   // plain f32 row-major store (out-proj)
#define EPI_NORMROPE_Q 4   // like NORMROPE but pre-scaled by 0.125*log2e (Q)
#define EPI_F32A       5   // f32 atomicAdd (split-K out-proj; y pre-zeroed)

typedef __attribute__((ext_vector_type(8))) short bf16x8;
typedef __attribute__((ext_vector_type(4))) float f32x4;
typedef const __attribute__((address_space(1))) unsigned char gu8_t;
typedef __attribute__((address_space(3))) unsigned char lu8_t;

__device__ __forceinline__ float bf2f(unsigned short h) {
    union { unsigned int u; float f; } v; v.u = ((unsigned int)h) << 16; return v.f;
}
__device__ __forceinline__ unsigned short f2b(float f) {   // RNE f32->bf16 raw bits
    union { float f; unsigned int u; } v; v.f = f;
    unsigned int u = v.u;
    return (unsigned short)((u + 0x7FFFu + ((u >> 16) & 1u)) >> 16);
}
__device__ __forceinline__ unsigned short f2b_trunc(float f) {  // trunc (p>=0 only)
    union { float f; unsigned int u; } v; v.f = f;
    return (unsigned short)(v.u >> 16);
}

// one-shot f32 -> bf16 conversion of x + 4 weights.
__global__ __launch_bounds__(256)
void to_bf16(const float* __restrict__ x,  const float* __restrict__ wq,
             const float* __restrict__ wk, const float* __restrict__ wv,
             const float* __restrict__ wo,
             unsigned short* __restrict__ xb,  unsigned short* __restrict__ wqb,
             unsigned short* __restrict__ wkb, unsigned short* __restrict__ wvb,
             unsigned short* __restrict__ wob)
{
    const int z = blockIdx.y;
    const float* s; unsigned short* d; int n;
    switch (z) {
        case 0: s = x;  d = xb;  n = S_LEN * D_DIM; break;
        case 1: s = wq; d = wqb; n = D_DIM * D_DIM; break;
        case 2: s = wk; d = wkb; n = D_DIM * D_DIM; break;
        case 3: s = wv; d = wvb; n = D_DIM * D_DIM; break;
        default: s = wo; d = wob; n = D_DIM * D_DIM; break;
    }
    int i8 = blockIdx.x * 256 + threadIdx.x;
    if (i8 * 8 >= n) return;
    const float* sp = s + (size_t)i8 * 8;
    float4 lo = *(const float4*)sp, hi = *(const float4*)(sp + 4);
    uint4 p;
    p.x = f2b(lo.x) | ((unsigned)f2b(lo.y) << 16);
    p.y = f2b(lo.z) | ((unsigned)f2b(lo.w) << 16);
    p.z = f2b(hi.x) | ((unsigned)f2b(hi.y) << 16);
    p.w = f2b(hi.z) | ((unsigned)f2b(hi.w) << 16);
    *(uint4*)(d + (size_t)i8 * 8) = p;
}

// 64x128-tile GEMM for the QKV projections: C = A[M,K] * B[N,K]^T.
// Grid (N/128, M/64, 3) = 768 blocks -> EXACTLY 3 blocks/CU, balanced
// (the old 128x128 grid was 384 blocks = 1.5/CU, half the CUs at 1 block).
// 4 waves as 2x2, each wave 32 rows x 64 cols (one head in N) -> acc[2][4].
__global__ __launch_bounds__(256, 3)
void gemm64(const unsigned short* __restrict__ A,
            const unsigned short* __restrict__ B0, const unsigned short* __restrict__ B1,
            const unsigned short* __restrict__ B2,
            void* __restrict__ C0, void* __restrict__ C1, void* __restrict__ C2,
            const float* __restrict__ vmix, const float* __restrict__ lam,
            int epiPack)
{
    const int which = blockIdx.z;
    const unsigned short* Bp = (which == 0) ? B0 : ((which == 1) ? B1 : B2);
    void* C = (which == 0) ? C0 : ((which == 1) ? C1 : C2);
    const int epi = (epiPack >> (8 * which)) & 0xff;
    const int tn = blockIdx.x * 128;
    const int tm = blockIdx.y * 64;

    __shared__ unsigned short Asl[64 * 32];    // unpadded: global_load_lds contract
    __shared__ unsigned short Bsl[128 * 32];

    const int t    = threadIdx.x;
    const int lane = t & 63;
    const int wave = t >> 6;
    const int wm   = (wave >> 1) * 32;
    const int wn   = (wave & 1) * 64;
    const int lrow = lane & 15;
    const int quad = lane >> 4;
    const int srow = t >> 2;          // staging row 0..63
    const int scol = (t & 3) * 8;     // staging col group

    f32x4 acc[2][4];
    #pragma unroll
    for (int i = 0; i < 2; ++i)
        #pragma unroll
        for (int j = 0; j < 4; ++j) {
            f32x4 z = {0.f, 0.f, 0.f, 0.f};
            acc[i][j] = z;
        }

    for (int k0 = 0; k0 < D_DIM; k0 += 32) {
        // A tile 64x32: one 16B load/thread; LDS dst linear in t (t*8 shorts).
        __builtin_amdgcn_global_load_lds(
            (gu8_t*)(A + (size_t)(tm + srow) * D_DIM + k0 + scol),
            (lu8_t*)&Asl[t * 8], 16, 0, 0);
        // B tile 128x32: two 16B loads/thread.
        __builtin_amdgcn_global_load_lds(
            (gu8_t*)(Bp + (size_t)(tn + srow) * D_DIM + k0 + scol),
            (lu8_t*)&Bsl[t * 8], 16, 0, 0);
        __builtin_amdgcn_global_load_lds(
            (gu8_t*)(Bp + (size_t)(tn + 64 + srow) * D_DIM + k0 + scol),
            (lu8_t*)&Bsl[2048 + t * 8], 16, 0, 0);
        __syncthreads();
        bf16x8 af[2], bfr[4];
        #pragma unroll
        for (int i = 0; i < 2; ++i)
            af[i] = *(const bf16x8*)(&Asl[(wm + i * 16 + lrow) * 32 + quad * 8]);
        #pragma unroll
        for (int j = 0; j < 4; ++j)
            bfr[j] = *(const bf16x8*)(&Bsl[(wn + j * 16 + lrow) * 32 + quad * 8]);
        #pragma unroll
        for (int i = 0; i < 2; ++i)
            #pragma unroll
            for (int j = 0; j < 4; ++j)
                acc[i][j] = __builtin_amdgcn_mfma_f32_16x16x32_bf16(af[i], bfr[j], acc[i][j], 0, 0, 0);
        __syncthreads();
    }

    if (epi == EPI_NORMROPE || epi == EPI_NORMROPE_Q) {
        // wave covers cols [tn+wn, tn+wn+64) = one head. RoPE pair = (v0,v2),(v1,v3).
        const float post = (epi == EPI_NORMROPE_Q) ? 0.18033688011112042f : 1.0f;
        #pragma unroll
        for (int i = 0; i < 2; ++i) {
            #pragma unroll
            for (int r = 0; r < 4; ++r) {
                int row = tm + wm + i * 16 + quad * 4 + r;   // seq position (m89/m91 C-map)
                float v0 = acc[i][0][r], v1 = acc[i][1][r];
                float v2 = acc[i][2][r], v3 = acc[i][3][r];
                float ss = v0 * v0 + v1 * v1 + v2 * v2 + v3 * v3;
                ss += __shfl_xor(ss, 1); ss += __shfl_xor(ss, 2);
                ss += __shfl_xor(ss, 4); ss += __shfl_xor(ss, 8);   // 16-lane group = full head
                float rms = rsqrtf(ss * (1.f / 64.f) + 1.1920929e-7f) * post;
                v0 *= rms; v1 *= rms; v2 *= rms; v3 *= rms;
                float fs = (float)row;
                float a0 = fs * exp2f(-0.41524101186092030f * (float)lrow);        // 10000^(-2i/64)
                float a1 = fs * exp2f(-0.41524101186092030f * (float)(16 + lrow));
                float s0, c0, s1, c1;
                __sincosf(a0, &s0, &c0);
                __sincosf(a1, &s1, &c1);
                unsigned short* Cb = (unsigned short*)C;
                size_t base = (size_t)row * D_DIM + tn + wn + lrow;
                Cb[base]      = f2b(v0 * c0 + v2 * s0);
                Cb[base + 16] = f2b(v1 * c1 + v3 * s1);
                Cb[base + 32] = f2b(-v0 * s0 + v2 * c0);
                Cb[base + 48] = f2b(-v1 * s1 + v3 * c1);
            }
        }
    } else if (epi == EPI_VMIX_T) {
        float lamf = *lam;
        #pragma unroll
        for (int i = 0; i < 2; ++i) {
            int cm0 = tm + wm + i * 16 + quad * 4;
            #pragma unroll
            for (int j = 0; j < 4; ++j) {
                int cn = tn + wn + j * 16 + lrow;
                ushort4 pk;
                float vals[4];
                #pragma unroll
                for (int r = 0; r < 4; ++r) {
                    size_t idx = (size_t)(cm0 + r) * D_DIM + cn;
                    vals[r] = (1.f - lamf) * acc[i][j][r] + lamf * vmix[idx];
                }
                pk.x = f2b(vals[0]); pk.y = f2b(vals[1]);
                pk.z = f2b(vals[2]); pk.w = f2b(vals[3]);
                *(ushort4*)((unsigned short*)C + (size_t)cn * S_LEN + cm0) = pk;
            }
        }
    } else {   // EPI_F32
        #pragma unroll
        for (int i = 0; i < 2; ++i) {
            int cm0 = tm + wm + i * 16 + quad * 4;
            #pragma unroll
            for (int j = 0; j < 4; ++j) {
                int cn = tn + wn + j * 16 + lrow;
                #pragma unroll
                for (int r = 0; r < 4; ++r)
                    ((float*)C)[(size_t)(cm0 + r) * D_DIM + cn] = acc[i][j][r];
            }
        }
    }
}

// 128x128-tile GEMM (m97 structure), used for the split-K out-projection.
__global__ __launch_bounds__(256, 3)
void gemm_bt(const unsigned short* __restrict__ A,
             const unsigned short* __restrict__ B0,
             void* __restrict__ C0,
             const float* __restrict__ lam,
             int epi, int splitK)
{
    const int which = blockIdx.z;
    const unsigned short* Bp = B0;
    void* C = C0;
    int kLo = 0, kHi = D_DIM;
    if (splitK) { kLo = which * (D_DIM / 2); kHi = kLo + D_DIM / 2; }
    const int tn = blockIdx.x * 128;
    const int tm = blockIdx.y * 128;

    __shared__ unsigned short Asl[128 * 32];   // unpadded: global_load_lds contract
    __shared__ unsigned short Bsl[128 * 32];

    const int t    = threadIdx.x;
    const int lane = t & 63;
    const int wave = t >> 6;
    const int wm   = (wave >> 1) * 64;
    const int wn   = (wave & 1) * 64;
    const int lrow = lane & 15;
    const int quad = lane >> 4;
    const int srow = lane >> 2;
    const int scol = (lane & 3) * 8;

    f32x4 acc[4][4];
    #pragma unroll
    for (int i = 0; i < 4; ++i)
        #pragma unroll
        for (int j = 0; j < 4; ++j) {
            f32x4 z = {0.f, 0.f, 0.f, 0.f};
            acc[i][j] = z;
        }

    for (int k0 = kLo; k0 < kHi; k0 += 32) {
        #pragma unroll
        for (int rep = 0; rep < 2; ++rep) {
            int grp = wave * 2 + rep;               // 0..7 (16 rows each)
            int row = grp * 16 + srow;
            __builtin_amdgcn_global_load_lds(
                (gu8_t*)(A + (size_t)(tm + row) * D_DIM + k0 + scol),
                (lu8_t*)&Asl[grp * 512], 16, 0, 0);
            __builtin_amdgcn_global_load_lds(
                (gu8_t*)(Bp + (size_t)(tn + row) * D_DIM + k0 + scol),
                (lu8_t*)&Bsl[grp * 512], 16, 0, 0);
        }
        __syncthreads();
        bf16x8 af[4], bfr[4];
        #pragma unroll
        for (int i = 0; i < 4; ++i)
            af[i] = *(const bf16x8*)(&Asl[(wm + i * 16 + lrow) * 32 + quad * 8]);
        #pragma unroll
        for (int j = 0; j < 4; ++j)
            bfr[j] = *(const bf16x8*)(&Bsl[(wn + j * 16 + lrow) * 32 + quad * 8]);
        #pragma unroll
        for (int i = 0; i < 4; ++i)
            #pragma unroll
            for (int j = 0; j < 4; ++j)
                acc[i][j] = __builtin_amdgcn_mfma_f32_16x16x32_bf16(af[i], bfr[j], acc[i][j], 0, 0, 0);
        __syncthreads();
    }

    if (epi == EPI_F32A) {
        #pragma unroll
        for (int i = 0; i < 4; ++i) {
            int cm0 = tm + wm + i * 16 + quad * 4;
            #pragma unroll
            for (int j = 0; j < 4; ++j) {
                int cn = tn + wn + j * 16 + lrow;
                #pragma unroll
                for (int r = 0; r < 4; ++r)
                    atomicAdd(&((float*)C)[(size_t)(cm0 + r) * D_DIM + cn], acc[i][j][r]);
            }
        }
    } else {   // EPI_F32
        #pragma unroll
        for (int i = 0; i < 4; ++i) {
            int cm0 = tm + wm + i * 16 + quad * 4;
            #pragma unroll
            for (int j = 0; j < 4; ++j) {
                int cn = tn + wn + j * 16 + lrow;
                #pragma unroll
                for (int r = 0; r < 4; ++r)
                    ((float*)C)[(size_t)(cm0 + r) * D_DIM + cn] = acc[i][j][r];
            }
        }
    }
}

// MFMA flash attention, key-split with SWAPPED-OPERAND QK^T (see r2 notes).
// Fixed 8-key-tile chunks; static-max log2-domain softmax keeps chunk partials
// purely additive. s_setprio(1) wraps the MFMA clusters (T5: attn-structure win).
__global__ __launch_bounds__(256, 3)
void attn_mfma(const unsigned short* Qb,
               const unsigned short* __restrict__ Kb,
               const unsigned short* __restrict__ Vtg,
               float* __restrict__ Opart, float* __restrict__ Lpart)
{
    const int bx = blockIdx.x;            // 0..79, big qt first
    int qt, c;
    if (bx < 32)      { qt = 31 - (bx >> 2);            c = bx & 3;  }  // qt 31..24: 4 chunks
    else if (bx < 56) { int i = bx - 32; qt = 23 - i/3; c = i % 3;   }  // qt 23..16: 3 chunks
    else if (bx < 72) { int i = bx - 56; qt = 15 - (i>>1); c = i & 1;}  // qt 15..8 : 2 chunks
    else              { qt = 7 - (bx - 72);             c = 0;       }  // qt 7..0  : 1 chunk
    const int jlo = c * 8;
    const int jhi = min(jlo + 7, qt);
    const int h  = blockIdx.y;
    const int t  = threadIdx.x;
    const int w  = t >> 6;
    const int l  = t & 63;
    const int l15  = l & 15;
    const int quad = l >> 4;
    const int hco  = h * 64;
    const int slot = (qt * 4 + c) * NH + h;

    __shared__ unsigned short Ks[2][64][72];    // double-buffered
    __shared__ unsigned short Vt[2][64][72];    // Vt[buf][d][key]
    __shared__ unsigned short Ps[4][16][72];    // per-wave P tile [q][key]

    const unsigned short* qrow = Qb + (size_t)(qt * 64 + w * 16 + l15) * D_DIM + hco;
    bf16x8 qf0 = *(const bf16x8*)(qrow + quad * 8);
    bf16x8 qf1 = *(const bf16x8*)(qrow + 32 + quad * 8);

    f32x4 oac[4];
    #pragma unroll
    for (int nt = 0; nt < 4; ++nt) { f32x4 z = {0.f,0.f,0.f,0.f}; oac[nt] = z; }
    float lsum = 0.f;                    // per-lane: keys {nt*16+quad*4+r}, q = l15

    const int rr = t >> 2;          // staging row (K: key row; Vt: d row)
    const int dc = (t & 3) * 16;    // 16-col group

    const unsigned short* kbase = Kb  + (size_t)rr * D_DIM + hco + dc;
    const unsigned short* vbase = Vtg + (size_t)(hco + rr) * S_LEN + dc;

    uint4 ka0, ka1, va0, va1;
    {
        const unsigned short* kp = kbase + (size_t)jlo * 64 * D_DIM;
        const unsigned short* vp = vbase + (size_t)jlo * 64;
        ka0 = *(const uint4*)kp;  ka1 = *(const uint4*)(kp + 8);
        va0 = *(const uint4*)vp;  va1 = *(const uint4*)(vp + 8);
    }

    const int q_g = qt * 64 + w * 16 + l15;             // this lane's query row
    const float C2 = -11.541560327111707f;              // -8 * log2(e)

    for (int j = jlo; j <= jhi; ++j) {
        const int buf = (j - jlo) & 1;
        // write this tile's LDS from prefetched regs (vmcnt wait auto-inserted)
        *(uint4*)&Ks[buf][rr][dc]     = ka0;
        *(uint4*)&Ks[buf][rr][dc + 8] = ka1;
        *(uint4*)&Vt[buf][rr][dc]     = va0;
        *(uint4*)&Vt[buf][rr][dc + 8] = va1;
        __syncthreads();                       // ONE barrier per iteration
        if (j < jhi) {                         // prefetch next tile into regs
            const unsigned short* kp = kbase + (size_t)(j + 1) * 64 * D_DIM;
            const unsigned short* vp = vbase + (size_t)(j + 1) * 64;
            ka0 = *(const uint4*)kp;  ka1 = *(const uint4*)(kp + 8);
            va0 = *(const uint4*)vp;  va1 = *(const uint4*)(vp + 8);
        }

        // S^T = K Q^T (64 keys x 16 q-rows): key = nt*16 + quad*4 + reg, q = l15.
        f32x4 sac[4];
        __builtin_amdgcn_s_setprio(1);
        #pragma unroll
        for (int nt = 0; nt < 4; ++nt) {
            f32x4 z = {0.f,0.f,0.f,0.f};
            bf16x8 kf0 = *(const bf16x8*)&Ks[buf][nt * 16 + l15][quad * 8];
            z = __builtin_amdgcn_mfma_f32_16x16x32_bf16(kf0, qf0, z, 0, 0, 0);
            bf16x8 kf1 = *(const bf16x8*)&Ks[buf][nt * 16 + l15][32 + quad * 8];
            z = __builtin_amdgcn_mfma_f32_16x16x32_bf16(kf1, qf1, z, 0, 0, 0);
            sac[nt] = z;
        }
        __builtin_amdgcn_s_setprio(0);

        if (j < qt) {
            // bulk: no masking needed
            #pragma unroll
            for (int nt = 0; nt < 4; ++nt) {
                float pe0 = exp2f(sac[nt][0] + C2);
                float pe1 = exp2f(sac[nt][1] + C2);
                float pe2 = exp2f(sac[nt][2] + C2);
                float pe3 = exp2f(sac[nt][3] + C2);
                lsum += (pe0 + pe1) + (pe2 + pe3);
                ushort4 pk;
                pk.x = f2b_trunc(pe0); pk.y = f2b_trunc(pe1);
                pk.z = f2b_trunc(pe2); pk.w = f2b_trunc(pe3);
                *(ushort4*)&Ps[w][l15][nt * 16 + quad * 4] = pk;
            }
        } else {
            // diagonal tile: causal mask on key index (reg-indexed)
            #pragma unroll
            for (int nt = 0; nt < 4; ++nt) {
                int key0 = j * 64 + nt * 16 + quad * 4;
                float pe[4];
                #pragma unroll
                for (int r = 0; r < 4; ++r) {
                    float s = sac[nt][r] + C2;
                    if (key0 + r > q_g) s = NEG_BIG;
                    pe[r] = exp2f(s);
                    lsum += pe[r];
                }
                ushort4 pk;
                pk.x = f2b_trunc(pe[0]); pk.y = f2b_trunc(pe[1]);
                pk.z = f2b_trunc(pe[2]); pk.w = f2b_trunc(pe[3]);
                *(ushort4*)&Ps[w][l15][nt * 16 + quad * 4] = pk;
            }
        }

        // P is already [q][key] in LDS; read A-frag directly, then PV
        bf16x8 pf0 = *(const bf16x8*)&Ps[w][l15][quad * 8];
        bf16x8 pf1 = *(const bf16x8*)&Ps[w][l15][32 + quad * 8];
        __builtin_amdgcn_s_setprio(1);
        #pragma unroll
        for (int nt = 0; nt < 4; ++nt) {
            bf16x8 vf0 = *(const bf16x8*)&Vt[buf][nt * 16 + l15][quad * 8];
            oac[nt] = __builtin_amdgcn_mfma_f32_16x16x32_bf16(pf0, vf0, oac[nt], 0, 0, 0);
            bf16x8 vf1 = *(const bf16x8*)&Vt[buf][nt * 16 + l15][32 + quad * 8];
            oac[nt] = __builtin_amdgcn_mfma_f32_16x16x32_bf16(pf1, vf1, oac[nt], 0, 0, 0);
        }
        __builtin_amdgcn_s_setprio(0);
    }

    // partials: l per q-row (reduce lane-scalar across quads) + unnormalized O
    float lr = lsum;
    lr += __shfl_xor(lr, 16);
    lr += __shfl_xor(lr, 32);            // all quads now hold l[q = l15]
    if (l < 16)
        Lpart[(size_t)slot * 64 + w * 16 + l15] = lr;
    float* Op = Opart + (size_t)slot * 4096;
    #pragma unroll
    for (int nt = 0; nt < 4; ++nt)
        #pragma unroll
        for (int r = 0; r < 4; ++r)
            Op[(size_t)(w * 16 + quad * 4 + r) * 64 + nt * 16 + l15] = oac[nt][r];
}

// sum <=4 key-chunk partials, normalize, cast to bf16. Also zeroes the f32 y
// region (needed by the split-K atomic out-projection that follows).
__global__ __launch_bounds__(256)
void attn_combine(const float* __restrict__ Opart, const float* __restrict__ Lpart,
                  unsigned short* __restrict__ Ob, float* __restrict__ yzero)
{
    const int qt  = blockIdx.x;
    const int h   = blockIdx.y;
    const int t   = threadIdx.x;
    const int row = t >> 2;
    const int c0  = (t & 3) * 16;
    float acc[16];
    #pragma unroll
    for (int i = 0; i < 16; ++i) acc[i] = 0.f;
    float lsum = 0.f;
    for (int c = 0; c < 4; ++c) {
        if (c * 8 > qt) break;                        // chunks are 8 key-tiles each
        const size_t slot = (size_t)((qt * 4 + c) * NH + h);
        const float* Op = Opart + slot * 4096 + (size_t)row * 64 + c0;
        #pragma unroll
        for (int g = 0; g < 4; ++g) {
            float4 a = *(const float4*)(Op + g * 4);
            acc[g * 4 + 0] += a.x; acc[g * 4 + 1] += a.y;
            acc[g * 4 + 2] += a.z; acc[g * 4 + 3] += a.w;
        }
        lsum += Lpart[slot * 64 + row];
    }
    const float inv = 1.f / lsum;   // > 0: diagonal key always contributes
    unsigned int pk[8];
    #pragma unroll
    for (int i = 0; i < 8; ++i)
        pk[i] = f2b(acc[2 * i] * inv) | ((unsigned)f2b(acc[2 * i + 1] * inv) << 16);
    unsigned short* dst = Ob + (size_t)(qt * 64 + row) * D_DIM + h * 64 + c0;
    *(uint4*)dst       = make_uint4(pk[0], pk[1], pk[2], pk[3]);
    *(uint4*)(dst + 8) = make_uint4(pk[4], pk[5], pk[6], pk[7]);

    // zero 16 floats of y (2M floats / 131072 threads)
    const int flat = (h * 32 + qt) * 256 + t;
    float4 z4 = {0.f, 0.f, 0.f, 0.f};
    float4* yz = (float4*)(yzero + (size_t)flat * 16);
    yz[0] = z4; yz[1] = z4; yz[2] = z4; yz[3] = z4;
}

// v1 passthrough (f32), 16B chunks.
__global__ __launch_bounds__(256)
void copy_v1(const uint4* __restrict__ src, uint4* __restrict__ dst) {
    int i = blockIdx.x * 256 + threadIdx.x;
    dst[i] = src[i];
}

extern "C" void kernel_launch(void* const* d_in, const int* in_sizes, int n_in,
                              void* d_out, int out_size, void* d_ws, size_t ws_size,
                              hipStream_t stream)
{
    const float* x    = (const float*)d_in[0];
    const float* v1   = (const float*)d_in[1];
    const float* Wq   = (const float*)d_in[2];
    const float* Wk   = (const float*)d_in[3];
    const float* Wv   = (const float*)d_in[4];
    const float* Wout = (const float*)d_in[5];
    const float* lam  = (const float*)d_in[6];
    float* out = (float*)d_out;

    const size_t SD = (size_t)S_LEN * D_DIM;
    const size_t DD = (size_t)D_DIM * D_DIM;
    unsigned short* Qb  = (unsigned short*)d_ws;         // internal bf16, 4 MB
    unsigned short* Kb  = Qb + SD;                       // 4 MB
    unsigned short* Vtg = Kb + SD;                       // V transposed [D_DIM][S_LEN], 4 MB
    unsigned short* Ab  = Qb;                            // alias (attn output after combine)
    float* Opart = (float*)(Vtg + SD);                   // 2048 slots * 16 KB = 32 MB
    float* Lpart = Opart + (size_t)2048 * 4096;          // 512 KB

    // bf16 scratch in d_out (16 MB f32)
    unsigned short* Wqb   = (unsigned short*)d_out;            // 2 MB
    unsigned short* Wkb   = Wqb + DD;                          // 2 MB
    unsigned short* Wvb   = Wkb + DD;                          // 2 MB
    unsigned short* xb    = (unsigned short*)(out + SD);       // 4 MB
    unsigned short* Woutb = xb + SD;                           // 2 MB

    to_bf16<<<dim3(1024, 5), 256, 0, stream>>>(
        x, Wq, Wk, Wv, Wout, xb, Wqb, Wkb, Wvb, Woutb);

    // Q/K/V projections, 64x128 tiles: 768 blocks = 3/CU balanced.
    gemm64<<<dim3(D_DIM / 128, S_LEN / 64, 3), 256, 0, stream>>>(
        xb, Wqb, Wkb, Wvb, Qb, Kb, Vtg, v1, lam,
        EPI_NORMROPE_Q | (EPI_NORMROPE << 8) | (EPI_VMIX_T << 16));

    // key-split flash attention: fixed 8-tile chunks, partials + combine
    attn_mfma<<<dim3(80, NH), 256, 0, stream>>>(Qb, Kb, Vtg, Opart, Lpart);
    attn_combine<<<dim3(S_LEN / 64, NH), 256, 0, stream>>>(Opart, Lpart, Ab, out);

    // output projection, split-K=2 (256 blocks), atomic f32 into zeroed y
    gemm_bt<<<dim3(D_DIM / 128, S_LEN / 128, 2), 256, 0, stream>>>(
        Ab, Woutb, d_out, lam, EPI_F32A, 1);

    copy_v1<<<dim3((unsigned)(SD / 4 / 256)), 256, 0, stream>>>(
        (const uint4*)v1, (uint4*)(out + SD));
}

// Round 4
// 173.439 us; speedup vs baseline: 1.0462x; 1.0146x over previous
//
#include <hip/hip_runtime.h>
#include <hip/hip_bf16.h>

#define S_LEN 2048
#define D_DIM 1024
#define NH    16
#define NEG_BIG (-1.0e30f)

// epilogue modes
#define EPI_NORMROPE   1   // RMSNorm + RoPE, store bf16 row-major (K)
#define EPI_VMIX_T     2   // v-mix with v1, store bf16 TRANSPOSED (V -> Vt_g[d][s])
#define EPI_F32        3   // plain f32 row-major store (out-proj)
#define EPI_NORMROPE_Q 4   // like NORMROPE but pre-scaled by 0.125*log2e (Q)
#define EPI_F32A       5   // f32 atomicAdd (split-K out-proj; y pre-zeroed)

typedef __attribute__((ext_vector_type(8))) short bf16x8;
typedef __attribute__((ext_vector_type(4))) float f32x4;
typedef const __attribute__((address_space(1))) unsigned char gu8_t;
typedef __attribute__((address_space(3))) unsigned char lu8_t;

__device__ __forceinline__ float bf2f(unsigned short h) {
    union { unsigned int u; float f; } v; v.u = ((unsigned int)h) << 16; return v.f;
}
__device__ __forceinline__ unsigned short f2b(float f) {   // RNE f32->bf16 raw bits
    union { float f; unsigned int u; } v; v.f = f;
    unsigned int u = v.u;
    return (unsigned short)((u + 0x7FFFu + ((u >> 16) & 1u)) >> 16);
}
__device__ __forceinline__ unsigned short f2b_trunc(float f) {  // trunc (p>=0 only)
    union { float f; unsigned int u; } v; v.f = f;
    return (unsigned short)(v.u >> 16);
}

// one-shot f32 -> bf16 conversion of x + 4 weights, PLUS the v1 f32 passthrough
// (z=5) so copy_v1 no longer needs its own dispatch.
__global__ __launch_bounds__(256)
void to_bf16(const float* __restrict__ x,  const float* __restrict__ wq,
             const float* __restrict__ wk, const float* __restrict__ wv,
             const float* __restrict__ wo, const float* __restrict__ v1,
             unsigned short* __restrict__ xb,  unsigned short* __restrict__ wqb,
             unsigned short* __restrict__ wkb, unsigned short* __restrict__ wvb,
             unsigned short* __restrict__ wob, float* __restrict__ v1dst)
{
    const int z = blockIdx.y;
    int i8 = blockIdx.x * 256 + threadIdx.x;
    if (z == 5) {           // v1 f32 passthrough: 1024*256*8 = 2M floats exactly
        const float* sp = v1 + (size_t)i8 * 8;
        float4 lo = *(const float4*)sp, hi = *(const float4*)(sp + 4);
        float* dp = v1dst + (size_t)i8 * 8;
        *(float4*)dp = lo; *(float4*)(dp + 4) = hi;
        return;
    }
    const float* s; unsigned short* d; int n;
    switch (z) {
        case 0: s = x;  d = xb;  n = S_LEN * D_DIM; break;
        case 1: s = wq; d = wqb; n = D_DIM * D_DIM; break;
        case 2: s = wk; d = wkb; n = D_DIM * D_DIM; break;
        case 3: s = wv; d = wvb; n = D_DIM * D_DIM; break;
        default: s = wo; d = wob; n = D_DIM * D_DIM; break;
    }
    if (i8 * 8 >= n) return;
    const float* sp = s + (size_t)i8 * 8;
    float4 lo = *(const float4*)sp, hi = *(const float4*)(sp + 4);
    uint4 p;
    p.x = f2b(lo.x) | ((unsigned)f2b(lo.y) << 16);
    p.y = f2b(lo.z) | ((unsigned)f2b(lo.w) << 16);
    p.z = f2b(hi.x) | ((unsigned)f2b(hi.y) << 16);
    p.w = f2b(hi.z) | ((unsigned)f2b(hi.w) << 16);
    *(uint4*)(d + (size_t)i8 * 8) = p;
}

// 64x128-tile GEMM for the QKV projections: C = A[M,K] * B[N,K]^T.
// Grid (N/128, M/64, 3) = 768 blocks -> exactly 3 blocks/CU, balanced.
__global__ __launch_bounds__(256, 3)
void gemm64(const unsigned short* __restrict__ A,
            const unsigned short* __restrict__ B0, const unsigned short* __restrict__ B1,
            const unsigned short* __restrict__ B2,
            void* __restrict__ C0, void* __restrict__ C1, void* __restrict__ C2,
            const float* __restrict__ vmix, const float* __restrict__ lam,
            int epiPack)
{
    const int which = blockIdx.z;
    const unsigned short* Bp = (which == 0) ? B0 : ((which == 1) ? B1 : B2);
    void* C = (which == 0) ? C0 : ((which == 1) ? C1 : C2);
    const int epi = (epiPack >> (8 * which)) & 0xff;
    const int tn = blockIdx.x * 128;
    const int tm = blockIdx.y * 64;

    __shared__ unsigned short Asl[64 * 32];    // unpadded: global_load_lds contract
    __shared__ unsigned short Bsl[128 * 32];

    const int t    = threadIdx.x;
    const int lane = t & 63;
    const int wave = t >> 6;
    const int wm   = (wave >> 1) * 32;
    const int wn   = (wave & 1) * 64;
    const int lrow = lane & 15;
    const int quad = lane >> 4;
    const int srow = t >> 2;          // staging row 0..63
    const int scol = (t & 3) * 8;     // staging col group

    f32x4 acc[2][4];
    #pragma unroll
    for (int i = 0; i < 2; ++i)
        #pragma unroll
        for (int j = 0; j < 4; ++j) {
            f32x4 z = {0.f, 0.f, 0.f, 0.f};
            acc[i][j] = z;
        }

    for (int k0 = 0; k0 < D_DIM; k0 += 32) {
        __builtin_amdgcn_global_load_lds(
            (gu8_t*)(A + (size_t)(tm + srow) * D_DIM + k0 + scol),
            (lu8_t*)&Asl[t * 8], 16, 0, 0);
        __builtin_amdgcn_global_load_lds(
            (gu8_t*)(Bp + (size_t)(tn + srow) * D_DIM + k0 + scol),
            (lu8_t*)&Bsl[t * 8], 16, 0, 0);
        __builtin_amdgcn_global_load_lds(
            (gu8_t*)(Bp + (size_t)(tn + 64 + srow) * D_DIM + k0 + scol),
            (lu8_t*)&Bsl[2048 + t * 8], 16, 0, 0);
        __syncthreads();
        bf16x8 af[2], bfr[4];
        #pragma unroll
        for (int i = 0; i < 2; ++i)
            af[i] = *(const bf16x8*)(&Asl[(wm + i * 16 + lrow) * 32 + quad * 8]);
        #pragma unroll
        for (int j = 0; j < 4; ++j)
            bfr[j] = *(const bf16x8*)(&Bsl[(wn + j * 16 + lrow) * 32 + quad * 8]);
        #pragma unroll
        for (int i = 0; i < 2; ++i)
            #pragma unroll
            for (int j = 0; j < 4; ++j)
                acc[i][j] = __builtin_amdgcn_mfma_f32_16x16x32_bf16(af[i], bfr[j], acc[i][j], 0, 0, 0);
        __syncthreads();
    }

    if (epi == EPI_NORMROPE || epi == EPI_NORMROPE_Q) {
        // wave covers cols [tn+wn, tn+wn+64) = one head. RoPE pair = (v0,v2),(v1,v3).
        const float post = (epi == EPI_NORMROPE_Q) ? 0.18033688011112042f : 1.0f;
        #pragma unroll
        for (int i = 0; i < 2; ++i) {
            #pragma unroll
            for (int r = 0; r < 4; ++r) {
                int row = tm + wm + i * 16 + quad * 4 + r;   // seq position (m89/m91 C-map)
                float v0 = acc[i][0][r], v1 = acc[i][1][r];
                float v2 = acc[i][2][r], v3 = acc[i][3][r];
                float ss = v0 * v0 + v1 * v1 + v2 * v2 + v3 * v3;
                ss += __shfl_xor(ss, 1); ss += __shfl_xor(ss, 2);
                ss += __shfl_xor(ss, 4); ss += __shfl_xor(ss, 8);   // 16-lane group = full head
                float rms = rsqrtf(ss * (1.f / 64.f) + 1.1920929e-7f) * post;
                v0 *= rms; v1 *= rms; v2 *= rms; v3 *= rms;
                float fs = (float)row;
                float a0 = fs * exp2f(-0.41524101186092030f * (float)lrow);        // 10000^(-2i/64)
                float a1 = fs * exp2f(-0.41524101186092030f * (float)(16 + lrow));
                float s0, c0, s1, c1;
                __sincosf(a0, &s0, &c0);
                __sincosf(a1, &s1, &c1);
                unsigned short* Cb = (unsigned short*)C;
                size_t base = (size_t)row * D_DIM + tn + wn + lrow;
                Cb[base]      = f2b(v0 * c0 + v2 * s0);
                Cb[base + 16] = f2b(v1 * c1 + v3 * s1);
                Cb[base + 32] = f2b(-v0 * s0 + v2 * c0);
                Cb[base + 48] = f2b(-v1 * s1 + v3 * c1);
            }
        }
    } else if (epi == EPI_VMIX_T) {
        float lamf = *lam;
        #pragma unroll
        for (int i = 0; i < 2; ++i) {
            int cm0 = tm + wm + i * 16 + quad * 4;
            #pragma unroll
            for (int j = 0; j < 4; ++j) {
                int cn = tn + wn + j * 16 + lrow;
                ushort4 pk;
                float vals[4];
                #pragma unroll
                for (int r = 0; r < 4; ++r) {
                    size_t idx = (size_t)(cm0 + r) * D_DIM + cn;
                    vals[r] = (1.f - lamf) * acc[i][j][r] + lamf * vmix[idx];
                }
                pk.x = f2b(vals[0]); pk.y = f2b(vals[1]);
                pk.z = f2b(vals[2]); pk.w = f2b(vals[3]);
                *(ushort4*)((unsigned short*)C + (size_t)cn * S_LEN + cm0) = pk;
            }
        }
    } else {   // EPI_F32
        #pragma unroll
        for (int i = 0; i < 2; ++i) {
            int cm0 = tm + wm + i * 16 + quad * 4;
            #pragma unroll
            for (int j = 0; j < 4; ++j) {
                int cn = tn + wn + j * 16 + lrow;
                #pragma unroll
                for (int r = 0; r < 4; ++r)
                    ((float*)C)[(size_t)(cm0 + r) * D_DIM + cn] = acc[i][j][r];
            }
        }
    }
}

// 128x128-tile GEMM (m97 structure), used for the split-K out-projection.
__global__ __launch_bounds__(256, 3)
void gemm_bt(const unsigned short* __restrict__ A,
             const unsigned short* __restrict__ B0,
             void* __restrict__ C0,
             const float* __restrict__ lam,
             int epi, int splitK)
{
    const int which = blockIdx.z;
    const unsigned short* Bp = B0;
    void* C = C0;
    int kLo = 0, kHi = D_DIM;
    if (splitK) { kLo = which * (D_DIM / 2); kHi = kLo + D_DIM / 2; }
    const int tn = blockIdx.x * 128;
    const int tm = blockIdx.y * 128;

    __shared__ unsigned short Asl[128 * 32];   // unpadded: global_load_lds contract
    __shared__ unsigned short Bsl[128 * 32];

    const int t    = threadIdx.x;
    const int lane = t & 63;
    const int wave = t >> 6;
    const int wm   = (wave >> 1) * 64;
    const int wn   = (wave & 1) * 64;
    const int lrow = lane & 15;
    const int quad = lane >> 4;
    const int srow = lane >> 2;
    const int scol = (lane & 3) * 8;

    f32x4 acc[4][4];
    #pragma unroll
    for (int i = 0; i < 4; ++i)
        #pragma unroll
        for (int j = 0; j < 4; ++j) {
            f32x4 z = {0.f, 0.f, 0.f, 0.f};
            acc[i][j] = z;
        }

    for (int k0 = kLo; k0 < kHi; k0 += 32) {
        #pragma unroll
        for (int rep = 0; rep < 2; ++rep) {
            int grp = wave * 2 + rep;               // 0..7 (16 rows each)
            int row = grp * 16 + srow;
            __builtin_amdgcn_global_load_lds(
                (gu8_t*)(A + (size_t)(tm + row) * D_DIM + k0 + scol),
                (lu8_t*)&Asl[grp * 512], 16, 0, 0);
            __builtin_amdgcn_global_load_lds(
                (gu8_t*)(Bp + (size_t)(tn + row) * D_DIM + k0 + scol),
                (lu8_t*)&Bsl[grp * 512], 16, 0, 0);
        }
        __syncthreads();
        bf16x8 af[4], bfr[4];
        #pragma unroll
        for (int i = 0; i < 4; ++i)
            af[i] = *(const bf16x8*)(&Asl[(wm + i * 16 + lrow) * 32 + quad * 8]);
        #pragma unroll
        for (int j = 0; j < 4; ++j)
            bfr[j] = *(const bf16x8*)(&Bsl[(wn + j * 16 + lrow) * 32 + quad * 8]);
        #pragma unroll
        for (int i = 0; i < 4; ++i)
            #pragma unroll
            for (int j = 0; j < 4; ++j)
                acc[i][j] = __builtin_amdgcn_mfma_f32_16x16x32_bf16(af[i], bfr[j], acc[i][j], 0, 0, 0);
        __syncthreads();
    }

    if (epi == EPI_F32A) {
        #pragma unroll
        for (int i = 0; i < 4; ++i) {
            int cm0 = tm + wm + i * 16 + quad * 4;
            #pragma unroll
            for (int j = 0; j < 4; ++j) {
                int cn = tn + wn + j * 16 + lrow;
                #pragma unroll
                for (int r = 0; r < 4; ++r)
                    atomicAdd(&((float*)C)[(size_t)(cm0 + r) * D_DIM + cn], acc[i][j][r]);
            }
        }
    } else {   // EPI_F32
        #pragma unroll
        for (int i = 0; i < 4; ++i) {
            int cm0 = tm + wm + i * 16 + quad * 4;
            #pragma unroll
            for (int j = 0; j < 4; ++j) {
                int cn = tn + wn + j * 16 + lrow;
                #pragma unroll
                for (int r = 0; r < 4; ++r)
                    ((float*)C)[(size_t)(cm0 + r) * D_DIM + cn] = acc[i][j][r];
            }
        }
    }
}

// MFMA flash attention, key-split, swapped-operand QK^T (S^T layout), with the
// per-wave P tile ALIASED into the stale K double-buffer half: Ks[buf^1] holds
// the already-consumed previous tile during iteration j, so wave w parks its
// P[16][64] at rows [16w,16w+16) of it. This deletes the 9 KB Ps array ->
// LDS 36864 B -> 4 blocks/CU (was 3). Cost: a second barrier per iteration
// (next iter's staging overwrites Ks[buf^1], must wait for all P reads).
// Static-max log2-domain softmax keeps key-chunk partials purely additive.
__global__ __launch_bounds__(256, 4)
void attn_mfma(const unsigned short* Qb,
               const unsigned short* __restrict__ Kb,
               const unsigned short* __restrict__ Vtg,
               float* __restrict__ Opart, float* __restrict__ Lpart)
{
    const int bx = blockIdx.x;            // 0..79, big qt first
    int qt, c;
    if (bx < 32)      { qt = 31 - (bx >> 2);            c = bx & 3;  }  // qt 31..24: 4 chunks
    else if (bx < 56) { int i = bx - 32; qt = 23 - i/3; c = i % 3;   }  // qt 23..16: 3 chunks
    else if (bx < 72) { int i = bx - 56; qt = 15 - (i>>1); c = i & 1;}  // qt 15..8 : 2 chunks
    else              { qt = 7 - (bx - 72);             c = 0;       }  // qt 7..0  : 1 chunk
    const int jlo = c * 8;
    const int jhi = min(jlo + 7, qt);
    const int h  = blockIdx.y;
    const int t  = threadIdx.x;
    const int w  = t >> 6;
    const int l  = t & 63;
    const int l15  = l & 15;
    const int quad = l >> 4;
    const int hco  = h * 64;
    const int slot = (qt * 4 + c) * NH + h;

    __shared__ unsigned short Ks[2][64][72];    // double-buffered; stale half doubles as P
    __shared__ unsigned short Vt[2][64][72];    // Vt[buf][d][key]

    const unsigned short* qrow = Qb + (size_t)(qt * 64 + w * 16 + l15) * D_DIM + hco;
    bf16x8 qf0 = *(const bf16x8*)(qrow + quad * 8);
    bf16x8 qf1 = *(const bf16x8*)(qrow + 32 + quad * 8);

    f32x4 oac[4];
    #pragma unroll
    for (int nt = 0; nt < 4; ++nt) { f32x4 z = {0.f,0.f,0.f,0.f}; oac[nt] = z; }
    float lsum = 0.f;                    // per-lane: keys {nt*16+quad*4+r}, q = l15

    const int rr = t >> 2;          // staging row (K: key row; Vt: d row)
    const int dc = (t & 3) * 16;    // 16-col group

    const unsigned short* kbase = Kb  + (size_t)rr * D_DIM + hco + dc;
    const unsigned short* vbase = Vtg + (size_t)(hco + rr) * S_LEN + dc;

    uint4 ka0, ka1, va0, va1;
    {
        const unsigned short* kp = kbase + (size_t)jlo * 64 * D_DIM;
        const unsigned short* vp = vbase + (size_t)jlo * 64;
        ka0 = *(const uint4*)kp;  ka1 = *(const uint4*)(kp + 8);
        va0 = *(const uint4*)vp;  va1 = *(const uint4*)(vp + 8);
    }

    const int q_g = qt * 64 + w * 16 + l15;             // this lane's query row
    const float C2 = -11.541560327111707f;              // -8 * log2(e)

    for (int j = jlo; j <= jhi; ++j) {
        const int buf = (j - jlo) & 1;
        // write this tile's LDS from prefetched regs (vmcnt wait auto-inserted)
        *(uint4*)&Ks[buf][rr][dc]     = ka0;
        *(uint4*)&Ks[buf][rr][dc + 8] = ka1;
        *(uint4*)&Vt[buf][rr][dc]     = va0;
        *(uint4*)&Vt[buf][rr][dc + 8] = va1;
        __syncthreads();                       // barrier 1: tile visible
        if (j < jhi) {                         // prefetch next tile into regs
            const unsigned short* kp = kbase + (size_t)(j + 1) * 64 * D_DIM;
            const unsigned short* vp = vbase + (size_t)(j + 1) * 64;
            ka0 = *(const uint4*)kp;  ka1 = *(const uint4*)(kp + 8);
            va0 = *(const uint4*)vp;  va1 = *(const uint4*)(vp + 8);
        }

        // S^T = K Q^T (64 keys x 16 q-rows): key = nt*16 + quad*4 + reg, q = l15.
        f32x4 sac[4];
        __builtin_amdgcn_s_setprio(1);
        #pragma unroll
        for (int nt = 0; nt < 4; ++nt) {
            f32x4 z = {0.f,0.f,0.f,0.f};
            bf16x8 kf0 = *(const bf16x8*)&Ks[buf][nt * 16 + l15][quad * 8];
            z = __builtin_amdgcn_mfma_f32_16x16x32_bf16(kf0, qf0, z, 0, 0, 0);
            bf16x8 kf1 = *(const bf16x8*)&Ks[buf][nt * 16 + l15][32 + quad * 8];
            z = __builtin_amdgcn_mfma_f32_16x16x32_bf16(kf1, qf1, z, 0, 0, 0);
            sac[nt] = z;
        }
        __builtin_amdgcn_s_setprio(0);

        // wave-private P tile aliased into the STALE K buffer half
        unsigned short (*Psw)[72] = (unsigned short (*)[72])&Ks[buf ^ 1][w * 16];

        if (j < qt) {
            // bulk: no masking needed
            #pragma unroll
            for (int nt = 0; nt < 4; ++nt) {
                float pe0 = exp2f(sac[nt][0] + C2);
                float pe1 = exp2f(sac[nt][1] + C2);
                float pe2 = exp2f(sac[nt][2] + C2);
                float pe3 = exp2f(sac[nt][3] + C2);
                lsum += (pe0 + pe1) + (pe2 + pe3);
                ushort4 pk;
                pk.x = f2b_trunc(pe0); pk.y = f2b_trunc(pe1);
                pk.z = f2b_trunc(pe2); pk.w = f2b_trunc(pe3);
                *(ushort4*)&Psw[l15][nt * 16 + quad * 4] = pk;
            }
        } else {
            // diagonal tile: causal mask on key index (reg-indexed)
            #pragma unroll
            for (int nt = 0; nt < 4; ++nt) {
                int key0 = j * 64 + nt * 16 + quad * 4;
                float pe[4];
                #pragma unroll
                for (int r = 0; r < 4; ++r) {
                    float s = sac[nt][r] + C2;
                    if (key0 + r > q_g) s = NEG_BIG;
                    pe[r] = exp2f(s);
                    lsum += pe[r];
                }
                ushort4 pk;
                pk.x = f2b_trunc(pe[0]); pk.y = f2b_trunc(pe[1]);
                pk.z = f2b_trunc(pe[2]); pk.w = f2b_trunc(pe[3]);
                *(ushort4*)&Psw[l15][nt * 16 + quad * 4] = pk;
            }
        }

        // P is [q][key] in the aliased tile; read A-frag directly, then PV
        bf16x8 pf0 = *(const bf16x8*)&Psw[l15][quad * 8];
        bf16x8 pf1 = *(const bf16x8*)&Psw[l15][32 + quad * 8];
        __builtin_amdgcn_s_setprio(1);
        #pragma unroll
        for (int nt = 0; nt < 4; ++nt) {
            bf16x8 vf0 = *(const bf16x8*)&Vt[buf][nt * 16 + l15][quad * 8];
            oac[nt] = __builtin_amdgcn_mfma_f32_16x16x32_bf16(pf0, vf0, oac[nt], 0, 0, 0);
            bf16x8 vf1 = *(const bf16x8*)&Vt[buf][nt * 16 + l15][32 + quad * 8];
            oac[nt] = __builtin_amdgcn_mfma_f32_16x16x32_bf16(pf1, vf1, oac[nt], 0, 0, 0);
        }
        __builtin_amdgcn_s_setprio(0);
        __syncthreads();   // barrier 2: P reads done before next staging overwrites Ks[buf^1]
    }

    // partials: l per q-row (reduce lane-scalar across quads) + unnormalized O
    float lr = lsum;
    lr += __shfl_xor(lr, 16);
    lr += __shfl_xor(lr, 32);            // all quads now hold l[q = l15]
    if (l < 16)
        Lpart[(size_t)slot * 64 + w * 16 + l15] = lr;
    float* Op = Opart + (size_t)slot * 4096;
    #pragma unroll
    for (int nt = 0; nt < 4; ++nt)
        #pragma unroll
        for (int r = 0; r < 4; ++r)
            Op[(size_t)(w * 16 + quad * 4 + r) * 64 + nt * 16 + l15] = oac[nt][r];
}

// sum <=4 key-chunk partials, normalize, cast to bf16. Also zeroes the f32 y
// region (needed by the split-K atomic out-projection that follows).
__global__ __launch_bounds__(256)
void attn_combine(const float* __restrict__ Opart, const float* __restrict__ Lpart,
                  unsigned short* __restrict__ Ob, float* __restrict__ yzero)
{
    const int qt  = blockIdx.x;
    const int h   = blockIdx.y;
    const int t   = threadIdx.x;
    const int row = t >> 2;
    const int c0  = (t & 3) * 16;
    float acc[16];
    #pragma unroll
    for (int i = 0; i < 16; ++i) acc[i] = 0.f;
    float lsum = 0.f;
    for (int c = 0; c < 4; ++c) {
        if (c * 8 > qt) break;                        // chunks are 8 key-tiles each
        const size_t slot = (size_t)((qt * 4 + c) * NH + h);
        const float* Op = Opart + slot * 4096 + (size_t)row * 64 + c0;
        #pragma unroll
        for (int g = 0; g < 4; ++g) {
            float4 a = *(const float4*)(Op + g * 4);
            acc[g * 4 + 0] += a.x; acc[g * 4 + 1] += a.y;
            acc[g * 4 + 2] += a.z; acc[g * 4 + 3] += a.w;
        }
        lsum += Lpart[slot * 64 + row];
    }
    const float inv = 1.f / lsum;   // > 0: diagonal key always contributes
    unsigned int pk[8];
    #pragma unroll
    for (int i = 0; i < 8; ++i)
        pk[i] = f2b(acc[2 * i] * inv) | ((unsigned)f2b(acc[2 * i + 1] * inv) << 16);
    unsigned short* dst = Ob + (size_t)(qt * 64 + row) * D_DIM + h * 64 + c0;
    *(uint4*)dst       = make_uint4(pk[0], pk[1], pk[2], pk[3]);
    *(uint4*)(dst + 8) = make_uint4(pk[4], pk[5], pk[6], pk[7]);

    // zero 16 floats of y (2M floats / 131072 threads)
    const int flat = (h * 32 + qt) * 256 + t;
    float4 z4 = {0.f, 0.f, 0.f, 0.f};
    float4* yz = (float4*)(yzero + (size_t)flat * 16);
    yz[0] = z4; yz[1] = z4; yz[2] = z4; yz[3] = z4;
}

extern "C" void kernel_launch(void* const* d_in, const int* in_sizes, int n_in,
                              void* d_out, int out_size, void* d_ws, size_t ws_size,
                              hipStream_t stream)
{
    const float* x    = (const float*)d_in[0];
    const float* v1   = (const float*)d_in[1];
    const float* Wq   = (const float*)d_in[2];
    const float* Wk   = (const float*)d_in[3];
    const float* Wv   = (const float*)d_in[4];
    const float* Wout = (const float*)d_in[5];
    const float* lam  = (const float*)d_in[6];
    float* out = (float*)d_out;

    const size_t SD = (size_t)S_LEN * D_DIM;
    const size_t DD = (size_t)D_DIM * D_DIM;
    // d_ws layout (256 MB): Qb 0-4M | Kb 4-8M | Vtg 8-12M | Opart 12-44M |
    //                       Lpart 44-44.5M | xb 46-50M | Woutb 50-52M
    unsigned short* Qb  = (unsigned short*)d_ws;         // internal bf16, 4 MB
    unsigned short* Kb  = Qb + SD;                       // 4 MB
    unsigned short* Vtg = Kb + SD;                       // V transposed [D_DIM][S_LEN], 4 MB
    unsigned short* Ab  = Qb;                            // alias (attn output after combine)
    float* Opart = (float*)(Vtg + SD);                   // 2048 slots * 16 KB = 32 MB
    float* Lpart = Opart + (size_t)2048 * 4096;          // 512 KB
    unsigned short* xb    = (unsigned short*)((char*)d_ws + (46u << 20));  // 4 MB
    unsigned short* Woutb = (unsigned short*)((char*)d_ws + (50u << 20));  // 2 MB

    // bf16 weight scratch in d_out's y slot (first 6 MB of the 8 MB y region;
    // consumed by the QKV GEMM, then y is zeroed by attn_combine and re-filled
    // by the atomic out-projection). v1 slot (out+SD) receives the v1 copy
    // directly from to_bf16's z=5 branch.
    unsigned short* Wqb   = (unsigned short*)d_out;            // 2 MB
    unsigned short* Wkb   = Wqb + DD;                          // 2 MB
    unsigned short* Wvb   = Wkb + DD;                          // 2 MB

    to_bf16<<<dim3(1024, 6), 256, 0, stream>>>(
        x, Wq, Wk, Wv, Wout, v1, xb, Wqb, Wkb, Wvb, Woutb, out + SD);

    // Q/K/V projections, 64x128 tiles: 768 blocks = 3/CU balanced.
    gemm64<<<dim3(D_DIM / 128, S_LEN / 64, 3), 256, 0, stream>>>(
        xb, Wqb, Wkb, Wvb, Qb, Kb, Vtg, v1, lam,
        EPI_NORMROPE_Q | (EPI_NORMROPE << 8) | (EPI_VMIX_T << 16));

    // key-split flash attention (4 blocks/CU): fixed 8-tile chunks, partials + combine
    attn_mfma<<<dim3(80, NH), 256, 0, stream>>>(Qb, Kb, Vtg, Opart, Lpart);
    attn_combine<<<dim3(S_LEN / 64, NH), 256, 0, stream>>>(Opart, Lpart, Ab, out);

    // output projection, split-K=2 (256 blocks), atomic f32 into zeroed y
    gemm_bt<<<dim3(D_DIM / 128, S_LEN / 128, 2), 256, 0, stream>>>(
        Ab, Woutb, d_out, lam, EPI_F32A, 1);
}

// Round 5
// 170.326 us; speedup vs baseline: 1.0654x; 1.0183x over previous
//
#include <hip/hip_runtime.h>
#include <hip/hip_bf16.h>

#define S_LEN 2048
#define D_DIM 1024
#define NH    16
#define NEG_BIG (-1.0e30f)

// epilogue modes
#define EPI_NORMROPE   1   // RMSNorm + RoPE, store bf16 row-major (K)
#define EPI_VMIX_T     2   // v-mix with v1, store bf16 TRANSPOSED (V -> Vt_g[d][s])
#define EPI_F32        3   // plain f32 row-major store (out-proj)
#define EPI_NORMROPE_Q 4   // like NORMROPE but pre-scaled by 0.125*log2e (Q)

typedef __attribute__((ext_vector_type(8))) short bf16x8;
typedef __attribute__((ext_vector_type(4))) float f32x4;
typedef const __attribute__((address_space(1))) unsigned char gu8_t;
typedef __attribute__((address_space(3))) unsigned char lu8_t;

__device__ __forceinline__ float bf2f(unsigned short h) {
    union { unsigned int u; float f; } v; v.u = ((unsigned int)h) << 16; return v.f;
}
__device__ __forceinline__ unsigned short f2b(float f) {   // RNE f32->bf16 raw bits
    union { float f; unsigned int u; } v; v.f = f;
    unsigned int u = v.u;
    return (unsigned short)((u + 0x7FFFu + ((u >> 16) & 1u)) >> 16);
}
__device__ __forceinline__ unsigned short f2b_trunc(float f) {  // trunc (p>=0 only)
    union { float f; unsigned int u; } v; v.f = f;
    return (unsigned short)(v.u >> 16);
}

// one-shot f32 -> bf16 conversion of x + 4 weights, PLUS the v1 f32 passthrough
// (z=5) so the copy needs no separate dispatch.
__global__ __launch_bounds__(256)
void to_bf16(const float* __restrict__ x,  const float* __restrict__ wq,
             const float* __restrict__ wk, const float* __restrict__ wv,
             const float* __restrict__ wo, const float* __restrict__ v1,
             unsigned short* __restrict__ xb,  unsigned short* __restrict__ wqb,
             unsigned short* __restrict__ wkb, unsigned short* __restrict__ wvb,
             unsigned short* __restrict__ wob, float* __restrict__ v1dst)
{
    const int z = blockIdx.y;
    int i8 = blockIdx.x * 256 + threadIdx.x;
    if (z == 5) {           // v1 f32 passthrough: 1024*256*8 = 2M floats exactly
        const float* sp = v1 + (size_t)i8 * 8;
        float4 lo = *(const float4*)sp, hi = *(const float4*)(sp + 4);
        float* dp = v1dst + (size_t)i8 * 8;
        *(float4*)dp = lo; *(float4*)(dp + 4) = hi;
        return;
    }
    const float* s; unsigned short* d; int n;
    switch (z) {
        case 0: s = x;  d = xb;  n = S_LEN * D_DIM; break;
        case 1: s = wq; d = wqb; n = D_DIM * D_DIM; break;
        case 2: s = wk; d = wkb; n = D_DIM * D_DIM; break;
        case 3: s = wv; d = wvb; n = D_DIM * D_DIM; break;
        default: s = wo; d = wob; n = D_DIM * D_DIM; break;
    }
    if (i8 * 8 >= n) return;
    const float* sp = s + (size_t)i8 * 8;
    float4 lo = *(const float4*)sp, hi = *(const float4*)(sp + 4);
    uint4 p;
    p.x = f2b(lo.x) | ((unsigned)f2b(lo.y) << 16);
    p.y = f2b(lo.z) | ((unsigned)f2b(lo.w) << 16);
    p.z = f2b(hi.x) | ((unsigned)f2b(hi.y) << 16);
    p.w = f2b(hi.z) | ((unsigned)f2b(hi.w) << 16);
    *(uint4*)(d + (size_t)i8 * 8) = p;
}

// 64x128-tile GEMM: C = A[M,K] * B[N,K]^T.
// QKV: grid (8, 32, 3) = 768 blocks = 3/CU balanced.
// out-proj: grid (8, 32, 1) = 256 blocks balanced, EPI_F32, no atomics.
__global__ __launch_bounds__(256, 3)
void gemm64(const unsigned short* __restrict__ A,
            const unsigned short* __restrict__ B0, const unsigned short* __restrict__ B1,
            const unsigned short* __restrict__ B2,
            void* __restrict__ C0, void* __restrict__ C1, void* __restrict__ C2,
            const float* __restrict__ vmix, const float* __restrict__ lam,
            int epiPack)
{
    const int which = blockIdx.z;
    const unsigned short* Bp = (which == 0) ? B0 : ((which == 1) ? B1 : B2);
    void* C = (which == 0) ? C0 : ((which == 1) ? C1 : C2);
    const int epi = (epiPack >> (8 * which)) & 0xff;
    const int tn = blockIdx.x * 128;
    const int tm = blockIdx.y * 64;

    __shared__ unsigned short Asl[64 * 32];    // unpadded: global_load_lds contract
    __shared__ unsigned short Bsl[128 * 32];

    const int t    = threadIdx.x;
    const int lane = t & 63;
    const int wave = t >> 6;
    const int wm   = (wave >> 1) * 32;
    const int wn   = (wave & 1) * 64;
    const int lrow = lane & 15;
    const int quad = lane >> 4;
    const int srow = t >> 2;          // staging row 0..63
    const int scol = (t & 3) * 8;     // staging col group

    f32x4 acc[2][4];
    #pragma unroll
    for (int i = 0; i < 2; ++i)
        #pragma unroll
        for (int j = 0; j < 4; ++j) {
            f32x4 z = {0.f, 0.f, 0.f, 0.f};
            acc[i][j] = z;
        }

    for (int k0 = 0; k0 < D_DIM; k0 += 32) {
        __builtin_amdgcn_global_load_lds(
            (gu8_t*)(A + (size_t)(tm + srow) * D_DIM + k0 + scol),
            (lu8_t*)&Asl[t * 8], 16, 0, 0);
        __builtin_amdgcn_global_load_lds(
            (gu8_t*)(Bp + (size_t)(tn + srow) * D_DIM + k0 + scol),
            (lu8_t*)&Bsl[t * 8], 16, 0, 0);
        __builtin_amdgcn_global_load_lds(
            (gu8_t*)(Bp + (size_t)(tn + 64 + srow) * D_DIM + k0 + scol),
            (lu8_t*)&Bsl[2048 + t * 8], 16, 0, 0);
        __syncthreads();
        bf16x8 af[2], bfr[4];
        #pragma unroll
        for (int i = 0; i < 2; ++i)
            af[i] = *(const bf16x8*)(&Asl[(wm + i * 16 + lrow) * 32 + quad * 8]);
        #pragma unroll
        for (int j = 0; j < 4; ++j)
            bfr[j] = *(const bf16x8*)(&Bsl[(wn + j * 16 + lrow) * 32 + quad * 8]);
        #pragma unroll
        for (int i = 0; i < 2; ++i)
            #pragma unroll
            for (int j = 0; j < 4; ++j)
                acc[i][j] = __builtin_amdgcn_mfma_f32_16x16x32_bf16(af[i], bfr[j], acc[i][j], 0, 0, 0);
        __syncthreads();
    }

    if (epi == EPI_NORMROPE || epi == EPI_NORMROPE_Q) {
        // wave covers cols [tn+wn, tn+wn+64) = one head. RoPE pair = (v0,v2),(v1,v3).
        const float post = (epi == EPI_NORMROPE_Q) ? 0.18033688011112042f : 1.0f;
        #pragma unroll
        for (int i = 0; i < 2; ++i) {
            #pragma unroll
            for (int r = 0; r < 4; ++r) {
                int row = tm + wm + i * 16 + quad * 4 + r;   // seq position (m89/m91 C-map)
                float v0 = acc[i][0][r], v1 = acc[i][1][r];
                float v2 = acc[i][2][r], v3 = acc[i][3][r];
                float ss = v0 * v0 + v1 * v1 + v2 * v2 + v3 * v3;
                ss += __shfl_xor(ss, 1); ss += __shfl_xor(ss, 2);
                ss += __shfl_xor(ss, 4); ss += __shfl_xor(ss, 8);   // 16-lane group = full head
                float rms = rsqrtf(ss * (1.f / 64.f) + 1.1920929e-7f) * post;
                v0 *= rms; v1 *= rms; v2 *= rms; v3 *= rms;
                float fs = (float)row;
                float a0 = fs * exp2f(-0.41524101186092030f * (float)lrow);        // 10000^(-2i/64)
                float a1 = fs * exp2f(-0.41524101186092030f * (float)(16 + lrow));
                float s0, c0, s1, c1;
                __sincosf(a0, &s0, &c0);
                __sincosf(a1, &s1, &c1);
                unsigned short* Cb = (unsigned short*)C;
                size_t base = (size_t)row * D_DIM + tn + wn + lrow;
                Cb[base]      = f2b(v0 * c0 + v2 * s0);
                Cb[base + 16] = f2b(v1 * c1 + v3 * s1);
                Cb[base + 32] = f2b(-v0 * s0 + v2 * c0);
                Cb[base + 48] = f2b(-v1 * s1 + v3 * c1);
            }
        }
    } else if (epi == EPI_VMIX_T) {
        float lamf = *lam;
        #pragma unroll
        for (int i = 0; i < 2; ++i) {
            int cm0 = tm + wm + i * 16 + quad * 4;
            #pragma unroll
            for (int j = 0; j < 4; ++j) {
                int cn = tn + wn + j * 16 + lrow;
                ushort4 pk;
                float vals[4];
                #pragma unroll
                for (int r = 0; r < 4; ++r) {
                    size_t idx = (size_t)(cm0 + r) * D_DIM + cn;
                    vals[r] = (1.f - lamf) * acc[i][j][r] + lamf * vmix[idx];
                }
                pk.x = f2b(vals[0]); pk.y = f2b(vals[1]);
                pk.z = f2b(vals[2]); pk.w = f2b(vals[3]);
                *(ushort4*)((unsigned short*)C + (size_t)cn * S_LEN + cm0) = pk;
            }
        }
    } else {   // EPI_F32
        #pragma unroll
        for (int i = 0; i < 2; ++i) {
            int cm0 = tm + wm + i * 16 + quad * 4;
            #pragma unroll
            for (int j = 0; j < 4; ++j) {
                int cn = tn + wn + j * 16 + lrow;
                #pragma unroll
                for (int r = 0; r < 4; ++r)
                    ((float*)C)[(size_t)(cm0 + r) * D_DIM + cn] = acc[i][j][r];
            }
        }
    }
}

// MFMA flash attention, QBLK=128: each block covers 128 q-rows (wave = 32 rows,
// processed as two 16-row groups sequentially to bound VGPR). Staging + both
// barriers now amortize over 2x MFMA vs QBLK=64: total block-iters 8448->4352,
// K/V global traffic halved. P round-trips through the STALE double-buffer
// half (waves 0-1 alias Ks[buf^1], waves 2-3 alias Vt[buf^1]; 32 rows each).
// Key-split chunks of 8 key-tiles; static-max log2-domain softmax keeps chunk
// partials purely additive. 640 blocks < 1024 resident slots -> no queuing.
__global__ __launch_bounds__(256, 4)
void attn_mfma(const unsigned short* Qb,
               const unsigned short* __restrict__ Kb,
               const unsigned short* __restrict__ Vtg,
               float* __restrict__ Opart, float* __restrict__ Lpart)
{
    // map bx -> (qb, c): qb = 128-row q-block (0..15), chunk count ceil((2qb+2)/8),
    // big blocks dispatch first. Total bx = 40.
    const int bx = blockIdx.x;
    int qb = 0, c = 0;
    {
        int accum = 0;
        #pragma unroll
        for (int q = 15; q >= 0; --q) {
            int n = (2 * q + 9) >> 3;               // ceil((2q+2)/8)
            if (bx >= accum && bx < accum + n) { qb = q; c = bx - accum; }
            accum += n;
        }
    }
    const int jmax = 2 * qb + 1;                    // key tiles 0..jmax
    const int jlo  = c * 8;
    const int jhi  = min(jlo + 7, jmax);
    const int h  = blockIdx.y;
    const int t  = threadIdx.x;
    const int w  = t >> 6;
    const int l  = t & 63;
    const int l15  = l & 15;
    const int quad = l >> 4;
    const int hco  = h * 64;
    const int slot = (qb * 4 + c) * NH + h;         // <= 1023

    __shared__ unsigned short Ks[2][64][72];    // double-buffered; stale half = P (waves 0-1)
    __shared__ unsigned short Vt[2][64][72];    // Vt[buf][d][key]; stale half = P (waves 2-3)

    // Q fragments: rows qb*128 + w*32 + g*16 + l15
    bf16x8 qf[2][2];
    #pragma unroll
    for (int g = 0; g < 2; ++g) {
        const unsigned short* qrow =
            Qb + (size_t)(qb * 128 + w * 32 + g * 16 + l15) * D_DIM + hco;
        qf[g][0] = *(const bf16x8*)(qrow + quad * 8);
        qf[g][1] = *(const bf16x8*)(qrow + 32 + quad * 8);
    }

    f32x4 oac[2][4];
    #pragma unroll
    for (int g = 0; g < 2; ++g)
        #pragma unroll
        for (int nt = 0; nt < 4; ++nt) { f32x4 z = {0.f,0.f,0.f,0.f}; oac[g][nt] = z; }
    float lsum0 = 0.f, lsum1 = 0.f;      // per-lane: keys {nt*16+quad*4+r}, q = l15 (per group)

    const int rr = t >> 2;          // staging row (K: key row; Vt: d row)
    const int dc = (t & 3) * 16;    // 16-col group

    const unsigned short* kbase = Kb  + (size_t)rr * D_DIM + hco + dc;
    const unsigned short* vbase = Vtg + (size_t)(hco + rr) * S_LEN + dc;

    uint4 ka0, ka1, va0, va1;
    {
        const unsigned short* kp = kbase + (size_t)jlo * 64 * D_DIM;
        const unsigned short* vp = vbase + (size_t)jlo * 64;
        ka0 = *(const uint4*)kp;  ka1 = *(const uint4*)(kp + 8);
        va0 = *(const uint4*)vp;  va1 = *(const uint4*)(vp + 8);
    }

    const float C2 = -11.541560327111707f;              // -8 * log2(e)

    for (int j = jlo; j <= jhi; ++j) {
        const int buf = (j - jlo) & 1;
        // write this tile's LDS from prefetched regs (vmcnt wait auto-inserted)
        *(uint4*)&Ks[buf][rr][dc]     = ka0;
        *(uint4*)&Ks[buf][rr][dc + 8] = ka1;
        *(uint4*)&Vt[buf][rr][dc]     = va0;
        *(uint4*)&Vt[buf][rr][dc + 8] = va1;
        __syncthreads();                       // barrier 1: tile visible
        if (j < jhi) {                         // prefetch next tile into regs
            const unsigned short* kp = kbase + (size_t)(j + 1) * 64 * D_DIM;
            const unsigned short* vp = vbase + (size_t)(j + 1) * 64;
            ka0 = *(const uint4*)kp;  ka1 = *(const uint4*)(kp + 8);
            va0 = *(const uint4*)vp;  va1 = *(const uint4*)(vp + 8);
        }

        // wave-private P tile region in the STALE buffer half (32 rows/wave)
        unsigned short (*stale)[72] = (w < 2)
            ? (unsigned short (*)[72])&Ks[buf ^ 1][w * 32]
            : (unsigned short (*)[72])&Vt[buf ^ 1][(w - 2) * 32];
        const bool bulk = (j < 2 * qb);

        #pragma unroll
        for (int g = 0; g < 2; ++g) {
            // S^T = K Q^T for this 16-q group: key = nt*16+quad*4+reg, q = l15.
            f32x4 sac[4];
            __builtin_amdgcn_s_setprio(1);
            #pragma unroll
            for (int nt = 0; nt < 4; ++nt) {
                f32x4 z = {0.f,0.f,0.f,0.f};
                bf16x8 kf0 = *(const bf16x8*)&Ks[buf][nt * 16 + l15][quad * 8];
                z = __builtin_amdgcn_mfma_f32_16x16x32_bf16(kf0, qf[g][0], z, 0, 0, 0);
                bf16x8 kf1 = *(const bf16x8*)&Ks[buf][nt * 16 + l15][32 + quad * 8];
                z = __builtin_amdgcn_mfma_f32_16x16x32_bf16(kf1, qf[g][1], z, 0, 0, 0);
                sac[nt] = z;
            }
            __builtin_amdgcn_s_setprio(0);

            unsigned short (*Psw)[72] = (unsigned short (*)[72])&stale[g * 16];
            float lg = 0.f;
            if (bulk) {
                #pragma unroll
                for (int nt = 0; nt < 4; ++nt) {
                    float pe0 = exp2f(sac[nt][0] + C2);
                    float pe1 = exp2f(sac[nt][1] + C2);
                    float pe2 = exp2f(sac[nt][2] + C2);
                    float pe3 = exp2f(sac[nt][3] + C2);
                    lg += (pe0 + pe1) + (pe2 + pe3);
                    ushort4 pk;
                    pk.x = f2b_trunc(pe0); pk.y = f2b_trunc(pe1);
                    pk.z = f2b_trunc(pe2); pk.w = f2b_trunc(pe3);
                    *(ushort4*)&Psw[l15][nt * 16 + quad * 4] = pk;
                }
            } else {
                const int q_g = qb * 128 + w * 32 + g * 16 + l15;
                #pragma unroll
                for (int nt = 0; nt < 4; ++nt) {
                    int key0 = j * 64 + nt * 16 + quad * 4;
                    float pe[4];
                    #pragma unroll
                    for (int r = 0; r < 4; ++r) {
                        float s = sac[nt][r] + C2;
                        if (key0 + r > q_g) s = NEG_BIG;
                        pe[r] = exp2f(s);
                        lg += pe[r];
                    }
                    ushort4 pk;
                    pk.x = f2b_trunc(pe[0]); pk.y = f2b_trunc(pe[1]);
                    pk.z = f2b_trunc(pe[2]); pk.w = f2b_trunc(pe[3]);
                    *(ushort4*)&Psw[l15][nt * 16 + quad * 4] = pk;
                }
            }
            if (g == 0) lsum0 += lg; else lsum1 += lg;

            // PV for this group (P is wave-private: no barrier needed)
            bf16x8 pf0 = *(const bf16x8*)&Psw[l15][quad * 8];
            bf16x8 pf1 = *(const bf16x8*)&Psw[l15][32 + quad * 8];
            __builtin_amdgcn_s_setprio(1);
            #pragma unroll
            for (int nt = 0; nt < 4; ++nt) {
                bf16x8 vf0 = *(const bf16x8*)&Vt[buf][nt * 16 + l15][quad * 8];
                oac[g][nt] = __builtin_amdgcn_mfma_f32_16x16x32_bf16(pf0, vf0, oac[g][nt], 0, 0, 0);
                bf16x8 vf1 = *(const bf16x8*)&Vt[buf][nt * 16 + l15][32 + quad * 8];
                oac[g][nt] = __builtin_amdgcn_mfma_f32_16x16x32_bf16(pf1, vf1, oac[g][nt], 0, 0, 0);
            }
            __builtin_amdgcn_s_setprio(0);
        }
        __syncthreads();   // barrier 2: P reads done before next staging hits stale half
    }

    // partials: l per q-row (reduce lane-scalar across quads) + unnormalized O
    #pragma unroll
    for (int g = 0; g < 2; ++g) {
        float lr = (g == 0) ? lsum0 : lsum1;
        lr += __shfl_xor(lr, 16);
        lr += __shfl_xor(lr, 32);            // all quads hold l[q = l15]
        if (l < 16)
            Lpart[(size_t)slot * 128 + w * 32 + g * 16 + l15] = lr;
    }
    float* Op = Opart + (size_t)slot * 8192;
    #pragma unroll
    for (int g = 0; g < 2; ++g)
        #pragma unroll
        for (int nt = 0; nt < 4; ++nt)
            #pragma unroll
            for (int r = 0; r < 4; ++r)
                Op[(size_t)(w * 32 + g * 16 + quad * 4 + r) * 64 + nt * 16 + l15] = oac[g][nt][r];
}

// sum <=4 key-chunk partials, normalize, cast to bf16.
// grid (16 qb, 16 h), 256 threads: thread = (row 0..127, 32-col half).
__global__ __launch_bounds__(256)
void attn_combine(const float* __restrict__ Opart, const float* __restrict__ Lpart,
                  unsigned short* __restrict__ Ob)
{
    const int qb  = blockIdx.x;
    const int h   = blockIdx.y;
    const int t   = threadIdx.x;
    const int row = t >> 1;
    const int c0  = (t & 1) * 32;
    const int nchunks = (2 * qb + 9) >> 3;         // ceil((2qb+2)/8)
    float acc[32];
    #pragma unroll
    for (int i = 0; i < 32; ++i) acc[i] = 0.f;
    float lsum = 0.f;
    for (int c = 0; c < nchunks; ++c) {
        const size_t slot = (size_t)((qb * 4 + c) * NH + h);
        const float* Op = Opart + slot * 8192 + (size_t)row * 64 + c0;
        #pragma unroll
        for (int g = 0; g < 8; ++g) {
            float4 a = *(const float4*)(Op + g * 4);
            acc[g * 4 + 0] += a.x; acc[g * 4 + 1] += a.y;
            acc[g * 4 + 2] += a.z; acc[g * 4 + 3] += a.w;
        }
        lsum += Lpart[slot * 128 + row];
    }
    const float inv = 1.f / lsum;   // > 0: diagonal key always contributes
    unsigned int pk[16];
    #pragma unroll
    for (int i = 0; i < 16; ++i)
        pk[i] = f2b(acc[2 * i] * inv) | ((unsigned)f2b(acc[2 * i + 1] * inv) << 16);
    unsigned short* dst = Ob + (size_t)(qb * 128 + row) * D_DIM + h * 64 + c0;
    *(uint4*)dst        = make_uint4(pk[0],  pk[1],  pk[2],  pk[3]);
    *(uint4*)(dst + 8)  = make_uint4(pk[4],  pk[5],  pk[6],  pk[7]);
    *(uint4*)(dst + 16) = make_uint4(pk[8],  pk[9],  pk[10], pk[11]);
    *(uint4*)(dst + 24) = make_uint4(pk[12], pk[13], pk[14], pk[15]);
}

extern "C" void kernel_launch(void* const* d_in, const int* in_sizes, int n_in,
                              void* d_out, int out_size, void* d_ws, size_t ws_size,
                              hipStream_t stream)
{
    const float* x    = (const float*)d_in[0];
    const float* v1   = (const float*)d_in[1];
    const float* Wq   = (const float*)d_in[2];
    const float* Wk   = (const float*)d_in[3];
    const float* Wv   = (const float*)d_in[4];
    const float* Wout = (const float*)d_in[5];
    const float* lam  = (const float*)d_in[6];
    float* out = (float*)d_out;

    const size_t SD = (size_t)S_LEN * D_DIM;
    const size_t DD = (size_t)D_DIM * D_DIM;
    // d_ws layout (256 MB): Qb 0-4M | Kb 4-8M | Vtg 8-12M | Opart 12-44M |
    //                       Lpart 44-44.5M | xb 46-50M | Woutb 50-52M
    unsigned short* Qb  = (unsigned short*)d_ws;         // internal bf16, 4 MB
    unsigned short* Kb  = Qb + SD;                       // 4 MB
    unsigned short* Vtg = Kb + SD;                       // V transposed [D_DIM][S_LEN], 4 MB
    unsigned short* Ab  = Qb;                            // alias (attn output after combine)
    float* Opart = (float*)(Vtg + SD);                   // 1024 slots * 32 KB = 32 MB
    float* Lpart = Opart + (size_t)1024 * 8192;          // 512 KB
    unsigned short* xb    = (unsigned short*)((char*)d_ws + (46u << 20));  // 4 MB
    unsigned short* Woutb = (unsigned short*)((char*)d_ws + (50u << 20));  // 2 MB

    // bf16 weight scratch in d_out's y slot (first 6 MB of the 8 MB y region;
    // consumed by the QKV GEMM, then y is overwritten by the out-projection).
    // v1 slot (out+SD) is written directly by to_bf16's z=5 branch.
    unsigned short* Wqb   = (unsigned short*)d_out;            // 2 MB
    unsigned short* Wkb   = Wqb + DD;                          // 2 MB
    unsigned short* Wvb   = Wkb + DD;                          // 2 MB

    to_bf16<<<dim3(1024, 6), 256, 0, stream>>>(
        x, Wq, Wk, Wv, Wout, v1, xb, Wqb, Wkb, Wvb, Woutb, out + SD);

    // Q/K/V projections, 64x128 tiles: 768 blocks = 3/CU balanced.
    gemm64<<<dim3(D_DIM / 128, S_LEN / 64, 3), 256, 0, stream>>>(
        xb, Wqb, Wkb, Wvb, Qb, Kb, Vtg, v1, lam,
        EPI_NORMROPE_Q | (EPI_NORMROPE << 8) | (EPI_VMIX_T << 16));

    // key-split flash attention (QBLK=128, 4 blocks/CU): 640 blocks + combine
    attn_mfma<<<dim3(40, NH), 256, 0, stream>>>(Qb, Kb, Vtg, Opart, Lpart);
    attn_combine<<<dim3(S_LEN / 128, NH), 256, 0, stream>>>(Opart, Lpart, Ab);

    // output projection: same 64x128 GEMM, 256 blocks, plain f32 store
    gemm64<<<dim3(D_DIM / 128, S_LEN / 64, 1), 256, 0, stream>>>(
        Ab, Woutb, Woutb, Woutb, d_out, d_out, d_out, nullptr, lam, EPI_F32);
}

// Round 8
// 166.860 us; speedup vs baseline: 1.0875x; 1.0208x over previous
//
#include <hip/hip_runtime.h>
#include <hip/hip_bf16.h>

#define S_LEN 2048
#define D_DIM 1024
#define NH    16
#define NEG_BIG (-1.0e30f)

// epilogue modes
#define EPI_NORMROPE   1   // RMSNorm + RoPE, store bf16 row-major (K)
#define EPI_VMIX_T     2   // v-mix with v1, store bf16 TRANSPOSED (V -> Vt_g[d][s])
#define EPI_F32        3   // plain f32 row-major store
#define EPI_NORMROPE_Q 4   // like NORMROPE but pre-scaled by 0.125*log2e (Q)

typedef __attribute__((ext_vector_type(8))) short bf16x8;
typedef __attribute__((ext_vector_type(4))) float f32x4;
typedef const __attribute__((address_space(1))) unsigned char gu8_t;
typedef __attribute__((address_space(3))) unsigned char lu8_t;

__device__ __forceinline__ float bf2f(unsigned short h) {
    union { unsigned int u; float f; } v; v.u = ((unsigned int)h) << 16; return v.f;
}
__device__ __forceinline__ unsigned short f2b(float f) {   // RNE f32->bf16 raw bits
    union { float f; unsigned int u; } v; v.f = f;
    unsigned int u = v.u;
    return (unsigned short)((u + 0x7FFFu + ((u >> 16) & 1u)) >> 16);
}
__device__ __forceinline__ unsigned int pack2(float a, float b) { // trunc, p>=0
    union { float f; unsigned int u; } x, y; x.f = a; y.f = b;
    return (x.u >> 16) | (y.u & 0xFFFF0000u);
}

// one-shot f32 -> bf16 conversion of x + 4 weights, PLUS the v1 f32 passthrough.
__global__ __launch_bounds__(256)
void to_bf16(const float* __restrict__ x,  const float* __restrict__ wq,
             const float* __restrict__ wk, const float* __restrict__ wv,
             const float* __restrict__ wo, const float* __restrict__ v1,
             unsigned short* __restrict__ xb,  unsigned short* __restrict__ wqb,
             unsigned short* __restrict__ wkb, unsigned short* __restrict__ wvb,
             unsigned short* __restrict__ wob, float* __restrict__ v1dst)
{
    const int z = blockIdx.y;
    int i8 = blockIdx.x * 256 + threadIdx.x;
    if (z == 5) {           // v1 f32 passthrough: 1024*256*8 = 2M floats exactly
        const float* sp = v1 + (size_t)i8 * 8;
        float4 lo = *(const float4*)sp, hi = *(const float4*)(sp + 4);
        float* dp = v1dst + (size_t)i8 * 8;
        *(float4*)dp = lo; *(float4*)(dp + 4) = hi;
        return;
    }
    const float* s; unsigned short* d; int n;
    switch (z) {
        case 0: s = x;  d = xb;  n = S_LEN * D_DIM; break;
        case 1: s = wq; d = wqb; n = D_DIM * D_DIM; break;
        case 2: s = wk; d = wkb; n = D_DIM * D_DIM; break;
        case 3: s = wv; d = wvb; n = D_DIM * D_DIM; break;
        default: s = wo; d = wob; n = D_DIM * D_DIM; break;
    }
    if (i8 * 8 >= n) return;
    const float* sp = s + (size_t)i8 * 8;
    float4 lo = *(const float4*)sp, hi = *(const float4*)(sp + 4);
    uint4 p;
    p.x = f2b(lo.x) | ((unsigned)f2b(lo.y) << 16);
    p.y = f2b(lo.z) | ((unsigned)f2b(lo.w) << 16);
    p.z = f2b(hi.x) | ((unsigned)f2b(hi.y) << 16);
    p.w = f2b(hi.z) | ((unsigned)f2b(hi.w) << 16);
    *(uint4*)(d + (size_t)i8 * 8) = p;
}

// 64x128-tile GEMM for the QKV projections: C = A[M,K] * B[N,K]^T.
// Grid (8, 32, 3) = 768 blocks = 3/CU balanced.
__global__ __launch_bounds__(256, 3)
void gemm64(const unsigned short* __restrict__ A,
            const unsigned short* __restrict__ B0, const unsigned short* __restrict__ B1,
            const unsigned short* __restrict__ B2,
            void* __restrict__ C0, void* __restrict__ C1, void* __restrict__ C2,
            const float* __restrict__ vmix, const float* __restrict__ lam,
            int epiPack)
{
    const int which = blockIdx.z;
    const unsigned short* Bp = (which == 0) ? B0 : ((which == 1) ? B1 : B2);
    void* C = (which == 0) ? C0 : ((which == 1) ? C1 : C2);
    const int epi = (epiPack >> (8 * which)) & 0xff;
    const int tn = blockIdx.x * 128;
    const int tm = blockIdx.y * 64;

    __shared__ unsigned short Asl[64 * 32];    // unpadded: global_load_lds contract
    __shared__ unsigned short Bsl[128 * 32];

    const int t    = threadIdx.x;
    const int lane = t & 63;
    const int wave = t >> 6;
    const int wm   = (wave >> 1) * 32;
    const int wn   = (wave & 1) * 64;
    const int lrow = lane & 15;
    const int quad = lane >> 4;
    const int srow = t >> 2;          // staging row 0..63
    const int scol = (t & 3) * 8;     // staging col group

    f32x4 acc[2][4];
    #pragma unroll
    for (int i = 0; i < 2; ++i)
        #pragma unroll
        for (int j = 0; j < 4; ++j) {
            f32x4 z = {0.f, 0.f, 0.f, 0.f};
            acc[i][j] = z;
        }

    for (int k0 = 0; k0 < D_DIM; k0 += 32) {
        __builtin_amdgcn_global_load_lds(
            (gu8_t*)(A + (size_t)(tm + srow) * D_DIM + k0 + scol),
            (lu8_t*)&Asl[t * 8], 16, 0, 0);
        __builtin_amdgcn_global_load_lds(
            (gu8_t*)(Bp + (size_t)(tn + srow) * D_DIM + k0 + scol),
            (lu8_t*)&Bsl[t * 8], 16, 0, 0);
        __builtin_amdgcn_global_load_lds(
            (gu8_t*)(Bp + (size_t)(tn + 64 + srow) * D_DIM + k0 + scol),
            (lu8_t*)&Bsl[2048 + t * 8], 16, 0, 0);
        __syncthreads();
        bf16x8 af[2], bfr[4];
        #pragma unroll
        for (int i = 0; i < 2; ++i)
            af[i] = *(const bf16x8*)(&Asl[(wm + i * 16 + lrow) * 32 + quad * 8]);
        #pragma unroll
        for (int j = 0; j < 4; ++j)
            bfr[j] = *(const bf16x8*)(&Bsl[(wn + j * 16 + lrow) * 32 + quad * 8]);
        #pragma unroll
        for (int i = 0; i < 2; ++i)
            #pragma unroll
            for (int j = 0; j < 4; ++j)
                acc[i][j] = __builtin_amdgcn_mfma_f32_16x16x32_bf16(af[i], bfr[j], acc[i][j], 0, 0, 0);
        __syncthreads();
    }

    if (epi == EPI_NORMROPE || epi == EPI_NORMROPE_Q) {
        // wave covers cols [tn+wn, tn+wn+64) = one head. RoPE pair = (v0,v2),(v1,v3).
        const float post = (epi == EPI_NORMROPE_Q) ? 0.18033688011112042f : 1.0f;
        #pragma unroll
        for (int i = 0; i < 2; ++i) {
            #pragma unroll
            for (int r = 0; r < 4; ++r) {
                int row = tm + wm + i * 16 + quad * 4 + r;   // seq position (m89/m91 C-map)
                float v0 = acc[i][0][r], v1 = acc[i][1][r];
                float v2 = acc[i][2][r], v3 = acc[i][3][r];
                float ss = v0 * v0 + v1 * v1 + v2 * v2 + v3 * v3;
                ss += __shfl_xor(ss, 1); ss += __shfl_xor(ss, 2);
                ss += __shfl_xor(ss, 4); ss += __shfl_xor(ss, 8);   // 16-lane group = full head
                float rms = rsqrtf(ss * (1.f / 64.f) + 1.1920929e-7f) * post;
                v0 *= rms; v1 *= rms; v2 *= rms; v3 *= rms;
                float fs = (float)row;
                float a0 = fs * exp2f(-0.41524101186092030f * (float)lrow);        // 10000^(-2i/64)
                float a1 = fs * exp2f(-0.41524101186092030f * (float)(16 + lrow));
                float s0, c0, s1, c1;
                __sincosf(a0, &s0, &c0);
                __sincosf(a1, &s1, &c1);
                unsigned short* Cb = (unsigned short*)C;
                size_t base = (size_t)row * D_DIM + tn + wn + lrow;
                Cb[base]      = f2b(v0 * c0 + v2 * s0);
                Cb[base + 16] = f2b(v1 * c1 + v3 * s1);
                Cb[base + 32] = f2b(-v0 * s0 + v2 * c0);
                Cb[base + 48] = f2b(-v1 * s1 + v3 * c1);
            }
        }
    } else if (epi == EPI_VMIX_T) {
        float lamf = *lam;
        #pragma unroll
        for (int i = 0; i < 2; ++i) {
            int cm0 = tm + wm + i * 16 + quad * 4;
            #pragma unroll
            for (int j = 0; j < 4; ++j) {
                int cn = tn + wn + j * 16 + lrow;
                ushort4 pk;
                float vals[4];
                #pragma unroll
                for (int r = 0; r < 4; ++r) {
                    size_t idx = (size_t)(cm0 + r) * D_DIM + cn;
                    vals[r] = (1.f - lamf) * acc[i][j][r] + lamf * vmix[idx];
                }
                pk.x = f2b(vals[0]); pk.y = f2b(vals[1]);
                pk.z = f2b(vals[2]); pk.w = f2b(vals[3]);
                *(ushort4*)((unsigned short*)C + (size_t)cn * S_LEN + cm0) = pk;
            }
        }
    } else {   // EPI_F32
        #pragma unroll
        for (int i = 0; i < 2; ++i) {
            int cm0 = tm + wm + i * 16 + quad * 4;
            #pragma unroll
            for (int j = 0; j < 4; ++j) {
                int cn = tn + wn + j * 16 + lrow;
                #pragma unroll
                for (int r = 0; r < 4; ++r)
                    ((float*)C)[(size_t)(cm0 + r) * D_DIM + cn] = acc[i][j][r];
            }
        }
    }
}

// Out-projection GEMM, 64x64 tiles: grid (16, 32) = 512 blocks = 2/CU
// (the 64x128 grid gave only 256 blocks = 1 block/CU = 1 wave/SIMD: zero
// latency hiding). 4 waves 2x2, wave = 32x32, acc[2][2], f32 store.
__global__ __launch_bounds__(256, 4)
void gemm_out(const unsigned short* __restrict__ A,
              const unsigned short* __restrict__ B,
              float* __restrict__ C)
{
    const int tn = blockIdx.x * 64;
    const int tm = blockIdx.y * 64;

    __shared__ unsigned short Asl[64 * 32];
    __shared__ unsigned short Bsl[64 * 32];

    const int t    = threadIdx.x;
    const int lane = t & 63;
    const int wave = t >> 6;
    const int wm   = (wave >> 1) * 32;
    const int wn   = (wave & 1) * 32;
    const int lrow = lane & 15;
    const int quad = lane >> 4;
    const int srow = t >> 2;
    const int scol = (t & 3) * 8;

    f32x4 acc[2][2];
    #pragma unroll
    for (int i = 0; i < 2; ++i)
        #pragma unroll
        for (int j = 0; j < 2; ++j) {
            f32x4 z = {0.f, 0.f, 0.f, 0.f};
            acc[i][j] = z;
        }

    for (int k0 = 0; k0 < D_DIM; k0 += 32) {
        __builtin_amdgcn_global_load_lds(
            (gu8_t*)(A + (size_t)(tm + srow) * D_DIM + k0 + scol),
            (lu8_t*)&Asl[t * 8], 16, 0, 0);
        __builtin_amdgcn_global_load_lds(
            (gu8_t*)(B + (size_t)(tn + srow) * D_DIM + k0 + scol),
            (lu8_t*)&Bsl[t * 8], 16, 0, 0);
        __syncthreads();
        bf16x8 af[2], bfr[2];
        #pragma unroll
        for (int i = 0; i < 2; ++i)
            af[i] = *(const bf16x8*)(&Asl[(wm + i * 16 + lrow) * 32 + quad * 8]);
        #pragma unroll
        for (int j = 0; j < 2; ++j)
            bfr[j] = *(const bf16x8*)(&Bsl[(wn + j * 16 + lrow) * 32 + quad * 8]);
        #pragma unroll
        for (int i = 0; i < 2; ++i)
            #pragma unroll
            for (int j = 0; j < 2; ++j)
                acc[i][j] = __builtin_amdgcn_mfma_f32_16x16x32_bf16(af[i], bfr[j], acc[i][j], 0, 0, 0);
        __syncthreads();
    }

    #pragma unroll
    for (int i = 0; i < 2; ++i) {
        int cm0 = tm + wm + i * 16 + quad * 4;
        #pragma unroll
        for (int j = 0; j < 2; ++j) {
            int cn = tn + wn + j * 16 + lrow;
            #pragma unroll
            for (int r = 0; r < 4; ++r)
                C[(size_t)(cm0 + r) * D_DIM + cn] = acc[i][j][r];
        }
    }
}

// MFMA flash attention, QBLK=128, key-split (8-tile chunks), swapped QK^T.
// FUSED nt-loops: K-fragments and V-fragments depend only on (nt,l15,quad),
// NOT on the q-group g -> read each ONCE and feed both groups' MFMAs
// (halves kf/vf LDS reads; the kernel is LDS-issue-bound: ~36 b128-class
// ops vs ~160 MFMA cycles per wave-iter before, ~24 after).
// Softmax runs per-(g,nt) inside the QK loop so sac stays transient (VGPR).
// P parks in the STALE K/V double-buffer half (wave-private rows), barrier 2
// protects it from the next iteration's staging.
__global__ __launch_bounds__(256, 4)
void attn_mfma(const unsigned short* Qb,
               const unsigned short* __restrict__ Kb,
               const unsigned short* __restrict__ Vtg,
               float* __restrict__ Opart, float* __restrict__ Lpart)
{
    // map bx -> (qb, c): qb = 128-row q-block (0..15), chunk count ceil((2qb+2)/8),
    // big blocks dispatch first. Total bx = 40.
    const int bx = blockIdx.x;
    int qb = 0, c = 0;
    {
        int accum = 0;
        #pragma unroll
        for (int q = 15; q >= 0; --q) {
            int n = (2 * q + 9) >> 3;               // ceil((2q+2)/8)
            if (bx >= accum && bx < accum + n) { qb = q; c = bx - accum; }
            accum += n;
        }
    }
    const int jmax = 2 * qb + 1;                    // key tiles 0..jmax
    const int jlo  = c * 8;
    const int jhi  = min(jlo + 7, jmax);
    const int h  = blockIdx.y;
    const int t  = threadIdx.x;
    const int w  = t >> 6;
    const int l  = t & 63;
    const int l15  = l & 15;
    const int quad = l >> 4;
    const int hco  = h * 64;
    const int slot = (qb * 4 + c) * NH + h;         // <= 1023

    __shared__ unsigned short Ks[2][64][72];    // double-buffered; stale half = P (waves 0-1)
    __shared__ unsigned short Vt[2][64][72];    // Vt[buf][d][key]; stale half = P (waves 2-3)

    // Q fragments: rows qb*128 + w*32 + g*16 + l15
    bf16x8 qf[2][2];
    #pragma unroll
    for (int g = 0; g < 2; ++g) {
        const unsigned short* qrow =
            Qb + (size_t)(qb * 128 + w * 32 + g * 16 + l15) * D_DIM + hco;
        qf[g][0] = *(const bf16x8*)(qrow + quad * 8);
        qf[g][1] = *(const bf16x8*)(qrow + 32 + quad * 8);
    }

    f32x4 oac[2][4];
    #pragma unroll
    for (int g = 0; g < 2; ++g)
        #pragma unroll
        for (int nt = 0; nt < 4; ++nt) { f32x4 z = {0.f,0.f,0.f,0.f}; oac[g][nt] = z; }
    float lsum0 = 0.f, lsum1 = 0.f;      // per-lane: keys {nt*16+quad*4+r}, q = l15

    const int rr = t >> 2;          // staging row (K: key row; Vt: d row)
    const int dc = (t & 3) * 16;    // 16-col group

    const unsigned short* kbase = Kb  + (size_t)rr * D_DIM + hco + dc;
    const unsigned short* vbase = Vtg + (size_t)(hco + rr) * S_LEN + dc;

    uint4 ka0, ka1, va0, va1;
    {
        const unsigned short* kp = kbase + (size_t)jlo * 64 * D_DIM;
        const unsigned short* vp = vbase + (size_t)jlo * 64;
        ka0 = *(const uint4*)kp;  ka1 = *(const uint4*)(kp + 8);
        va0 = *(const uint4*)vp;  va1 = *(const uint4*)(vp + 8);
    }

    const float C2 = -11.541560327111707f;              // -8 * log2(e)

    for (int j = jlo; j <= jhi; ++j) {
        const int buf = (j - jlo) & 1;
        // write this tile's LDS from prefetched regs (vmcnt wait auto-inserted)
        *(uint4*)&Ks[buf][rr][dc]     = ka0;
        *(uint4*)&Ks[buf][rr][dc + 8] = ka1;
        *(uint4*)&Vt[buf][rr][dc]     = va0;
        *(uint4*)&Vt[buf][rr][dc + 8] = va1;
        __syncthreads();                       // barrier 1: tile visible
        if (j < jhi) {                         // prefetch next tile into regs
            const unsigned short* kp = kbase + (size_t)(j + 1) * 64 * D_DIM;
            const unsigned short* vp = vbase + (size_t)(j + 1) * 64;
            ka0 = *(const uint4*)kp;  ka1 = *(const uint4*)(kp + 8);
            va0 = *(const uint4*)vp;  va1 = *(const uint4*)(vp + 8);
        }

        // wave-private P tile region in the STALE buffer half (32 rows/wave)
        unsigned short (*stale)[72] = (w < 2)
            ? (unsigned short (*)[72])&Ks[buf ^ 1][w * 32]
            : (unsigned short (*)[72])&Vt[buf ^ 1][(w - 2) * 32];
        const bool bulk = (j < 2 * qb);

        // ---- fused QK^T + softmax: kf read ONCE per nt, used by both groups.
        // S^T layout: key = nt*16 + quad*4 + r, q = l15.
        unsigned pw[2][4][2];                  // [g][nt][word] packed bf16 key-pairs
        float ls0 = 0.f, ls1 = 0.f;
        __builtin_amdgcn_s_setprio(1);
        #pragma unroll
        for (int nt = 0; nt < 4; ++nt) {
            bf16x8 kf0 = *(const bf16x8*)&Ks[buf][nt * 16 + l15][quad * 8];
            bf16x8 kf1 = *(const bf16x8*)&Ks[buf][nt * 16 + l15][32 + quad * 8];
            #pragma unroll
            for (int g = 0; g < 2; ++g) {
                f32x4 z = {0.f,0.f,0.f,0.f};
                z = __builtin_amdgcn_mfma_f32_16x16x32_bf16(kf0, qf[g][0], z, 0, 0, 0);
                z = __builtin_amdgcn_mfma_f32_16x16x32_bf16(kf1, qf[g][1], z, 0, 0, 0);
                float pe[4];
                if (bulk) {
                    #pragma unroll
                    for (int r = 0; r < 4; ++r) pe[r] = exp2f(z[r] + C2);
                } else {
                    const int q_g  = qb * 128 + w * 32 + g * 16 + l15;
                    const int key0 = j * 64 + nt * 16 + quad * 4;
                    #pragma unroll
                    for (int r = 0; r < 4; ++r) {
                        float s = z[r] + C2;
                        if (key0 + r > q_g) s = NEG_BIG;
                        pe[r] = exp2f(s);
                    }
                }
                float psum = (pe[0] + pe[1]) + (pe[2] + pe[3]);
                if (g == 0) ls0 += psum; else ls1 += psum;
                pw[g][nt][0] = pack2(pe[0], pe[1]);
                pw[g][nt][1] = pack2(pe[2], pe[3]);
            }
        }
        __builtin_amdgcn_s_setprio(0);
        lsum0 += ls0; lsum1 += ls1;

        // park P (both groups) in the wave-private stale region
        #pragma unroll
        for (int g = 0; g < 2; ++g)
            #pragma unroll
            for (int nt = 0; nt < 4; ++nt) {
                uint2 pk; pk.x = pw[g][nt][0]; pk.y = pw[g][nt][1];
                *(uint2*)&stale[g * 16 + l15][nt * 16 + quad * 4] = pk;
            }

        // P A-fragments (C-layout -> A-layout via the LDS hop)
        bf16x8 pf[2][2];
        #pragma unroll
        for (int g = 0; g < 2; ++g) {
            pf[g][0] = *(const bf16x8*)&stale[g * 16 + l15][quad * 8];
            pf[g][1] = *(const bf16x8*)&stale[g * 16 + l15][32 + quad * 8];
        }

        // ---- fused PV: vf read ONCE per nt, used by both groups.
        __builtin_amdgcn_s_setprio(1);
        #pragma unroll
        for (int nt = 0; nt < 4; ++nt) {
            bf16x8 vf0 = *(const bf16x8*)&Vt[buf][nt * 16 + l15][quad * 8];
            bf16x8 vf1 = *(const bf16x8*)&Vt[buf][nt * 16 + l15][32 + quad * 8];
            oac[0][nt] = __builtin_amdgcn_mfma_f32_16x16x32_bf16(pf[0][0], vf0, oac[0][nt], 0, 0, 0);
            oac[0][nt] = __builtin_amdgcn_mfma_f32_16x16x32_bf16(pf[0][1], vf1, oac[0][nt], 0, 0, 0);
            oac[1][nt] = __builtin_amdgcn_mfma_f32_16x16x32_bf16(pf[1][0], vf0, oac[1][nt], 0, 0, 0);
            oac[1][nt] = __builtin_amdgcn_mfma_f32_16x16x32_bf16(pf[1][1], vf1, oac[1][nt], 0, 0, 0);
        }
        __builtin_amdgcn_s_setprio(0);
        __syncthreads();   // barrier 2: P reads done before next staging hits stale half
    }

    // partials: l per q-row (reduce lane-scalar across quads) + unnormalized O
    #pragma unroll
    for (int g = 0; g < 2; ++g) {
        float lr = (g == 0) ? lsum0 : lsum1;
        lr += __shfl_xor(lr, 16);
        lr += __shfl_xor(lr, 32);            // all quads hold l[q = l15]
        if (l < 16)
            Lpart[(size_t)slot * 128 + w * 32 + g * 16 + l15] = lr;
    }
    float* Op = Opart + (size_t)slot * 8192;
    #pragma unroll
    for (int g = 0; g < 2; ++g)
        #pragma unroll
        for (int nt = 0; nt < 4; ++nt)
            #pragma unroll
            for (int r = 0; r < 4; ++r)
                Op[(size_t)(w * 32 + g * 16 + quad * 4 + r) * 64 + nt * 16 + l15] = oac[g][nt][r];
}

// sum <=4 key-chunk partials, normalize, cast to bf16.
// grid (16 qb, 16 h), 256 threads: thread = (row 0..127, 32-col half).
__global__ __launch_bounds__(256)
void attn_combine(const float* __restrict__ Opart, const float* __restrict__ Lpart,
                  unsigned short* __restrict__ Ob)
{
    const int qb  = blockIdx.x;
    const int h   = blockIdx.y;
    const int t   = threadIdx.x;
    const int row = t >> 1;
    const int c0  = (t & 1) * 32;
    const int nchunks = (2 * qb + 9) >> 3;         // ceil((2qb+2)/8)
    float acc[32];
    #pragma unroll
    for (int i = 0; i < 32; ++i) acc[i] = 0.f;
    float lsum = 0.f;
    for (int c = 0; c < nchunks; ++c) {
        const size_t slot = (size_t)((qb * 4 + c) * NH + h);
        const float* Op = Opart + slot * 8192 + (size_t)row * 64 + c0;
        #pragma unroll
        for (int g = 0; g < 8; ++g) {
            float4 a = *(const float4*)(Op + g * 4);
            acc[g * 4 + 0] += a.x; acc[g * 4 + 1] += a.y;
            acc[g * 4 + 2] += a.z; acc[g * 4 + 3] += a.w;
        }
        lsum += Lpart[slot * 128 + row];
    }
    const float inv = 1.f / lsum;   // > 0: diagonal key always contributes
    unsigned int pk[16];
    #pragma unroll
    for (int i = 0; i < 16; ++i)
        pk[i] = f2b(acc[2 * i] * inv) | ((unsigned)f2b(acc[2 * i + 1] * inv) << 16);
    unsigned short* dst = Ob + (size_t)(qb * 128 + row) * D_DIM + h * 64 + c0;
    *(uint4*)dst        = make_uint4(pk[0],  pk[1],  pk[2],  pk[3]);
    *(uint4*)(dst + 8)  = make_uint4(pk[4],  pk[5],  pk[6],  pk[7]);
    *(uint4*)(dst + 16) = make_uint4(pk[8],  pk[9],  pk[10], pk[11]);
    *(uint4*)(dst + 24) = make_uint4(pk[12], pk[13], pk[14], pk[15]);
}

extern "C" void kernel_launch(void* const* d_in, const int* in_sizes, int n_in,
                              void* d_out, int out_size, void* d_ws, size_t ws_size,
                              hipStream_t stream)
{
    const float* x    = (const float*)d_in[0];
    const float* v1   = (const float*)d_in[1];
    const float* Wq   = (const float*)d_in[2];
    const float* Wk   = (const float*)d_in[3];
    const float* Wv   = (const float*)d_in[4];
    const float* Wout = (const float*)d_in[5];
    const float* lam  = (const float*)d_in[6];
    float* out = (float*)d_out;

    const size_t SD = (size_t)S_LEN * D_DIM;
    const size_t DD = (size_t)D_DIM * D_DIM;
    // d_ws layout (256 MB): Qb 0-4M | Kb 4-8M | Vtg 8-12M | Opart 12-44M |
    //                       Lpart 44-44.5M | xb 46-50M | Woutb 50-52M
    unsigned short* Qb  = (unsigned short*)d_ws;         // internal bf16, 4 MB
    unsigned short* Kb  = Qb + SD;                       // 4 MB
    unsigned short* Vtg = Kb + SD;                       // V transposed [D_DIM][S_LEN], 4 MB
    unsigned short* Ab  = Qb;                            // alias (attn output after combine)
    float* Opart = (float*)(Vtg + SD);                   // 1024 slots * 32 KB = 32 MB
    float* Lpart = Opart + (size_t)1024 * 8192;          // 512 KB
    unsigned short* xb    = (unsigned short*)((char*)d_ws + (46u << 20));  // 4 MB
    unsigned short* Woutb = (unsigned short*)((char*)d_ws + (50u << 20));  // 2 MB

    // bf16 weight scratch in d_out's y slot (first 6 MB of the 8 MB y region;
    // consumed by the QKV GEMM, then y is overwritten by the out-projection).
    // v1 slot (out+SD) is written directly by to_bf16's z=5 branch.
    unsigned short* Wqb   = (unsigned short*)d_out;            // 2 MB
    unsigned short* Wkb   = Wqb + DD;                          // 2 MB
    unsigned short* Wvb   = Wkb + DD;                          // 2 MB

    to_bf16<<<dim3(1024, 6), 256, 0, stream>>>(
        x, Wq, Wk, Wv, Wout, v1, xb, Wqb, Wkb, Wvb, Woutb, out + SD);

    // Q/K/V projections, 64x128 tiles: 768 blocks = 3/CU balanced.
    gemm64<<<dim3(D_DIM / 128, S_LEN / 64, 3), 256, 0, stream>>>(
        xb, Wqb, Wkb, Wvb, Qb, Kb, Vtg, v1, lam,
        EPI_NORMROPE_Q | (EPI_NORMROPE << 8) | (EPI_VMIX_T << 16));

    // key-split flash attention (QBLK=128, fused nt-loops, 4 blocks/CU)
    attn_mfma<<<dim3(40, NH), 256, 0, stream>>>(Qb, Kb, Vtg, Opart, Lpart);
    attn_combine<<<dim3(S_LEN / 128, NH), 256, 0, stream>>>(Opart, Lpart, Ab);

    // output projection: 64x64 tiles, 512 blocks = 2/CU, plain f32 store
    gemm_out<<<dim3(D_DIM / 64, S_LEN / 64), 256, 0, stream>>>(Ab, Woutb, out);
}

// Round 9
// 166.141 us; speedup vs baseline: 1.0922x; 1.0043x over previous
//
#include <hip/hip_runtime.h>
#include <hip/hip_bf16.h>

#define S_LEN 2048
#define D_DIM 1024
#define NH    16
#define NEG_BIG (-1.0e30f)

// epilogue modes
#define EPI_NORMROPE   1   // RMSNorm + RoPE, store bf16 row-major (K)
#define EPI_VMIX_T     2   // v-mix with v1, store bf16 TRANSPOSED (V -> Vt_g[d][s])
#define EPI_F32        3   // plain f32 row-major store
#define EPI_NORMROPE_Q 4   // like NORMROPE but pre-scaled by 0.125*log2e (Q)

typedef __attribute__((ext_vector_type(8))) short bf16x8;
typedef __attribute__((ext_vector_type(4))) float f32x4;
typedef const __attribute__((address_space(1))) unsigned char gu8_t;
typedef __attribute__((address_space(3))) unsigned char lu8_t;

__device__ __forceinline__ float bf2f(unsigned short h) {
    union { unsigned int u; float f; } v; v.u = ((unsigned int)h) << 16; return v.f;
}
__device__ __forceinline__ unsigned short f2b(float f) {   // RNE f32->bf16 raw bits
    union { float f; unsigned int u; } v; v.f = f;
    unsigned int u = v.u;
    return (unsigned short)((u + 0x7FFFu + ((u >> 16) & 1u)) >> 16);
}
__device__ __forceinline__ unsigned int pack2(float a, float b) { // trunc, p>=0
    union { float f; unsigned int u; } x, y; x.f = a; y.f = b;
    return (x.u >> 16) | (y.u & 0xFFFF0000u);
}

// one-shot f32 -> bf16 conversion of x + 4 weights, PLUS the v1 f32 passthrough.
__global__ __launch_bounds__(256)
void to_bf16(const float* __restrict__ x,  const float* __restrict__ wq,
             const float* __restrict__ wk, const float* __restrict__ wv,
             const float* __restrict__ wo, const float* __restrict__ v1,
             unsigned short* __restrict__ xb,  unsigned short* __restrict__ wqb,
             unsigned short* __restrict__ wkb, unsigned short* __restrict__ wvb,
             unsigned short* __restrict__ wob, float* __restrict__ v1dst)
{
    const int z = blockIdx.y;
    int i8 = blockIdx.x * 256 + threadIdx.x;
    if (z == 5) {           // v1 f32 passthrough: 1024*256*8 = 2M floats exactly
        const float* sp = v1 + (size_t)i8 * 8;
        float4 lo = *(const float4*)sp, hi = *(const float4*)(sp + 4);
        float* dp = v1dst + (size_t)i8 * 8;
        *(float4*)dp = lo; *(float4*)(dp + 4) = hi;
        return;
    }
    const float* s; unsigned short* d; int n;
    switch (z) {
        case 0: s = x;  d = xb;  n = S_LEN * D_DIM; break;
        case 1: s = wq; d = wqb; n = D_DIM * D_DIM; break;
        case 2: s = wk; d = wkb; n = D_DIM * D_DIM; break;
        case 3: s = wv; d = wvb; n = D_DIM * D_DIM; break;
        default: s = wo; d = wob; n = D_DIM * D_DIM; break;
    }
    if (i8 * 8 >= n) return;
    const float* sp = s + (size_t)i8 * 8;
    float4 lo = *(const float4*)sp, hi = *(const float4*)(sp + 4);
    uint4 p;
    p.x = f2b(lo.x) | ((unsigned)f2b(lo.y) << 16);
    p.y = f2b(lo.z) | ((unsigned)f2b(lo.w) << 16);
    p.z = f2b(hi.x) | ((unsigned)f2b(hi.y) << 16);
    p.w = f2b(hi.z) | ((unsigned)f2b(hi.w) << 16);
    *(uint4*)(d + (size_t)i8 * 8) = p;
}

// 64x128-tile GEMM for the QKV projections: C = A[M,K] * B[N,K]^T.
// Grid (8, 32, 3) = 768 blocks = 3/CU balanced.
// K_STEP=64 staged as TWO 32-col panels per barrier ([2][rows][32] LDS keeps
// the bank-friendly 64 B row stride; a [rows][64] layout would be a 16-way
// conflict). Halves the s_waitcnt-vmcnt(0)+s_barrier drain pairs (32 -> 16).
__global__ __launch_bounds__(256, 3)
void gemm64(const unsigned short* __restrict__ A,
            const unsigned short* __restrict__ B0, const unsigned short* __restrict__ B1,
            const unsigned short* __restrict__ B2,
            void* __restrict__ C0, void* __restrict__ C1, void* __restrict__ C2,
            const float* __restrict__ vmix, const float* __restrict__ lam,
            int epiPack)
{
    const int which = blockIdx.z;
    const unsigned short* Bp = (which == 0) ? B0 : ((which == 1) ? B1 : B2);
    void* C = (which == 0) ? C0 : ((which == 1) ? C1 : C2);
    const int epi = (epiPack >> (8 * which)) & 0xff;
    const int tn = blockIdx.x * 128;
    const int tm = blockIdx.y * 64;

    __shared__ unsigned short Asl[2][64 * 32];    // [panel][row*32+col]
    __shared__ unsigned short Bsl[2][128 * 32];

    const int t    = threadIdx.x;
    const int lane = t & 63;
    const int wave = t >> 6;
    const int wm   = (wave >> 1) * 32;
    const int wn   = (wave & 1) * 64;
    const int lrow = lane & 15;
    const int quad = lane >> 4;
    const int srow = t >> 2;          // staging row 0..63
    const int scol = (t & 3) * 8;     // staging col group

    f32x4 acc[2][4];
    #pragma unroll
    for (int i = 0; i < 2; ++i)
        #pragma unroll
        for (int j = 0; j < 4; ++j) {
            f32x4 z = {0.f, 0.f, 0.f, 0.f};
            acc[i][j] = z;
        }

    for (int k0 = 0; k0 < D_DIM; k0 += 64) {
        #pragma unroll
        for (int ks = 0; ks < 2; ++ks) {
            const int kc = k0 + ks * 32 + scol;
            __builtin_amdgcn_global_load_lds(
                (gu8_t*)(A + (size_t)(tm + srow) * D_DIM + kc),
                (lu8_t*)&Asl[ks][t * 8], 16, 0, 0);
            __builtin_amdgcn_global_load_lds(
                (gu8_t*)(Bp + (size_t)(tn + srow) * D_DIM + kc),
                (lu8_t*)&Bsl[ks][t * 8], 16, 0, 0);
            __builtin_amdgcn_global_load_lds(
                (gu8_t*)(Bp + (size_t)(tn + 64 + srow) * D_DIM + kc),
                (lu8_t*)&Bsl[ks][2048 + t * 8], 16, 0, 0);
        }
        __syncthreads();
        #pragma unroll
        for (int ks = 0; ks < 2; ++ks) {
            bf16x8 af[2], bfr[4];
            #pragma unroll
            for (int i = 0; i < 2; ++i)
                af[i] = *(const bf16x8*)(&Asl[ks][(wm + i * 16 + lrow) * 32 + quad * 8]);
            #pragma unroll
            for (int j = 0; j < 4; ++j)
                bfr[j] = *(const bf16x8*)(&Bsl[ks][(wn + j * 16 + lrow) * 32 + quad * 8]);
            #pragma unroll
            for (int i = 0; i < 2; ++i)
                #pragma unroll
                for (int j = 0; j < 4; ++j)
                    acc[i][j] = __builtin_amdgcn_mfma_f32_16x16x32_bf16(af[i], bfr[j], acc[i][j], 0, 0, 0);
        }
        __syncthreads();
    }

    if (epi == EPI_NORMROPE || epi == EPI_NORMROPE_Q) {
        // wave covers cols [tn+wn, tn+wn+64) = one head. RoPE pair = (v0,v2),(v1,v3).
        const float post = (epi == EPI_NORMROPE_Q) ? 0.18033688011112042f : 1.0f;
        #pragma unroll
        for (int i = 0; i < 2; ++i) {
            #pragma unroll
            for (int r = 0; r < 4; ++r) {
                int row = tm + wm + i * 16 + quad * 4 + r;   // seq position (m89/m91 C-map)
                float v0 = acc[i][0][r], v1 = acc[i][1][r];
                float v2 = acc[i][2][r], v3 = acc[i][3][r];
                float ss = v0 * v0 + v1 * v1 + v2 * v2 + v3 * v3;
                ss += __shfl_xor(ss, 1); ss += __shfl_xor(ss, 2);
                ss += __shfl_xor(ss, 4); ss += __shfl_xor(ss, 8);   // 16-lane group = full head
                float rms = rsqrtf(ss * (1.f / 64.f) + 1.1920929e-7f) * post;
                v0 *= rms; v1 *= rms; v2 *= rms; v3 *= rms;
                float fs = (float)row;
                float a0 = fs * exp2f(-0.41524101186092030f * (float)lrow);        // 10000^(-2i/64)
                float a1 = fs * exp2f(-0.41524101186092030f * (float)(16 + lrow));
                float s0, c0, s1, c1;
                __sincosf(a0, &s0, &c0);
                __sincosf(a1, &s1, &c1);
                unsigned short* Cb = (unsigned short*)C;
                size_t base = (size_t)row * D_DIM + tn + wn + lrow;
                Cb[base]      = f2b(v0 * c0 + v2 * s0);
                Cb[base + 16] = f2b(v1 * c1 + v3 * s1);
                Cb[base + 32] = f2b(-v0 * s0 + v2 * c0);
                Cb[base + 48] = f2b(-v1 * s1 + v3 * c1);
            }
        }
    } else if (epi == EPI_VMIX_T) {
        float lamf = *lam;
        #pragma unroll
        for (int i = 0; i < 2; ++i) {
            int cm0 = tm + wm + i * 16 + quad * 4;
            #pragma unroll
            for (int j = 0; j < 4; ++j) {
                int cn = tn + wn + j * 16 + lrow;
                ushort4 pk;
                float vals[4];
                #pragma unroll
                for (int r = 0; r < 4; ++r) {
                    size_t idx = (size_t)(cm0 + r) * D_DIM + cn;
                    vals[r] = (1.f - lamf) * acc[i][j][r] + lamf * vmix[idx];
                }
                pk.x = f2b(vals[0]); pk.y = f2b(vals[1]);
                pk.z = f2b(vals[2]); pk.w = f2b(vals[3]);
                *(ushort4*)((unsigned short*)C + (size_t)cn * S_LEN + cm0) = pk;
            }
        }
    } else {   // EPI_F32
        #pragma unroll
        for (int i = 0; i < 2; ++i) {
            int cm0 = tm + wm + i * 16 + quad * 4;
            #pragma unroll
            for (int j = 0; j < 4; ++j) {
                int cn = tn + wn + j * 16 + lrow;
                #pragma unroll
                for (int r = 0; r < 4; ++r)
                    ((float*)C)[(size_t)(cm0 + r) * D_DIM + cn] = acc[i][j][r];
            }
        }
    }
}

// Out-projection GEMM, 64x64 tiles, K_STEP=64 (two 32-col panels/barrier):
// grid (16, 32) = 512 blocks = 2/CU. 4 waves 2x2, wave = 32x32, acc[2][2].
__global__ __launch_bounds__(256, 4)
void gemm_out(const unsigned short* __restrict__ A,
              const unsigned short* __restrict__ B,
              float* __restrict__ C)
{
    const int tn = blockIdx.x * 64;
    const int tm = blockIdx.y * 64;

    __shared__ unsigned short Asl[2][64 * 32];
    __shared__ unsigned short Bsl[2][64 * 32];

    const int t    = threadIdx.x;
    const int lane = t & 63;
    const int wave = t >> 6;
    const int wm   = (wave >> 1) * 32;
    const int wn   = (wave & 1) * 32;
    const int lrow = lane & 15;
    const int quad = lane >> 4;
    const int srow = t >> 2;
    const int scol = (t & 3) * 8;

    f32x4 acc[2][2];
    #pragma unroll
    for (int i = 0; i < 2; ++i)
        #pragma unroll
        for (int j = 0; j < 2; ++j) {
            f32x4 z = {0.f, 0.f, 0.f, 0.f};
            acc[i][j] = z;
        }

    for (int k0 = 0; k0 < D_DIM; k0 += 64) {
        #pragma unroll
        for (int ks = 0; ks < 2; ++ks) {
            const int kc = k0 + ks * 32 + scol;
            __builtin_amdgcn_global_load_lds(
                (gu8_t*)(A + (size_t)(tm + srow) * D_DIM + kc),
                (lu8_t*)&Asl[ks][t * 8], 16, 0, 0);
            __builtin_amdgcn_global_load_lds(
                (gu8_t*)(B + (size_t)(tn + srow) * D_DIM + kc),
                (lu8_t*)&Bsl[ks][t * 8], 16, 0, 0);
        }
        __syncthreads();
        #pragma unroll
        for (int ks = 0; ks < 2; ++ks) {
            bf16x8 af[2], bfr[2];
            #pragma unroll
            for (int i = 0; i < 2; ++i)
                af[i] = *(const bf16x8*)(&Asl[ks][(wm + i * 16 + lrow) * 32 + quad * 8]);
            #pragma unroll
            for (int j = 0; j < 2; ++j)
                bfr[j] = *(const bf16x8*)(&Bsl[ks][(wn + j * 16 + lrow) * 32 + quad * 8]);
            #pragma unroll
            for (int i = 0; i < 2; ++i)
                #pragma unroll
                for (int j = 0; j < 2; ++j)
                    acc[i][j] = __builtin_amdgcn_mfma_f32_16x16x32_bf16(af[i], bfr[j], acc[i][j], 0, 0, 0);
        }
        __syncthreads();
    }

    #pragma unroll
    for (int i = 0; i < 2; ++i) {
        int cm0 = tm + wm + i * 16 + quad * 4;
        #pragma unroll
        for (int j = 0; j < 2; ++j) {
            int cn = tn + wn + j * 16 + lrow;
            #pragma unroll
            for (int r = 0; r < 4; ++r)
                C[(size_t)(cm0 + r) * D_DIM + cn] = acc[i][j][r];
        }
    }
}

// MFMA flash attention, QBLK=128, key-split (8-tile chunks), swapped QK^T,
// fused nt-loops (kf/vf read once, feed both q-groups), P parked in the stale
// double-buffer half. Unchanged from round 8 (validated at 166.9 us).
__global__ __launch_bounds__(256, 4)
void attn_mfma(const unsigned short* Qb,
               const unsigned short* __restrict__ Kb,
               const unsigned short* __restrict__ Vtg,
               float* __restrict__ Opart, float* __restrict__ Lpart)
{
    // map bx -> (qb, c): qb = 128-row q-block (0..15), chunk count ceil((2qb+2)/8),
    // big blocks dispatch first. Total bx = 40.
    const int bx = blockIdx.x;
    int qb = 0, c = 0;
    {
        int accum = 0;
        #pragma unroll
        for (int q = 15; q >= 0; --q) {
            int n = (2 * q + 9) >> 3;               // ceil((2q+2)/8)
            if (bx >= accum && bx < accum + n) { qb = q; c = bx - accum; }
            accum += n;
        }
    }
    const int jmax = 2 * qb + 1;                    // key tiles 0..jmax
    const int jlo  = c * 8;
    const int jhi  = min(jlo + 7, jmax);
    const int h  = blockIdx.y;
    const int t  = threadIdx.x;
    const int w  = t >> 6;
    const int l  = t & 63;
    const int l15  = l & 15;
    const int quad = l >> 4;
    const int hco  = h * 64;
    const int slot = (qb * 4 + c) * NH + h;         // <= 1023

    __shared__ unsigned short Ks[2][64][72];    // double-buffered; stale half = P (waves 0-1)
    __shared__ unsigned short Vt[2][64][72];    // Vt[buf][d][key]; stale half = P (waves 2-3)

    // Q fragments: rows qb*128 + w*32 + g*16 + l15
    bf16x8 qf[2][2];
    #pragma unroll
    for (int g = 0; g < 2; ++g) {
        const unsigned short* qrow =
            Qb + (size_t)(qb * 128 + w * 32 + g * 16 + l15) * D_DIM + hco;
        qf[g][0] = *(const bf16x8*)(qrow + quad * 8);
        qf[g][1] = *(const bf16x8*)(qrow + 32 + quad * 8);
    }

    f32x4 oac[2][4];
    #pragma unroll
    for (int g = 0; g < 2; ++g)
        #pragma unroll
        for (int nt = 0; nt < 4; ++nt) { f32x4 z = {0.f,0.f,0.f,0.f}; oac[g][nt] = z; }
    float lsum0 = 0.f, lsum1 = 0.f;      // per-lane: keys {nt*16+quad*4+r}, q = l15

    const int rr = t >> 2;          // staging row (K: key row; Vt: d row)
    const int dc = (t & 3) * 16;    // 16-col group

    const unsigned short* kbase = Kb  + (size_t)rr * D_DIM + hco + dc;
    const unsigned short* vbase = Vtg + (size_t)(hco + rr) * S_LEN + dc;

    uint4 ka0, ka1, va0, va1;
    {
        const unsigned short* kp = kbase + (size_t)jlo * 64 * D_DIM;
        const unsigned short* vp = vbase + (size_t)jlo * 64;
        ka0 = *(const uint4*)kp;  ka1 = *(const uint4*)(kp + 8);
        va0 = *(const uint4*)vp;  va1 = *(const uint4*)(vp + 8);
    }

    const float C2 = -11.541560327111707f;              // -8 * log2(e)

    for (int j = jlo; j <= jhi; ++j) {
        const int buf = (j - jlo) & 1;
        // write this tile's LDS from prefetched regs (vmcnt wait auto-inserted)
        *(uint4*)&Ks[buf][rr][dc]     = ka0;
        *(uint4*)&Ks[buf][rr][dc + 8] = ka1;
        *(uint4*)&Vt[buf][rr][dc]     = va0;
        *(uint4*)&Vt[buf][rr][dc + 8] = va1;
        __syncthreads();                       // barrier 1: tile visible
        if (j < jhi) {                         // prefetch next tile into regs
            const unsigned short* kp = kbase + (size_t)(j + 1) * 64 * D_DIM;
            const unsigned short* vp = vbase + (size_t)(j + 1) * 64;
            ka0 = *(const uint4*)kp;  ka1 = *(const uint4*)(kp + 8);
            va0 = *(const uint4*)vp;  va1 = *(const uint4*)(vp + 8);
        }

        // wave-private P tile region in the STALE buffer half (32 rows/wave)
        unsigned short (*stale)[72] = (w < 2)
            ? (unsigned short (*)[72])&Ks[buf ^ 1][w * 32]
            : (unsigned short (*)[72])&Vt[buf ^ 1][(w - 2) * 32];
        const bool bulk = (j < 2 * qb);

        // ---- fused QK^T + softmax: kf read ONCE per nt, used by both groups.
        // S^T layout: key = nt*16 + quad*4 + r, q = l15.
        unsigned pw[2][4][2];                  // [g][nt][word] packed bf16 key-pairs
        float ls0 = 0.f, ls1 = 0.f;
        __builtin_amdgcn_s_setprio(1);
        #pragma unroll
        for (int nt = 0; nt < 4; ++nt) {
            bf16x8 kf0 = *(const bf16x8*)&Ks[buf][nt * 16 + l15][quad * 8];
            bf16x8 kf1 = *(const bf16x8*)&Ks[buf][nt * 16 + l15][32 + quad * 8];
            #pragma unroll
            for (int g = 0; g < 2; ++g) {
                f32x4 z = {0.f,0.f,0.f,0.f};
                z = __builtin_amdgcn_mfma_f32_16x16x32_bf16(kf0, qf[g][0], z, 0, 0, 0);
                z = __builtin_amdgcn_mfma_f32_16x16x32_bf16(kf1, qf[g][1], z, 0, 0, 0);
                float pe[4];
                if (bulk) {
                    #pragma unroll
                    for (int r = 0; r < 4; ++r) pe[r] = exp2f(z[r] + C2);
                } else {
                    const int q_g  = qb * 128 + w * 32 + g * 16 + l15;
                    const int key0 = j * 64 + nt * 16 + quad * 4;
                    #pragma unroll
                    for (int r = 0; r < 4; ++r) {
                        float s = z[r] + C2;
                        if (key0 + r > q_g) s = NEG_BIG;
                        pe[r] = exp2f(s);
                    }
                }
                float psum = (pe[0] + pe[1]) + (pe[2] + pe[3]);
                if (g == 0) ls0 += psum; else ls1 += psum;
                pw[g][nt][0] = pack2(pe[0], pe[1]);
                pw[g][nt][1] = pack2(pe[2], pe[3]);
            }
        }
        __builtin_amdgcn_s_setprio(0);
        lsum0 += ls0; lsum1 += ls1;

        // park P (both groups) in the wave-private stale region
        #pragma unroll
        for (int g = 0; g < 2; ++g)
            #pragma unroll
            for (int nt = 0; nt < 4; ++nt) {
                uint2 pk; pk.x = pw[g][nt][0]; pk.y = pw[g][nt][1];
                *(uint2*)&stale[g * 16 + l15][nt * 16 + quad * 4] = pk;
            }

        // P A-fragments (C-layout -> A-layout via the LDS hop)
        bf16x8 pf[2][2];
        #pragma unroll
        for (int g = 0; g < 2; ++g) {
            pf[g][0] = *(const bf16x8*)&stale[g * 16 + l15][quad * 8];
            pf[g][1] = *(const bf16x8*)&stale[g * 16 + l15][32 + quad * 8];
        }

        // ---- fused PV: vf read ONCE per nt, used by both groups.
        __builtin_amdgcn_s_setprio(1);
        #pragma unroll
        for (int nt = 0; nt < 4; ++nt) {
            bf16x8 vf0 = *(const bf16x8*)&Vt[buf][nt * 16 + l15][quad * 8];
            bf16x8 vf1 = *(const bf16x8*)&Vt[buf][nt * 16 + l15][32 + quad * 8];
            oac[0][nt] = __builtin_amdgcn_mfma_f32_16x16x32_bf16(pf[0][0], vf0, oac[0][nt], 0, 0, 0);
            oac[0][nt] = __builtin_amdgcn_mfma_f32_16x16x32_bf16(pf[0][1], vf1, oac[0][nt], 0, 0, 0);
            oac[1][nt] = __builtin_amdgcn_mfma_f32_16x16x32_bf16(pf[1][0], vf0, oac[1][nt], 0, 0, 0);
            oac[1][nt] = __builtin_amdgcn_mfma_f32_16x16x32_bf16(pf[1][1], vf1, oac[1][nt], 0, 0, 0);
        }
        __builtin_amdgcn_s_setprio(0);
        __syncthreads();   // barrier 2: P reads done before next staging hits stale half
    }

    // partials: l per q-row (reduce lane-scalar across quads) + unnormalized O
    #pragma unroll
    for (int g = 0; g < 2; ++g) {
        float lr = (g == 0) ? lsum0 : lsum1;
        lr += __shfl_xor(lr, 16);
        lr += __shfl_xor(lr, 32);            // all quads hold l[q = l15]
        if (l < 16)
            Lpart[(size_t)slot * 128 + w * 32 + g * 16 + l15] = lr;
    }
    float* Op = Opart + (size_t)slot * 8192;
    #pragma unroll
    for (int g = 0; g < 2; ++g)
        #pragma unroll
        for (int nt = 0; nt < 4; ++nt)
            #pragma unroll
            for (int r = 0; r < 4; ++r)
                Op[(size_t)(w * 32 + g * 16 + quad * 4 + r) * 64 + nt * 16 + l15] = oac[g][nt][r];
}

// sum <=4 key-chunk partials, normalize, cast to bf16.
// grid (16 qb, 16 h), 256 threads: thread = (row 0..127, 32-col half).
__global__ __launch_bounds__(256)
void attn_combine(const float* __restrict__ Opart, const float* __restrict__ Lpart,
                  unsigned short* __restrict__ Ob)
{
    const int qb  = blockIdx.x;
    const int h   = blockIdx.y;
    const int t   = threadIdx.x;
    const int row = t >> 1;
    const int c0  = (t & 1) * 32;
    const int nchunks = (2 * qb + 9) >> 3;         // ceil((2qb+2)/8)
    float acc[32];
    #pragma unroll
    for (int i = 0; i < 32; ++i) acc[i] = 0.f;
    float lsum = 0.f;
    for (int c = 0; c < nchunks; ++c) {
        const size_t slot = (size_t)((qb * 4 + c) * NH + h);
        const float* Op = Opart + slot * 8192 + (size_t)row * 64 + c0;
        #pragma unroll
        for (int g = 0; g < 8; ++g) {
            float4 a = *(const float4*)(Op + g * 4);
            acc[g * 4 + 0] += a.x; acc[g * 4 + 1] += a.y;
            acc[g * 4 + 2] += a.z; acc[g * 4 + 3] += a.w;
        }
        lsum += Lpart[slot * 128 + row];
    }
    const float inv = 1.f / lsum;   // > 0: diagonal key always contributes
    unsigned int pk[16];
    #pragma unroll
    for (int i = 0; i < 16; ++i)
        pk[i] = f2b(acc[2 * i] * inv) | ((unsigned)f2b(acc[2 * i + 1] * inv) << 16);
    unsigned short* dst = Ob + (size_t)(qb * 128 + row) * D_DIM + h * 64 + c0;
    *(uint4*)dst        = make_uint4(pk[0],  pk[1],  pk[2],  pk[3]);
    *(uint4*)(dst + 8)  = make_uint4(pk[4],  pk[5],  pk[6],  pk[7]);
    *(uint4*)(dst + 16) = make_uint4(pk[8],  pk[9],  pk[10], pk[11]);
    *(uint4*)(dst + 24) = make_uint4(pk[12], pk[13], pk[14], pk[15]);
}

extern "C" void kernel_launch(void* const* d_in, const int* in_sizes, int n_in,
                              void* d_out, int out_size, void* d_ws, size_t ws_size,
                              hipStream_t stream)
{
    const float* x    = (const float*)d_in[0];
    const float* v1   = (const float*)d_in[1];
    const float* Wq   = (const float*)d_in[2];
    const float* Wk   = (const float*)d_in[3];
    const float* Wv   = (const float*)d_in[4];
    const float* Wout = (const float*)d_in[5];
    const float* lam  = (const float*)d_in[6];
    float* out = (float*)d_out;

    const size_t SD = (size_t)S_LEN * D_DIM;
    const size_t DD = (size_t)D_DIM * D_DIM;
    // d_ws layout (256 MB): Qb 0-4M | Kb 4-8M | Vtg 8-12M | Opart 12-44M |
    //                       Lpart 44-44.5M | xb 46-50M | Woutb 50-52M
    unsigned short* Qb  = (unsigned short*)d_ws;         // internal bf16, 4 MB
    unsigned short* Kb  = Qb + SD;                       // 4 MB
    unsigned short* Vtg = Kb + SD;                       // V transposed [D_DIM][S_LEN], 4 MB
    unsigned short* Ab  = Qb;                            // alias (attn output after combine)
    float* Opart = (float*)(Vtg + SD);                   // 1024 slots * 32 KB = 32 MB
    float* Lpart = Opart + (size_t)1024 * 8192;          // 512 KB
    unsigned short* xb    = (unsigned short*)((char*)d_ws + (46u << 20));  // 4 MB
    unsigned short* Woutb = (unsigned short*)((char*)d_ws + (50u << 20));  // 2 MB

    // bf16 weight scratch in d_out's y slot (first 6 MB of the 8 MB y region;
    // consumed by the QKV GEMM, then y is overwritten by the out-projection).
    // v1 slot (out+SD) is written directly by to_bf16's z=5 branch.
    unsigned short* Wqb   = (unsigned short*)d_out;            // 2 MB
    unsigned short* Wkb   = Wqb + DD;                          // 2 MB
    unsigned short* Wvb   = Wkb + DD;                          // 2 MB

    to_bf16<<<dim3(1024, 6), 256, 0, stream>>>(
        x, Wq, Wk, Wv, Wout, v1, xb, Wqb, Wkb, Wvb, Woutb, out + SD);

    // Q/K/V projections, 64x128 tiles, K_STEP=64: 768 blocks = 3/CU balanced.
    gemm64<<<dim3(D_DIM / 128, S_LEN / 64, 3), 256, 0, stream>>>(
        xb, Wqb, Wkb, Wvb, Qb, Kb, Vtg, v1, lam,
        EPI_NORMROPE_Q | (EPI_NORMROPE << 8) | (EPI_VMIX_T << 16));

    // key-split flash attention (QBLK=128, fused nt-loops, 4 blocks/CU)
    attn_mfma<<<dim3(40, NH), 256, 0, stream>>>(Qb, Kb, Vtg, Opart, Lpart);
    attn_combine<<<dim3(S_LEN / 128, NH), 256, 0, stream>>>(Opart, Lpart, Ab);

    // output projection: 64x64 tiles, K_STEP=64, 512 blocks = 2/CU
    gemm_out<<<dim3(D_DIM / 64, S_LEN / 64), 256, 0, stream>>>(Ab, Woutb, out);
}

// Round 10
// 163.050 us; speedup vs baseline: 1.1129x; 1.0190x over previous
//
#include <hip/hip_runtime.h>
#include <hip/hip_bf16.h>

#define S_LEN 2048
#define D_DIM 1024
#define NH    16
#define NEG_BIG (-1.0e30f)

// epilogue modes
#define EPI_NORMROPE   1   // RMSNorm + RoPE, store bf16 row-major (K)
#define EPI_VMIX_T     2   // v-mix with v1, store bf16 TRANSPOSED (V -> Vt_g[d][s])
#define EPI_F32        3   // plain f32 row-major store
#define EPI_NORMROPE_Q 4   // like NORMROPE but pre-scaled by 0.125*log2e (Q)

typedef __attribute__((ext_vector_type(8))) short bf16x8;
typedef __attribute__((ext_vector_type(4))) float f32x4;
typedef const __attribute__((address_space(1))) unsigned char gu8_t;
typedef __attribute__((address_space(3))) unsigned char lu8_t;

__device__ __forceinline__ float bf2f(unsigned short h) {
    union { unsigned int u; float f; } v; v.u = ((unsigned int)h) << 16; return v.f;
}
__device__ __forceinline__ unsigned short f2b(float f) {   // RNE f32->bf16 raw bits
    union { float f; unsigned int u; } v; v.f = f;
    unsigned int u = v.u;
    return (unsigned short)((u + 0x7FFFu + ((u >> 16) & 1u)) >> 16);
}
__device__ __forceinline__ unsigned int pack2(float a, float b) { // trunc, p>=0
    union { float f; unsigned int u; } x, y; x.f = a; y.f = b;
    return (x.u >> 16) | (y.u & 0xFFFF0000u);
}

// Flat one-shot conversion/copy pass: x,Wq,Wk,Wv,Wout f32->bf16 + v1 f32 copy.
// 1,048,576 8-elem units -> 4096 blocks EXACT (old layout launched 6144 blocks,
// ~3840 of which returned immediately). All region boundaries are multiples of
// 131072 units = 512 blocks, so every branch below is block-uniform.
__global__ __launch_bounds__(256)
void to_bf16(const float* __restrict__ x,  const float* __restrict__ wq,
             const float* __restrict__ wk, const float* __restrict__ wv,
             const float* __restrict__ wo, const float* __restrict__ v1,
             unsigned short* __restrict__ xb,  unsigned short* __restrict__ wqb,
             unsigned short* __restrict__ wkb, unsigned short* __restrict__ wvb,
             unsigned short* __restrict__ wob, float* __restrict__ v1dst)
{
    const unsigned u = blockIdx.x * 256 + threadIdx.x;   // 8-elem unit index
    if (u >= 786432u) {                                  // v1 f32 passthrough
        const size_t i = (size_t)(u - 786432u) * 8;
        float4 lo = *(const float4*)(v1 + i), hi = *(const float4*)(v1 + i + 4);
        *(float4*)(v1dst + i) = lo; *(float4*)(v1dst + i + 4) = hi;
        return;
    }
    const float* s; unsigned short* d; unsigned base;
    if (u < 262144u)      { s = x;  d = xb;  base = 0; }
    else if (u < 393216u) { s = wq; d = wqb; base = 262144u; }
    else if (u < 524288u) { s = wk; d = wkb; base = 393216u; }
    else if (u < 655360u) { s = wv; d = wvb; base = 524288u; }
    else                  { s = wo; d = wob; base = 655360u; }
    const size_t i = (size_t)(u - base) * 8;
    float4 lo = *(const float4*)(s + i), hi = *(const float4*)(s + i + 4);
    uint4 p;
    p.x = f2b(lo.x) | ((unsigned)f2b(lo.y) << 16);
    p.y = f2b(lo.z) | ((unsigned)f2b(lo.w) << 16);
    p.z = f2b(hi.x) | ((unsigned)f2b(hi.y) << 16);
    p.w = f2b(hi.z) | ((unsigned)f2b(hi.w) << 16);
    *(uint4*)(d + i) = p;
}

// 64x128-tile GEMM for the QKV projections: C = A[M,K] * B[N,K]^T.
// Grid (8, 32, 3) = 768 blocks = 3/CU balanced. K_STEP=64 as two 32-col panels
// per barrier ([2][rows][32] LDS keeps the bank-friendly 64 B row stride).
__global__ __launch_bounds__(256, 3)
void gemm64(const unsigned short* __restrict__ A,
            const unsigned short* __restrict__ B0, const unsigned short* __restrict__ B1,
            const unsigned short* __restrict__ B2,
            void* __restrict__ C0, void* __restrict__ C1, void* __restrict__ C2,
            const float* __restrict__ vmix, const float* __restrict__ lam,
            int epiPack)
{
    const int which = blockIdx.z;
    const unsigned short* Bp = (which == 0) ? B0 : ((which == 1) ? B1 : B2);
    void* C = (which == 0) ? C0 : ((which == 1) ? C1 : C2);
    const int epi = (epiPack >> (8 * which)) & 0xff;
    const int tn = blockIdx.x * 128;
    const int tm = blockIdx.y * 64;

    __shared__ unsigned short Asl[2][64 * 32];    // [panel][row*32+col]
    __shared__ unsigned short Bsl[2][128 * 32];

    const int t    = threadIdx.x;
    const int lane = t & 63;
    const int wave = t >> 6;
    const int wm   = (wave >> 1) * 32;
    const int wn   = (wave & 1) * 64;
    const int lrow = lane & 15;
    const int quad = lane >> 4;
    const int srow = t >> 2;          // staging row 0..63
    const int scol = (t & 3) * 8;     // staging col group

    f32x4 acc[2][4];
    #pragma unroll
    for (int i = 0; i < 2; ++i)
        #pragma unroll
        for (int j = 0; j < 4; ++j) {
            f32x4 z = {0.f, 0.f, 0.f, 0.f};
            acc[i][j] = z;
        }

    for (int k0 = 0; k0 < D_DIM; k0 += 64) {
        #pragma unroll
        for (int ks = 0; ks < 2; ++ks) {
            const int kc = k0 + ks * 32 + scol;
            __builtin_amdgcn_global_load_lds(
                (gu8_t*)(A + (size_t)(tm + srow) * D_DIM + kc),
                (lu8_t*)&Asl[ks][t * 8], 16, 0, 0);
            __builtin_amdgcn_global_load_lds(
                (gu8_t*)(Bp + (size_t)(tn + srow) * D_DIM + kc),
                (lu8_t*)&Bsl[ks][t * 8], 16, 0, 0);
            __builtin_amdgcn_global_load_lds(
                (gu8_t*)(Bp + (size_t)(tn + 64 + srow) * D_DIM + kc),
                (lu8_t*)&Bsl[ks][2048 + t * 8], 16, 0, 0);
        }
        __syncthreads();
        #pragma unroll
        for (int ks = 0; ks < 2; ++ks) {
            bf16x8 af[2], bfr[4];
            #pragma unroll
            for (int i = 0; i < 2; ++i)
                af[i] = *(const bf16x8*)(&Asl[ks][(wm + i * 16 + lrow) * 32 + quad * 8]);
            #pragma unroll
            for (int j = 0; j < 4; ++j)
                bfr[j] = *(const bf16x8*)(&Bsl[ks][(wn + j * 16 + lrow) * 32 + quad * 8]);
            #pragma unroll
            for (int i = 0; i < 2; ++i)
                #pragma unroll
                for (int j = 0; j < 4; ++j)
                    acc[i][j] = __builtin_amdgcn_mfma_f32_16x16x32_bf16(af[i], bfr[j], acc[i][j], 0, 0, 0);
        }
        __syncthreads();
    }

    if (epi == EPI_NORMROPE || epi == EPI_NORMROPE_Q) {
        // wave covers cols [tn+wn, tn+wn+64) = one head. RoPE pair = (v0,v2),(v1,v3).
        const float post = (epi == EPI_NORMROPE_Q) ? 0.18033688011112042f : 1.0f;
        #pragma unroll
        for (int i = 0; i < 2; ++i) {
            #pragma unroll
            for (int r = 0; r < 4; ++r) {
                int row = tm + wm + i * 16 + quad * 4 + r;   // seq position (m89/m91 C-map)
                float v0 = acc[i][0][r], v1 = acc[i][1][r];
                float v2 = acc[i][2][r], v3 = acc[i][3][r];
                float ss = v0 * v0 + v1 * v1 + v2 * v2 + v3 * v3;
                ss += __shfl_xor(ss, 1); ss += __shfl_xor(ss, 2);
                ss += __shfl_xor(ss, 4); ss += __shfl_xor(ss, 8);   // 16-lane group = full head
                float rms = rsqrtf(ss * (1.f / 64.f) + 1.1920929e-7f) * post;
                v0 *= rms; v1 *= rms; v2 *= rms; v3 *= rms;
                float fs = (float)row;
                float a0 = fs * exp2f(-0.41524101186092030f * (float)lrow);        // 10000^(-2i/64)
                float a1 = fs * exp2f(-0.41524101186092030f * (float)(16 + lrow));
                float s0, c0, s1, c1;
                __sincosf(a0, &s0, &c0);
                __sincosf(a1, &s1, &c1);
                unsigned short* Cb = (unsigned short*)C;
                size_t base = (size_t)row * D_DIM + tn + wn + lrow;
                Cb[base]      = f2b(v0 * c0 + v2 * s0);
                Cb[base + 16] = f2b(v1 * c1 + v3 * s1);
                Cb[base + 32] = f2b(-v0 * s0 + v2 * c0);
                Cb[base + 48] = f2b(-v1 * s1 + v3 * c1);
            }
        }
    } else if (epi == EPI_VMIX_T) {
        float lamf = *lam;
        #pragma unroll
        for (int i = 0; i < 2; ++i) {
            int cm0 = tm + wm + i * 16 + quad * 4;
            #pragma unroll
            for (int j = 0; j < 4; ++j) {
                int cn = tn + wn + j * 16 + lrow;
                ushort4 pk;
                float vals[4];
                #pragma unroll
                for (int r = 0; r < 4; ++r) {
                    size_t idx = (size_t)(cm0 + r) * D_DIM + cn;
                    vals[r] = (1.f - lamf) * acc[i][j][r] + lamf * vmix[idx];
                }
                pk.x = f2b(vals[0]); pk.y = f2b(vals[1]);
                pk.z = f2b(vals[2]); pk.w = f2b(vals[3]);
                *(ushort4*)((unsigned short*)C + (size_t)cn * S_LEN + cm0) = pk;
            }
        }
    } else {   // EPI_F32
        #pragma unroll
        for (int i = 0; i < 2; ++i) {
            int cm0 = tm + wm + i * 16 + quad * 4;
            #pragma unroll
            for (int j = 0; j < 4; ++j) {
                int cn = tn + wn + j * 16 + lrow;
                #pragma unroll
                for (int r = 0; r < 4; ++r)
                    ((float*)C)[(size_t)(cm0 + r) * D_DIM + cn] = acc[i][j][r];
            }
        }
    }
}

// Out-projection GEMM, 64x64 tiles, K_STEP=64 (two 32-col panels/barrier):
// grid (16, 32) = 512 blocks = 2/CU. 4 waves 2x2, wave = 32x32, acc[2][2].
__global__ __launch_bounds__(256, 4)
void gemm_out(const unsigned short* __restrict__ A,
              const unsigned short* __restrict__ B,
              float* __restrict__ C)
{
    const int tn = blockIdx.x * 64;
    const int tm = blockIdx.y * 64;

    __shared__ unsigned short Asl[2][64 * 32];
    __shared__ unsigned short Bsl[2][64 * 32];

    const int t    = threadIdx.x;
    const int lane = t & 63;
    const int wave = t >> 6;
    const int wm   = (wave >> 1) * 32;
    const int wn   = (wave & 1) * 32;
    const int lrow = lane & 15;
    const int quad = lane >> 4;
    const int srow = t >> 2;
    const int scol = (t & 3) * 8;

    f32x4 acc[2][2];
    #pragma unroll
    for (int i = 0; i < 2; ++i)
        #pragma unroll
        for (int j = 0; j < 2; ++j) {
            f32x4 z = {0.f, 0.f, 0.f, 0.f};
            acc[i][j] = z;
        }

    for (int k0 = 0; k0 < D_DIM; k0 += 64) {
        #pragma unroll
        for (int ks = 0; ks < 2; ++ks) {
            const int kc = k0 + ks * 32 + scol;
            __builtin_amdgcn_global_load_lds(
                (gu8_t*)(A + (size_t)(tm + srow) * D_DIM + kc),
                (lu8_t*)&Asl[ks][t * 8], 16, 0, 0);
            __builtin_amdgcn_global_load_lds(
                (gu8_t*)(B + (size_t)(tn + srow) * D_DIM + kc),
                (lu8_t*)&Bsl[ks][t * 8], 16, 0, 0);
        }
        __syncthreads();
        #pragma unroll
        for (int ks = 0; ks < 2; ++ks) {
            bf16x8 af[2], bfr[2];
            #pragma unroll
            for (int i = 0; i < 2; ++i)
                af[i] = *(const bf16x8*)(&Asl[ks][(wm + i * 16 + lrow) * 32 + quad * 8]);
            #pragma unroll
            for (int j = 0; j < 2; ++j)
                bfr[j] = *(const bf16x8*)(&Bsl[ks][(wn + j * 16 + lrow) * 32 + quad * 8]);
            #pragma unroll
            for (int i = 0; i < 2; ++i)
                #pragma unroll
                for (int j = 0; j < 2; ++j)
                    acc[i][j] = __builtin_amdgcn_mfma_f32_16x16x32_bf16(af[i], bfr[j], acc[i][j], 0, 0, 0);
        }
        __syncthreads();
    }

    #pragma unroll
    for (int i = 0; i < 2; ++i) {
        int cm0 = tm + wm + i * 16 + quad * 4;
        #pragma unroll
        for (int j = 0; j < 2; ++j) {
            int cn = tn + wn + j * 16 + lrow;
            #pragma unroll
            for (int r = 0; r < 4; ++r)
                C[(size_t)(cm0 + r) * D_DIM + cn] = acc[i][j][r];
        }
    }
}

// MFMA flash attention, QBLK=128, key-split (8-tile chunks), swapped QK^T,
// fused nt-loops (kf/vf read once, feed both q-groups), P parked in the stale
// double-buffer half. Unchanged from rounds 8/9 (validated).
__global__ __launch_bounds__(256, 4)
void attn_mfma(const unsigned short* Qb,
               const unsigned short* __restrict__ Kb,
               const unsigned short* __restrict__ Vtg,
               float* __restrict__ Opart, float* __restrict__ Lpart)
{
    // map bx -> (qb, c): qb = 128-row q-block (0..15), chunk count ceil((2qb+2)/8),
    // big blocks dispatch first. Total bx = 40.
    const int bx = blockIdx.x;
    int qb = 0, c = 0;
    {
        int accum = 0;
        #pragma unroll
        for (int q = 15; q >= 0; --q) {
            int n = (2 * q + 9) >> 3;               // ceil((2q+2)/8)
            if (bx >= accum && bx < accum + n) { qb = q; c = bx - accum; }
            accum += n;
        }
    }
    const int jmax = 2 * qb + 1;                    // key tiles 0..jmax
    const int jlo  = c * 8;
    const int jhi  = min(jlo + 7, jmax);
    const int h  = blockIdx.y;
    const int t  = threadIdx.x;
    const int w  = t >> 6;
    const int l  = t & 63;
    const int l15  = l & 15;
    const int quad = l >> 4;
    const int hco  = h * 64;
    const int slot = (qb * 4 + c) * NH + h;         // <= 1023

    __shared__ unsigned short Ks[2][64][72];    // double-buffered; stale half = P (waves 0-1)
    __shared__ unsigned short Vt[2][64][72];    // Vt[buf][d][key]; stale half = P (waves 2-3)

    // Q fragments: rows qb*128 + w*32 + g*16 + l15
    bf16x8 qf[2][2];
    #pragma unroll
    for (int g = 0; g < 2; ++g) {
        const unsigned short* qrow =
            Qb + (size_t)(qb * 128 + w * 32 + g * 16 + l15) * D_DIM + hco;
        qf[g][0] = *(const bf16x8*)(qrow + quad * 8);
        qf[g][1] = *(const bf16x8*)(qrow + 32 + quad * 8);
    }

    f32x4 oac[2][4];
    #pragma unroll
    for (int g = 0; g < 2; ++g)
        #pragma unroll
        for (int nt = 0; nt < 4; ++nt) { f32x4 z = {0.f,0.f,0.f,0.f}; oac[g][nt] = z; }
    float lsum0 = 0.f, lsum1 = 0.f;      // per-lane: keys {nt*16+quad*4+r}, q = l15

    const int rr = t >> 2;          // staging row (K: key row; Vt: d row)
    const int dc = (t & 3) * 16;    // 16-col group

    const unsigned short* kbase = Kb  + (size_t)rr * D_DIM + hco + dc;
    const unsigned short* vbase = Vtg + (size_t)(hco + rr) * S_LEN + dc;

    uint4 ka0, ka1, va0, va1;
    {
        const unsigned short* kp = kbase + (size_t)jlo * 64 * D_DIM;
        const unsigned short* vp = vbase + (size_t)jlo * 64;
        ka0 = *(const uint4*)kp;  ka1 = *(const uint4*)(kp + 8);
        va0 = *(const uint4*)vp;  va1 = *(const uint4*)(vp + 8);
    }

    const float C2 = -11.541560327111707f;              // -8 * log2(e)

    for (int j = jlo; j <= jhi; ++j) {
        const int buf = (j - jlo) & 1;
        // write this tile's LDS from prefetched regs (vmcnt wait auto-inserted)
        *(uint4*)&Ks[buf][rr][dc]     = ka0;
        *(uint4*)&Ks[buf][rr][dc + 8] = ka1;
        *(uint4*)&Vt[buf][rr][dc]     = va0;
        *(uint4*)&Vt[buf][rr][dc + 8] = va1;
        __syncthreads();                       // barrier 1: tile visible
        if (j < jhi) {                         // prefetch next tile into regs
            const unsigned short* kp = kbase + (size_t)(j + 1) * 64 * D_DIM;
            const unsigned short* vp = vbase + (size_t)(j + 1) * 64;
            ka0 = *(const uint4*)kp;  ka1 = *(const uint4*)(kp + 8);
            va0 = *(const uint4*)vp;  va1 = *(const uint4*)(vp + 8);
        }

        // wave-private P tile region in the STALE buffer half (32 rows/wave)
        unsigned short (*stale)[72] = (w < 2)
            ? (unsigned short (*)[72])&Ks[buf ^ 1][w * 32]
            : (unsigned short (*)[72])&Vt[buf ^ 1][(w - 2) * 32];
        const bool bulk = (j < 2 * qb);

        // ---- fused QK^T + softmax: kf read ONCE per nt, used by both groups.
        // S^T layout: key = nt*16 + quad*4 + r, q = l15.
        unsigned pw[2][4][2];                  // [g][nt][word] packed bf16 key-pairs
        float ls0 = 0.f, ls1 = 0.f;
        __builtin_amdgcn_s_setprio(1);
        #pragma unroll
        for (int nt = 0; nt < 4; ++nt) {
            bf16x8 kf0 = *(const bf16x8*)&Ks[buf][nt * 16 + l15][quad * 8];
            bf16x8 kf1 = *(const bf16x8*)&Ks[buf][nt * 16 + l15][32 + quad * 8];
            #pragma unroll
            for (int g = 0; g < 2; ++g) {
                f32x4 z = {0.f,0.f,0.f,0.f};
                z = __builtin_amdgcn_mfma_f32_16x16x32_bf16(kf0, qf[g][0], z, 0, 0, 0);
                z = __builtin_amdgcn_mfma_f32_16x16x32_bf16(kf1, qf[g][1], z, 0, 0, 0);
                float pe[4];
                if (bulk) {
                    #pragma unroll
                    for (int r = 0; r < 4; ++r) pe[r] = exp2f(z[r] + C2);
                } else {
                    const int q_g  = qb * 128 + w * 32 + g * 16 + l15;
                    const int key0 = j * 64 + nt * 16 + quad * 4;
                    #pragma unroll
                    for (int r = 0; r < 4; ++r) {
                        float s = z[r] + C2;
                        if (key0 + r > q_g) s = NEG_BIG;
                        pe[r] = exp2f(s);
                    }
                }
                float psum = (pe[0] + pe[1]) + (pe[2] + pe[3]);
                if (g == 0) ls0 += psum; else ls1 += psum;
                pw[g][nt][0] = pack2(pe[0], pe[1]);
                pw[g][nt][1] = pack2(pe[2], pe[3]);
            }
        }
        __builtin_amdgcn_s_setprio(0);
        lsum0 += ls0; lsum1 += ls1;

        // park P (both groups) in the wave-private stale region
        #pragma unroll
        for (int g = 0; g < 2; ++g)
            #pragma unroll
            for (int nt = 0; nt < 4; ++nt) {
                uint2 pk; pk.x = pw[g][nt][0]; pk.y = pw[g][nt][1];
                *(uint2*)&stale[g * 16 + l15][nt * 16 + quad * 4] = pk;
            }

        // P A-fragments (C-layout -> A-layout via the LDS hop)
        bf16x8 pf[2][2];
        #pragma unroll
        for (int g = 0; g < 2; ++g) {
            pf[g][0] = *(const bf16x8*)&stale[g * 16 + l15][quad * 8];
            pf[g][1] = *(const bf16x8*)&stale[g * 16 + l15][32 + quad * 8];
        }

        // ---- fused PV: vf read ONCE per nt, used by both groups.
        __builtin_amdgcn_s_setprio(1);
        #pragma unroll
        for (int nt = 0; nt < 4; ++nt) {
            bf16x8 vf0 = *(const bf16x8*)&Vt[buf][nt * 16 + l15][quad * 8];
            bf16x8 vf1 = *(const bf16x8*)&Vt[buf][nt * 16 + l15][32 + quad * 8];
            oac[0][nt] = __builtin_amdgcn_mfma_f32_16x16x32_bf16(pf[0][0], vf0, oac[0][nt], 0, 0, 0);
            oac[0][nt] = __builtin_amdgcn_mfma_f32_16x16x32_bf16(pf[0][1], vf1, oac[0][nt], 0, 0, 0);
            oac[1][nt] = __builtin_amdgcn_mfma_f32_16x16x32_bf16(pf[1][0], vf0, oac[1][nt], 0, 0, 0);
            oac[1][nt] = __builtin_amdgcn_mfma_f32_16x16x32_bf16(pf[1][1], vf1, oac[1][nt], 0, 0, 0);
        }
        __builtin_amdgcn_s_setprio(0);
        __syncthreads();   // barrier 2: P reads done before next staging hits stale half
    }

    // partials: l per q-row (reduce lane-scalar across quads) + unnormalized O
    #pragma unroll
    for (int g = 0; g < 2; ++g) {
        float lr = (g == 0) ? lsum0 : lsum1;
        lr += __shfl_xor(lr, 16);
        lr += __shfl_xor(lr, 32);            // all quads hold l[q = l15]
        if (l < 16)
            Lpart[(size_t)slot * 128 + w * 32 + g * 16 + l15] = lr;
    }
    float* Op = Opart + (size_t)slot * 8192;
    #pragma unroll
    for (int g = 0; g < 2; ++g)
        #pragma unroll
        for (int nt = 0; nt < 4; ++nt)
            #pragma unroll
            for (int r = 0; r < 4; ++r)
                Op[(size_t)(w * 32 + g * 16 + quad * 4 + r) * 64 + nt * 16 + l15] = oac[g][nt][r];
}

// sum <=4 key-chunk partials, normalize, cast to bf16.
// grid (16 qb, 16 h, 2 col-halves) = 512 blocks = 2/CU (was 256 = 1/CU with
// no latency hiding on the Opart stream). Thread = (row 0..127, 16-col granule).
__global__ __launch_bounds__(256)
void attn_combine(const float* __restrict__ Opart, const float* __restrict__ Lpart,
                  unsigned short* __restrict__ Ob)
{
    const int qb  = blockIdx.x;
    const int h   = blockIdx.y;
    const int zh  = blockIdx.z;
    const int t   = threadIdx.x;
    const int row = t >> 1;
    const int c0  = zh * 32 + (t & 1) * 16;
    const int nchunks = (2 * qb + 9) >> 3;         // ceil((2qb+2)/8)
    float acc[16];
    #pragma unroll
    for (int i = 0; i < 16; ++i) acc[i] = 0.f;
    float lsum = 0.f;
    for (int c = 0; c < nchunks; ++c) {
        const size_t slot = (size_t)((qb * 4 + c) * NH + h);
        const float* Op = Opart + slot * 8192 + (size_t)row * 64 + c0;
        #pragma unroll
        for (int g = 0; g < 4; ++g) {
            float4 a = *(const float4*)(Op + g * 4);
            acc[g * 4 + 0] += a.x; acc[g * 4 + 1] += a.y;
            acc[g * 4 + 2] += a.z; acc[g * 4 + 3] += a.w;
        }
        lsum += Lpart[slot * 128 + row];
    }
    const float inv = 1.f / lsum;   // > 0: diagonal key always contributes
    unsigned int pk[8];
    #pragma unroll
    for (int i = 0; i < 8; ++i)
        pk[i] = f2b(acc[2 * i] * inv) | ((unsigned)f2b(acc[2 * i + 1] * inv) << 16);
    unsigned short* dst = Ob + (size_t)(qb * 128 + row) * D_DIM + h * 64 + c0;
    *(uint4*)dst       = make_uint4(pk[0], pk[1], pk[2], pk[3]);
    *(uint4*)(dst + 8) = make_uint4(pk[4], pk[5], pk[6], pk[7]);
}

extern "C" void kernel_launch(void* const* d_in, const int* in_sizes, int n_in,
                              void* d_out, int out_size, void* d_ws, size_t ws_size,
                              hipStream_t stream)
{
    const float* x    = (const float*)d_in[0];
    const float* v1   = (const float*)d_in[1];
    const float* Wq   = (const float*)d_in[2];
    const float* Wk   = (const float*)d_in[3];
    const float* Wv   = (const float*)d_in[4];
    const float* Wout = (const float*)d_in[5];
    const float* lam  = (const float*)d_in[6];
    float* out = (float*)d_out;

    const size_t SD = (size_t)S_LEN * D_DIM;
    const size_t DD = (size_t)D_DIM * D_DIM;
    // d_ws layout (256 MB): Qb 0-4M | Kb 4-8M | Vtg 8-12M | Opart 12-44M |
    //                       Lpart 44-44.5M | xb 46-50M | Woutb 50-52M
    unsigned short* Qb  = (unsigned short*)d_ws;         // internal bf16, 4 MB
    unsigned short* Kb  = Qb + SD;                       // 4 MB
    unsigned short* Vtg = Kb + SD;                       // V transposed [D_DIM][S_LEN], 4 MB
    unsigned short* Ab  = Qb;                            // alias (attn output after combine)
    float* Opart = (float*)(Vtg + SD);                   // 1024 slots * 32 KB = 32 MB
    float* Lpart = Opart + (size_t)1024 * 8192;          // 512 KB
    unsigned short* xb    = (unsigned short*)((char*)d_ws + (46u << 20));  // 4 MB
    unsigned short* Woutb = (unsigned short*)((char*)d_ws + (50u << 20));  // 2 MB

    // bf16 weight scratch in d_out's y slot (first 6 MB of the 8 MB y region;
    // consumed by the QKV GEMM, then y is overwritten by the out-projection).
    // v1 slot (out+SD) is written directly by to_bf16's v1 branch.
    unsigned short* Wqb   = (unsigned short*)d_out;            // 2 MB
    unsigned short* Wkb   = Wqb + DD;                          // 2 MB
    unsigned short* Wvb   = Wkb + DD;                          // 2 MB

    // flat conversion/copy pass: 4096 blocks exact, no dead blocks
    to_bf16<<<dim3(4096), 256, 0, stream>>>(
        x, Wq, Wk, Wv, Wout, v1, xb, Wqb, Wkb, Wvb, Woutb, out + SD);

    // Q/K/V projections, 64x128 tiles, K_STEP=64: 768 blocks = 3/CU balanced.
    gemm64<<<dim3(D_DIM / 128, S_LEN / 64, 3), 256, 0, stream>>>(
        xb, Wqb, Wkb, Wvb, Qb, Kb, Vtg, v1, lam,
        EPI_NORMROPE_Q | (EPI_NORMROPE << 8) | (EPI_VMIX_T << 16));

    // key-split flash attention (QBLK=128, fused nt-loops, 4 blocks/CU)
    attn_mfma<<<dim3(40, NH), 256, 0, stream>>>(Qb, Kb, Vtg, Opart, Lpart);
    attn_combine<<<dim3(S_LEN / 128, NH, 2), 256, 0, stream>>>(Opart, Lpart, Ab);

    // output projection: 64x64 tiles, K_STEP=64, 512 blocks = 2/CU
    gemm_out<<<dim3(D_DIM / 64, S_LEN / 64), 256, 0, stream>>>(Ab, Woutb, out);
}

// Round 11
// 161.212 us; speedup vs baseline: 1.1256x; 1.0114x over previous
//
#include <hip/hip_runtime.h>
#include <hip/hip_bf16.h>

#define S_LEN 2048
#define D_DIM 1024
#define NH    16
#define NEG_BIG (-1.0e30f)

// epilogue modes
#define EPI_NORMROPE   1   // RMSNorm + RoPE, store bf16 row-major (K)
#define EPI_VMIX_T     2   // v-mix with v1, store bf16 TRANSPOSED (V -> Vt_g[d][s])
#define EPI_F32        3   // plain f32 row-major store
#define EPI_NORMROPE_Q 4   // like NORMROPE but pre-scaled by 0.125*log2e (Q)

typedef __attribute__((ext_vector_type(8))) short bf16x8;
typedef __attribute__((ext_vector_type(4))) float f32x4;
typedef const __attribute__((address_space(1))) unsigned char gu8_t;
typedef __attribute__((address_space(3))) unsigned char lu8_t;

__device__ __forceinline__ float bf2f(unsigned short h) {
    union { unsigned int u; float f; } v; v.u = ((unsigned int)h) << 16; return v.f;
}
__device__ __forceinline__ unsigned short f2b(float f) {   // RNE f32->bf16 raw bits
    union { float f; unsigned int u; } v; v.f = f;
    unsigned int u = v.u;
    return (unsigned short)((u + 0x7FFFu + ((u >> 16) & 1u)) >> 16);
}
__device__ __forceinline__ unsigned int pack2(float a, float b) { // trunc, p>=0
    union { float f; unsigned int u; } x, y; x.f = a; y.f = b;
    return (x.u >> 16) | (y.u & 0xFFFF0000u);
}

// Flat one-shot conversion/copy pass: x,Wq,Wk,Wv,Wout f32->bf16 + v1 f32 copy.
// 1,048,576 8-elem units -> 4096 blocks EXACT. Region boundaries are multiples
// of 512 blocks, so every branch below is block-uniform.
__global__ __launch_bounds__(256)
void to_bf16(const float* __restrict__ x,  const float* __restrict__ wq,
             const float* __restrict__ wk, const float* __restrict__ wv,
             const float* __restrict__ wo, const float* __restrict__ v1,
             unsigned short* __restrict__ xb,  unsigned short* __restrict__ wqb,
             unsigned short* __restrict__ wkb, unsigned short* __restrict__ wvb,
             unsigned short* __restrict__ wob, float* __restrict__ v1dst)
{
    const unsigned u = blockIdx.x * 256 + threadIdx.x;   // 8-elem unit index
    if (u >= 786432u) {                                  // v1 f32 passthrough
        const size_t i = (size_t)(u - 786432u) * 8;
        float4 lo = *(const float4*)(v1 + i), hi = *(const float4*)(v1 + i + 4);
        *(float4*)(v1dst + i) = lo; *(float4*)(v1dst + i + 4) = hi;
        return;
    }
    const float* s; unsigned short* d; unsigned base;
    if (u < 262144u)      { s = x;  d = xb;  base = 0; }
    else if (u < 393216u) { s = wq; d = wqb; base = 262144u; }
    else if (u < 524288u) { s = wk; d = wkb; base = 393216u; }
    else if (u < 655360u) { s = wv; d = wvb; base = 524288u; }
    else                  { s = wo; d = wob; base = 655360u; }
    const size_t i = (size_t)(u - base) * 8;
    float4 lo = *(const float4*)(s + i), hi = *(const float4*)(s + i + 4);
    uint4 p;
    p.x = f2b(lo.x) | ((unsigned)f2b(lo.y) << 16);
    p.y = f2b(lo.z) | ((unsigned)f2b(lo.w) << 16);
    p.z = f2b(hi.x) | ((unsigned)f2b(hi.y) << 16);
    p.w = f2b(hi.z) | ((unsigned)f2b(hi.w) << 16);
    *(uint4*)(d + i) = p;
}

// 64x128-tile GEMM for the QKV projections: C = A[M,K] * B[N,K]^T.
// Grid (8, 32, 3) = 768 blocks = 3/CU balanced. K_STEP=64 as two 32-col panels
// per barrier ([2][rows][32] LDS keeps the bank-friendly 64 B row stride).
__global__ __launch_bounds__(256, 3)
void gemm64(const unsigned short* __restrict__ A,
            const unsigned short* __restrict__ B0, const unsigned short* __restrict__ B1,
            const unsigned short* __restrict__ B2,
            void* __restrict__ C0, void* __restrict__ C1, void* __restrict__ C2,
            const float* __restrict__ vmix, const float* __restrict__ lam,
            int epiPack)
{
    const int which = blockIdx.z;
    const unsigned short* Bp = (which == 0) ? B0 : ((which == 1) ? B1 : B2);
    void* C = (which == 0) ? C0 : ((which == 1) ? C1 : C2);
    const int epi = (epiPack >> (8 * which)) & 0xff;
    const int tn = blockIdx.x * 128;
    const int tm = blockIdx.y * 64;

    __shared__ unsigned short Asl[2][64 * 32];    // [panel][row*32+col]
    __shared__ unsigned short Bsl[2][128 * 32];

    const int t    = threadIdx.x;
    const int lane = t & 63;
    const int wave = t >> 6;
    const int wm   = (wave >> 1) * 32;
    const int wn   = (wave & 1) * 64;
    const int lrow = lane & 15;
    const int quad = lane >> 4;
    const int srow = t >> 2;          // staging row 0..63
    const int scol = (t & 3) * 8;     // staging col group

    f32x4 acc[2][4];
    #pragma unroll
    for (int i = 0; i < 2; ++i)
        #pragma unroll
        for (int j = 0; j < 4; ++j) {
            f32x4 z = {0.f, 0.f, 0.f, 0.f};
            acc[i][j] = z;
        }

    for (int k0 = 0; k0 < D_DIM; k0 += 64) {
        #pragma unroll
        for (int ks = 0; ks < 2; ++ks) {
            const int kc = k0 + ks * 32 + scol;
            __builtin_amdgcn_global_load_lds(
                (gu8_t*)(A + (size_t)(tm + srow) * D_DIM + kc),
                (lu8_t*)&Asl[ks][t * 8], 16, 0, 0);
            __builtin_amdgcn_global_load_lds(
                (gu8_t*)(Bp + (size_t)(tn + srow) * D_DIM + kc),
                (lu8_t*)&Bsl[ks][t * 8], 16, 0, 0);
            __builtin_amdgcn_global_load_lds(
                (gu8_t*)(Bp + (size_t)(tn + 64 + srow) * D_DIM + kc),
                (lu8_t*)&Bsl[ks][2048 + t * 8], 16, 0, 0);
        }
        __syncthreads();
        #pragma unroll
        for (int ks = 0; ks < 2; ++ks) {
            bf16x8 af[2], bfr[4];
            #pragma unroll
            for (int i = 0; i < 2; ++i)
                af[i] = *(const bf16x8*)(&Asl[ks][(wm + i * 16 + lrow) * 32 + quad * 8]);
            #pragma unroll
            for (int j = 0; j < 4; ++j)
                bfr[j] = *(const bf16x8*)(&Bsl[ks][(wn + j * 16 + lrow) * 32 + quad * 8]);
            #pragma unroll
            for (int i = 0; i < 2; ++i)
                #pragma unroll
                for (int j = 0; j < 4; ++j)
                    acc[i][j] = __builtin_amdgcn_mfma_f32_16x16x32_bf16(af[i], bfr[j], acc[i][j], 0, 0, 0);
        }
        __syncthreads();
    }

    if (epi == EPI_NORMROPE || epi == EPI_NORMROPE_Q) {
        // wave covers cols [tn+wn, tn+wn+64) = one head. RoPE pair = (v0,v2),(v1,v3).
        const float post = (epi == EPI_NORMROPE_Q) ? 0.18033688011112042f : 1.0f;
        #pragma unroll
        for (int i = 0; i < 2; ++i) {
            #pragma unroll
            for (int r = 0; r < 4; ++r) {
                int row = tm + wm + i * 16 + quad * 4 + r;   // seq position (m89/m91 C-map)
                float v0 = acc[i][0][r], v1 = acc[i][1][r];
                float v2 = acc[i][2][r], v3 = acc[i][3][r];
                float ss = v0 * v0 + v1 * v1 + v2 * v2 + v3 * v3;
                ss += __shfl_xor(ss, 1); ss += __shfl_xor(ss, 2);
                ss += __shfl_xor(ss, 4); ss += __shfl_xor(ss, 8);   // 16-lane group = full head
                float rms = rsqrtf(ss * (1.f / 64.f) + 1.1920929e-7f) * post;
                v0 *= rms; v1 *= rms; v2 *= rms; v3 *= rms;
                float fs = (float)row;
                float a0 = fs * exp2f(-0.41524101186092030f * (float)lrow);        // 10000^(-2i/64)
                float a1 = fs * exp2f(-0.41524101186092030f * (float)(16 + lrow));
                float s0, c0, s1, c1;
                __sincosf(a0, &s0, &c0);
                __sincosf(a1, &s1, &c1);
                unsigned short* Cb = (unsigned short*)C;
                size_t base = (size_t)row * D_DIM + tn + wn + lrow;
                Cb[base]      = f2b(v0 * c0 + v2 * s0);
                Cb[base + 16] = f2b(v1 * c1 + v3 * s1);
                Cb[base + 32] = f2b(-v0 * s0 + v2 * c0);
                Cb[base + 48] = f2b(-v1 * s1 + v3 * c1);
            }
        }
    } else if (epi == EPI_VMIX_T) {
        float lamf = *lam;
        #pragma unroll
        for (int i = 0; i < 2; ++i) {
            int cm0 = tm + wm + i * 16 + quad * 4;
            #pragma unroll
            for (int j = 0; j < 4; ++j) {
                int cn = tn + wn + j * 16 + lrow;
                ushort4 pk;
                float vals[4];
                #pragma unroll
                for (int r = 0; r < 4; ++r) {
                    size_t idx = (size_t)(cm0 + r) * D_DIM + cn;
                    vals[r] = (1.f - lamf) * acc[i][j][r] + lamf * vmix[idx];
                }
                pk.x = f2b(vals[0]); pk.y = f2b(vals[1]);
                pk.z = f2b(vals[2]); pk.w = f2b(vals[3]);
                *(ushort4*)((unsigned short*)C + (size_t)cn * S_LEN + cm0) = pk;
            }
        }
    } else {   // EPI_F32
        #pragma unroll
        for (int i = 0; i < 2; ++i) {
            int cm0 = tm + wm + i * 16 + quad * 4;
            #pragma unroll
            for (int j = 0; j < 4; ++j) {
                int cn = tn + wn + j * 16 + lrow;
                #pragma unroll
                for (int r = 0; r < 4; ++r)
                    ((float*)C)[(size_t)(cm0 + r) * D_DIM + cn] = acc[i][j][r];
            }
        }
    }
}

// Out-projection GEMM, 64x64 tiles, K_STEP=64 (two 32-col panels/barrier):
// grid (16, 32) = 512 blocks = 2/CU. 4 waves 2x2, wave = 32x32, acc[2][2].
__global__ __launch_bounds__(256, 4)
void gemm_out(const unsigned short* __restrict__ A,
              const unsigned short* __restrict__ B,
              float* __restrict__ C)
{
    const int tn = blockIdx.x * 64;
    const int tm = blockIdx.y * 64;

    __shared__ unsigned short Asl[2][64 * 32];
    __shared__ unsigned short Bsl[2][64 * 32];

    const int t    = threadIdx.x;
    const int lane = t & 63;
    const int wave = t >> 6;
    const int wm   = (wave >> 1) * 32;
    const int wn   = (wave & 1) * 32;
    const int lrow = lane & 15;
    const int quad = lane >> 4;
    const int srow = t >> 2;
    const int scol = (t & 3) * 8;

    f32x4 acc[2][2];
    #pragma unroll
    for (int i = 0; i < 2; ++i)
        #pragma unroll
        for (int j = 0; j < 2; ++j) {
            f32x4 z = {0.f, 0.f, 0.f, 0.f};
            acc[i][j] = z;
        }

    for (int k0 = 0; k0 < D_DIM; k0 += 64) {
        #pragma unroll
        for (int ks = 0; ks < 2; ++ks) {
            const int kc = k0 + ks * 32 + scol;
            __builtin_amdgcn_global_load_lds(
                (gu8_t*)(A + (size_t)(tm + srow) * D_DIM + kc),
                (lu8_t*)&Asl[ks][t * 8], 16, 0, 0);
            __builtin_amdgcn_global_load_lds(
                (gu8_t*)(B + (size_t)(tn + srow) * D_DIM + kc),
                (lu8_t*)&Bsl[ks][t * 8], 16, 0, 0);
        }
        __syncthreads();
        #pragma unroll
        for (int ks = 0; ks < 2; ++ks) {
            bf16x8 af[2], bfr[2];
            #pragma unroll
            for (int i = 0; i < 2; ++i)
                af[i] = *(const bf16x8*)(&Asl[ks][(wm + i * 16 + lrow) * 32 + quad * 8]);
            #pragma unroll
            for (int j = 0; j < 2; ++j)
                bfr[j] = *(const bf16x8*)(&Bsl[ks][(wn + j * 16 + lrow) * 32 + quad * 8]);
            #pragma unroll
            for (int i = 0; i < 2; ++i)
                #pragma unroll
                for (int j = 0; j < 2; ++j)
                    acc[i][j] = __builtin_amdgcn_mfma_f32_16x16x32_bf16(af[i], bfr[j], acc[i][j], 0, 0, 0);
        }
        __syncthreads();
    }

    #pragma unroll
    for (int i = 0; i < 2; ++i) {
        int cm0 = tm + wm + i * 16 + quad * 4;
        #pragma unroll
        for (int j = 0; j < 2; ++j) {
            int cn = tn + wn + j * 16 + lrow;
            #pragma unroll
            for (int r = 0; r < 4; ++r)
                C[(size_t)(cm0 + r) * D_DIM + cn] = acc[i][j][r];
        }
    }
}

// MFMA flash attention, QBLK=128, key-split with CHUNK=6 key-tiles (was 8):
// 816 blocks <= 1024 resident slots (4/CU) -> all blocks co-resident, so the
// dispatch duration = the longest block = 6 iterations (was 8): critical path
// -25%. Partials stored BF16 (was f32): halves partial stream traffic; adds
// one 2^-9-relative rounding per <=6-term partial sum, upstream of the
// out-projection's 1024-term reduction. Swapped QK^T, fused nt-loops, P parked
// in the stale double-buffer half (all validated in rounds 8-10).
__global__ __launch_bounds__(256, 4)
void attn_mfma(const unsigned short* Qb,
               const unsigned short* __restrict__ Kb,
               const unsigned short* __restrict__ Vtg,
               unsigned short* __restrict__ Opart, float* __restrict__ Lpart)
{
    // map bx -> (qb, c): qb = 128-row q-block (0..15), nchunks = ceil((2qb+2)/6),
    // big blocks dispatch first. Total bx = 51.
    const int bx = blockIdx.x;
    int qb = 0, c = 0;
    {
        int accum = 0;
        #pragma unroll
        for (int q = 15; q >= 0; --q) {
            int n = (2 * q + 7) / 6;                // ceil((2q+2)/6)
            if (bx >= accum && bx < accum + n) { qb = q; c = bx - accum; }
            accum += n;
        }
    }
    const int jmax = 2 * qb + 1;                    // key tiles 0..jmax
    const int jlo  = c * 6;
    const int jhi  = min(jlo + 5, jmax);
    const int h  = blockIdx.y;
    const int t  = threadIdx.x;
    const int w  = t >> 6;
    const int l  = t & 63;
    const int l15  = l & 15;
    const int quad = l >> 4;
    const int hco  = h * 64;
    const int slot = (qb * 6 + c) * NH + h;         // <= 1535

    __shared__ unsigned short Ks[2][64][72];    // double-buffered; stale half = P (waves 0-1)
    __shared__ unsigned short Vt[2][64][72];    // Vt[buf][d][key]; stale half = P (waves 2-3)

    // Q fragments: rows qb*128 + w*32 + g*16 + l15
    bf16x8 qf[2][2];
    #pragma unroll
    for (int g = 0; g < 2; ++g) {
        const unsigned short* qrow =
            Qb + (size_t)(qb * 128 + w * 32 + g * 16 + l15) * D_DIM + hco;
        qf[g][0] = *(const bf16x8*)(qrow + quad * 8);
        qf[g][1] = *(const bf16x8*)(qrow + 32 + quad * 8);
    }

    f32x4 oac[2][4];
    #pragma unroll
    for (int g = 0; g < 2; ++g)
        #pragma unroll
        for (int nt = 0; nt < 4; ++nt) { f32x4 z = {0.f,0.f,0.f,0.f}; oac[g][nt] = z; }
    float lsum0 = 0.f, lsum1 = 0.f;      // per-lane: keys {nt*16+quad*4+r}, q = l15

    const int rr = t >> 2;          // staging row (K: key row; Vt: d row)
    const int dc = (t & 3) * 16;    // 16-col group

    const unsigned short* kbase = Kb  + (size_t)rr * D_DIM + hco + dc;
    const unsigned short* vbase = Vtg + (size_t)(hco + rr) * S_LEN + dc;

    uint4 ka0, ka1, va0, va1;
    {
        const unsigned short* kp = kbase + (size_t)jlo * 64 * D_DIM;
        const unsigned short* vp = vbase + (size_t)jlo * 64;
        ka0 = *(const uint4*)kp;  ka1 = *(const uint4*)(kp + 8);
        va0 = *(const uint4*)vp;  va1 = *(const uint4*)(vp + 8);
    }

    const float C2 = -11.541560327111707f;              // -8 * log2(e)

    for (int j = jlo; j <= jhi; ++j) {
        const int buf = (j - jlo) & 1;
        // write this tile's LDS from prefetched regs (vmcnt wait auto-inserted)
        *(uint4*)&Ks[buf][rr][dc]     = ka0;
        *(uint4*)&Ks[buf][rr][dc + 8] = ka1;
        *(uint4*)&Vt[buf][rr][dc]     = va0;
        *(uint4*)&Vt[buf][rr][dc + 8] = va1;
        __syncthreads();                       // barrier 1: tile visible
        if (j < jhi) {                         // prefetch next tile into regs
            const unsigned short* kp = kbase + (size_t)(j + 1) * 64 * D_DIM;
            const unsigned short* vp = vbase + (size_t)(j + 1) * 64;
            ka0 = *(const uint4*)kp;  ka1 = *(const uint4*)(kp + 8);
            va0 = *(const uint4*)vp;  va1 = *(const uint4*)(vp + 8);
        }

        // wave-private P tile region in the STALE buffer half (32 rows/wave)
        unsigned short (*stale)[72] = (w < 2)
            ? (unsigned short (*)[72])&Ks[buf ^ 1][w * 32]
            : (unsigned short (*)[72])&Vt[buf ^ 1][(w - 2) * 32];
        const bool bulk = (j < 2 * qb);

        // ---- fused QK^T + softmax: kf read ONCE per nt, used by both groups.
        // S^T layout: key = nt*16 + quad*4 + r, q = l15.
        unsigned pw[2][4][2];                  // [g][nt][word] packed bf16 key-pairs
        float ls0 = 0.f, ls1 = 0.f;
        __builtin_amdgcn_s_setprio(1);
        #pragma unroll
        for (int nt = 0; nt < 4; ++nt) {
            bf16x8 kf0 = *(const bf16x8*)&Ks[buf][nt * 16 + l15][quad * 8];
            bf16x8 kf1 = *(const bf16x8*)&Ks[buf][nt * 16 + l15][32 + quad * 8];
            #pragma unroll
            for (int g = 0; g < 2; ++g) {
                f32x4 z = {0.f,0.f,0.f,0.f};
                z = __builtin_amdgcn_mfma_f32_16x16x32_bf16(kf0, qf[g][0], z, 0, 0, 0);
                z = __builtin_amdgcn_mfma_f32_16x16x32_bf16(kf1, qf[g][1], z, 0, 0, 0);
                float pe[4];
                if (bulk) {
                    #pragma unroll
                    for (int r = 0; r < 4; ++r) pe[r] = exp2f(z[r] + C2);
                } else {
                    const int q_g  = qb * 128 + w * 32 + g * 16 + l15;
                    const int key0 = j * 64 + nt * 16 + quad * 4;
                    #pragma unroll
                    for (int r = 0; r < 4; ++r) {
                        float s = z[r] + C2;
                        if (key0 + r > q_g) s = NEG_BIG;
                        pe[r] = exp2f(s);
                    }
                }
                float psum = (pe[0] + pe[1]) + (pe[2] + pe[3]);
                if (g == 0) ls0 += psum; else ls1 += psum;
                pw[g][nt][0] = pack2(pe[0], pe[1]);
                pw[g][nt][1] = pack2(pe[2], pe[3]);
            }
        }
        __builtin_amdgcn_s_setprio(0);
        lsum0 += ls0; lsum1 += ls1;

        // park P (both groups) in the wave-private stale region
        #pragma unroll
        for (int g = 0; g < 2; ++g)
            #pragma unroll
            for (int nt = 0; nt < 4; ++nt) {
                uint2 pk; pk.x = pw[g][nt][0]; pk.y = pw[g][nt][1];
                *(uint2*)&stale[g * 16 + l15][nt * 16 + quad * 4] = pk;
            }

        // P A-fragments (C-layout -> A-layout via the LDS hop)
        bf16x8 pf[2][2];
        #pragma unroll
        for (int g = 0; g < 2; ++g) {
            pf[g][0] = *(const bf16x8*)&stale[g * 16 + l15][quad * 8];
            pf[g][1] = *(const bf16x8*)&stale[g * 16 + l15][32 + quad * 8];
        }

        // ---- fused PV: vf read ONCE per nt, used by both groups.
        __builtin_amdgcn_s_setprio(1);
        #pragma unroll
        for (int nt = 0; nt < 4; ++nt) {
            bf16x8 vf0 = *(const bf16x8*)&Vt[buf][nt * 16 + l15][quad * 8];
            bf16x8 vf1 = *(const bf16x8*)&Vt[buf][nt * 16 + l15][32 + quad * 8];
            oac[0][nt] = __builtin_amdgcn_mfma_f32_16x16x32_bf16(pf[0][0], vf0, oac[0][nt], 0, 0, 0);
            oac[0][nt] = __builtin_amdgcn_mfma_f32_16x16x32_bf16(pf[0][1], vf1, oac[0][nt], 0, 0, 0);
            oac[1][nt] = __builtin_amdgcn_mfma_f32_16x16x32_bf16(pf[1][0], vf0, oac[1][nt], 0, 0, 0);
            oac[1][nt] = __builtin_amdgcn_mfma_f32_16x16x32_bf16(pf[1][1], vf1, oac[1][nt], 0, 0, 0);
        }
        __builtin_amdgcn_s_setprio(0);
        __syncthreads();   // barrier 2: P reads done before next staging hits stale half
    }

    // partials: l per q-row (reduce lane-scalar across quads) + unnormalized O (bf16)
    #pragma unroll
    for (int g = 0; g < 2; ++g) {
        float lr = (g == 0) ? lsum0 : lsum1;
        lr += __shfl_xor(lr, 16);
        lr += __shfl_xor(lr, 32);            // all quads hold l[q = l15]
        if (l < 16)
            Lpart[(size_t)slot * 128 + w * 32 + g * 16 + l15] = lr;
    }
    unsigned short* Op = Opart + (size_t)slot * 8192;
    #pragma unroll
    for (int g = 0; g < 2; ++g)
        #pragma unroll
        for (int nt = 0; nt < 4; ++nt)
            #pragma unroll
            for (int r = 0; r < 4; ++r)
                Op[(size_t)(w * 32 + g * 16 + quad * 4 + r) * 64 + nt * 16 + l15] = f2b(oac[g][nt][r]);
}

// sum <=6 bf16 key-chunk partials, normalize, cast to bf16.
// grid (16 qb, 16 h, 2 col-halves) = 512 blocks = 2/CU.
// Thread = (row 0..127, 16-col granule).
__global__ __launch_bounds__(256)
void attn_combine(const unsigned short* __restrict__ Opart, const float* __restrict__ Lpart,
                  unsigned short* __restrict__ Ob)
{
    const int qb  = blockIdx.x;
    const int h   = blockIdx.y;
    const int zh  = blockIdx.z;
    const int t   = threadIdx.x;
    const int row = t >> 1;
    const int c0  = zh * 32 + (t & 1) * 16;
    const int nchunks = (2 * qb + 7) / 6;          // ceil((2qb+2)/6)
    float acc[16];
    #pragma unroll
    for (int i = 0; i < 16; ++i) acc[i] = 0.f;
    float lsum = 0.f;
    for (int c = 0; c < nchunks; ++c) {
        const size_t slot = (size_t)((qb * 6 + c) * NH + h);
        const unsigned short* Op = Opart + slot * 8192 + (size_t)row * 64 + c0;
        unsigned wds[8];
        *(uint4*)&wds[0] = *(const uint4*)Op;        // cols 0..7  (8 bf16)
        *(uint4*)&wds[4] = *(const uint4*)(Op + 8);  // cols 8..15
        #pragma unroll
        for (int i2 = 0; i2 < 8; ++i2) {
            const unsigned wv = wds[i2];
            union { unsigned u; float f; } lo, hi;
            lo.u = wv << 16; hi.u = wv & 0xFFFF0000u;
            acc[2 * i2]     += lo.f;
            acc[2 * i2 + 1] += hi.f;
        }
        lsum += Lpart[slot * 128 + row];
    }
    const float inv = 1.f / lsum;   // > 0: diagonal key always contributes
    unsigned int pk[8];
    #pragma unroll
    for (int i = 0; i < 8; ++i)
        pk[i] = f2b(acc[2 * i] * inv) | ((unsigned)f2b(acc[2 * i + 1] * inv) << 16);
    unsigned short* dst = Ob + (size_t)(qb * 128 + row) * D_DIM + h * 64 + c0;
    *(uint4*)dst       = make_uint4(pk[0], pk[1], pk[2], pk[3]);
    *(uint4*)(dst + 8) = make_uint4(pk[4], pk[5], pk[6], pk[7]);
}

extern "C" void kernel_launch(void* const* d_in, const int* in_sizes, int n_in,
                              void* d_out, int out_size, void* d_ws, size_t ws_size,
                              hipStream_t stream)
{
    const float* x    = (const float*)d_in[0];
    const float* v1   = (const float*)d_in[1];
    const float* Wq   = (const float*)d_in[2];
    const float* Wk   = (const float*)d_in[3];
    const float* Wv   = (const float*)d_in[4];
    const float* Wout = (const float*)d_in[5];
    const float* lam  = (const float*)d_in[6];
    float* out = (float*)d_out;

    const size_t SD = (size_t)S_LEN * D_DIM;
    const size_t DD = (size_t)D_DIM * D_DIM;
    // d_ws layout (256 MB): Qb 0-4M | Kb 4-8M | Vtg 8-12M | Opart(bf16) 12-36M |
    //                       Lpart 37-37.75M | xb 40-44M | Woutb 44-46M
    unsigned short* Qb  = (unsigned short*)d_ws;         // internal bf16, 4 MB
    unsigned short* Kb  = Qb + SD;                       // 4 MB
    unsigned short* Vtg = Kb + SD;                       // V transposed [D_DIM][S_LEN], 4 MB
    unsigned short* Ab  = Qb;                            // alias (attn output after combine)
    unsigned short* Opart = (unsigned short*)((char*)d_ws + (12u << 20));  // 1536 slots * 16 KB
    float* Lpart          = (float*)((char*)d_ws + (37u << 20));           // 768 KB
    unsigned short* xb    = (unsigned short*)((char*)d_ws + (40u << 20));  // 4 MB
    unsigned short* Woutb = (unsigned short*)((char*)d_ws + (44u << 20));  // 2 MB

    // bf16 weight scratch in d_out's y slot (first 6 MB of the 8 MB y region;
    // consumed by the QKV GEMM, then y is overwritten by the out-projection).
    // v1 slot (out+SD) is written directly by to_bf16's v1 branch.
    unsigned short* Wqb   = (unsigned short*)d_out;            // 2 MB
    unsigned short* Wkb   = Wqb + DD;                          // 2 MB
    unsigned short* Wvb   = Wkb + DD;                          // 2 MB

    // flat conversion/copy pass: 4096 blocks exact, no dead blocks
    to_bf16<<<dim3(4096), 256, 0, stream>>>(
        x, Wq, Wk, Wv, Wout, v1, xb, Wqb, Wkb, Wvb, Woutb, out + SD);

    // Q/K/V projections, 64x128 tiles, K_STEP=64: 768 blocks = 3/CU balanced.
    gemm64<<<dim3(D_DIM / 128, S_LEN / 64, 3), 256, 0, stream>>>(
        xb, Wqb, Wkb, Wvb, Qb, Kb, Vtg, v1, lam,
        EPI_NORMROPE_Q | (EPI_NORMROPE << 8) | (EPI_VMIX_T << 16));

    // key-split flash attention (QBLK=128, CHUNK=6, 816 blocks all-resident)
    attn_mfma<<<dim3(51, NH), 256, 0, stream>>>(Qb, Kb, Vtg, Opart, Lpart);
    attn_combine<<<dim3(S_LEN / 128, NH, 2), 256, 0, stream>>>(Opart, Lpart, Ab);

    // output projection: 64x64 tiles, K_STEP=64, 512 blocks = 2/CU
    gemm_out<<<dim3(D_DIM / 64, S_LEN / 64), 256, 0, stream>>>(Ab, Woutb, out);
}

// Round 12
// 158.695 us; speedup vs baseline: 1.1434x; 1.0159x over previous
//
#include <hip/hip_runtime.h>
#include <hip/hip_bf16.h>

#define S_LEN 2048
#define D_DIM 1024
#define NH    16
#define NEG_BIG (-1.0e30f)

// epilogue modes
#define EPI_NORMROPE   1   // RMSNorm + RoPE, store bf16 row-major (K)
#define EPI_VMIX_T     2   // v-mix with v1, store bf16 TRANSPOSED (V -> Vt_g[d][s])
#define EPI_F32        3   // plain f32 row-major store
#define EPI_NORMROPE_Q 4   // like NORMROPE but pre-scaled by 0.125*log2e (Q)

typedef __attribute__((ext_vector_type(8))) short bf16x8;
typedef __attribute__((ext_vector_type(4))) float f32x4;
typedef const __attribute__((address_space(1))) unsigned char gu8_t;
typedef __attribute__((address_space(3))) unsigned char lu8_t;

__device__ __forceinline__ float bf2f(unsigned short h) {
    union { unsigned int u; float f; } v; v.u = ((unsigned int)h) << 16; return v.f;
}
__device__ __forceinline__ unsigned short f2b(float f) {   // RNE f32->bf16 raw bits
    union { float f; unsigned int u; } v; v.f = f;
    unsigned int u = v.u;
    return (unsigned short)((u + 0x7FFFu + ((u >> 16) & 1u)) >> 16);
}
__device__ __forceinline__ unsigned int pack2(float a, float b) { // trunc, p>=0
    union { float f; unsigned int u; } x, y; x.f = a; y.f = b;
    return (x.u >> 16) | (y.u & 0xFFFF0000u);
}

// Flat one-shot conversion/copy pass: x,Wq,Wk,Wv,Wout f32->bf16 + v1 f32 copy.
// 1,048,576 8-elem units -> 4096 blocks EXACT. Region boundaries are multiples
// of 512 blocks, so every branch below is block-uniform.
__global__ __launch_bounds__(256)
void to_bf16(const float* __restrict__ x,  const float* __restrict__ wq,
             const float* __restrict__ wk, const float* __restrict__ wv,
             const float* __restrict__ wo, const float* __restrict__ v1,
             unsigned short* __restrict__ xb,  unsigned short* __restrict__ wqb,
             unsigned short* __restrict__ wkb, unsigned short* __restrict__ wvb,
             unsigned short* __restrict__ wob, float* __restrict__ v1dst)
{
    const unsigned u = blockIdx.x * 256 + threadIdx.x;   // 8-elem unit index
    if (u >= 786432u) {                                  // v1 f32 passthrough
        const size_t i = (size_t)(u - 786432u) * 8;
        float4 lo = *(const float4*)(v1 + i), hi = *(const float4*)(v1 + i + 4);
        *(float4*)(v1dst + i) = lo; *(float4*)(v1dst + i + 4) = hi;
        return;
    }
    const float* s; unsigned short* d; unsigned base;
    if (u < 262144u)      { s = x;  d = xb;  base = 0; }
    else if (u < 393216u) { s = wq; d = wqb; base = 262144u; }
    else if (u < 524288u) { s = wk; d = wkb; base = 393216u; }
    else if (u < 655360u) { s = wv; d = wvb; base = 524288u; }
    else                  { s = wo; d = wob; base = 655360u; }
    const size_t i = (size_t)(u - base) * 8;
    float4 lo = *(const float4*)(s + i), hi = *(const float4*)(s + i + 4);
    uint4 p;
    p.x = f2b(lo.x) | ((unsigned)f2b(lo.y) << 16);
    p.y = f2b(lo.z) | ((unsigned)f2b(lo.w) << 16);
    p.z = f2b(hi.x) | ((unsigned)f2b(hi.y) << 16);
    p.w = f2b(hi.z) | ((unsigned)f2b(hi.w) << 16);
    *(uint4*)(d + i) = p;
}

// 64x128-tile GEMM for the QKV projections: C = A[M,K] * B[N,K]^T.
// Grid (8, 32, 3) = 768 blocks = 3/CU balanced. K_STEP=64 as two 32-col panels
// per barrier ([2][rows][32] LDS keeps the bank-friendly 64 B row stride).
__global__ __launch_bounds__(256, 3)
void gemm64(const unsigned short* __restrict__ A,
            const unsigned short* __restrict__ B0, const unsigned short* __restrict__ B1,
            const unsigned short* __restrict__ B2,
            void* __restrict__ C0, void* __restrict__ C1, void* __restrict__ C2,
            const float* __restrict__ vmix, const float* __restrict__ lam,
            int epiPack)
{
    const int which = blockIdx.z;
    const unsigned short* Bp = (which == 0) ? B0 : ((which == 1) ? B1 : B2);
    void* C = (which == 0) ? C0 : ((which == 1) ? C1 : C2);
    const int epi = (epiPack >> (8 * which)) & 0xff;
    const int tn = blockIdx.x * 128;
    const int tm = blockIdx.y * 64;

    __shared__ unsigned short Asl[2][64 * 32];    // [panel][row*32+col]
    __shared__ unsigned short Bsl[2][128 * 32];

    const int t    = threadIdx.x;
    const int lane = t & 63;
    const int wave = t >> 6;
    const int wm   = (wave >> 1) * 32;
    const int wn   = (wave & 1) * 64;
    const int lrow = lane & 15;
    const int quad = lane >> 4;
    const int srow = t >> 2;          // staging row 0..63
    const int scol = (t & 3) * 8;     // staging col group

    f32x4 acc[2][4];
    #pragma unroll
    for (int i = 0; i < 2; ++i)
        #pragma unroll
        for (int j = 0; j < 4; ++j) {
            f32x4 z = {0.f, 0.f, 0.f, 0.f};
            acc[i][j] = z;
        }

    for (int k0 = 0; k0 < D_DIM; k0 += 64) {
        #pragma unroll
        for (int ks = 0; ks < 2; ++ks) {
            const int kc = k0 + ks * 32 + scol;
            __builtin_amdgcn_global_load_lds(
                (gu8_t*)(A + (size_t)(tm + srow) * D_DIM + kc),
                (lu8_t*)&Asl[ks][t * 8], 16, 0, 0);
            __builtin_amdgcn_global_load_lds(
                (gu8_t*)(Bp + (size_t)(tn + srow) * D_DIM + kc),
                (lu8_t*)&Bsl[ks][t * 8], 16, 0, 0);
            __builtin_amdgcn_global_load_lds(
                (gu8_t*)(Bp + (size_t)(tn + 64 + srow) * D_DIM + kc),
                (lu8_t*)&Bsl[ks][2048 + t * 8], 16, 0, 0);
        }
        __syncthreads();
        #pragma unroll
        for (int ks = 0; ks < 2; ++ks) {
            bf16x8 af[2], bfr[4];
            #pragma unroll
            for (int i = 0; i < 2; ++i)
                af[i] = *(const bf16x8*)(&Asl[ks][(wm + i * 16 + lrow) * 32 + quad * 8]);
            #pragma unroll
            for (int j = 0; j < 4; ++j)
                bfr[j] = *(const bf16x8*)(&Bsl[ks][(wn + j * 16 + lrow) * 32 + quad * 8]);
            #pragma unroll
            for (int i = 0; i < 2; ++i)
                #pragma unroll
                for (int j = 0; j < 4; ++j)
                    acc[i][j] = __builtin_amdgcn_mfma_f32_16x16x32_bf16(af[i], bfr[j], acc[i][j], 0, 0, 0);
        }
        __syncthreads();
    }

    if (epi == EPI_NORMROPE || epi == EPI_NORMROPE_Q) {
        // wave covers cols [tn+wn, tn+wn+64) = one head. RoPE pair = (v0,v2),(v1,v3).
        const float post = (epi == EPI_NORMROPE_Q) ? 0.18033688011112042f : 1.0f;
        #pragma unroll
        for (int i = 0; i < 2; ++i) {
            #pragma unroll
            for (int r = 0; r < 4; ++r) {
                int row = tm + wm + i * 16 + quad * 4 + r;   // seq position (m89/m91 C-map)
                float v0 = acc[i][0][r], v1 = acc[i][1][r];
                float v2 = acc[i][2][r], v3 = acc[i][3][r];
                float ss = v0 * v0 + v1 * v1 + v2 * v2 + v3 * v3;
                ss += __shfl_xor(ss, 1); ss += __shfl_xor(ss, 2);
                ss += __shfl_xor(ss, 4); ss += __shfl_xor(ss, 8);   // 16-lane group = full head
                float rms = rsqrtf(ss * (1.f / 64.f) + 1.1920929e-7f) * post;
                v0 *= rms; v1 *= rms; v2 *= rms; v3 *= rms;
                float fs = (float)row;
                float a0 = fs * exp2f(-0.41524101186092030f * (float)lrow);        // 10000^(-2i/64)
                float a1 = fs * exp2f(-0.41524101186092030f * (float)(16 + lrow));
                float s0, c0, s1, c1;
                __sincosf(a0, &s0, &c0);
                __sincosf(a1, &s1, &c1);
                unsigned short* Cb = (unsigned short*)C;
                size_t base = (size_t)row * D_DIM + tn + wn + lrow;
                Cb[base]      = f2b(v0 * c0 + v2 * s0);
                Cb[base + 16] = f2b(v1 * c1 + v3 * s1);
                Cb[base + 32] = f2b(-v0 * s0 + v2 * c0);
                Cb[base + 48] = f2b(-v1 * s1 + v3 * c1);
            }
        }
    } else if (epi == EPI_VMIX_T) {
        float lamf = *lam;
        #pragma unroll
        for (int i = 0; i < 2; ++i) {
            int cm0 = tm + wm + i * 16 + quad * 4;
            #pragma unroll
            for (int j = 0; j < 4; ++j) {
                int cn = tn + wn + j * 16 + lrow;
                ushort4 pk;
                float vals[4];
                #pragma unroll
                for (int r = 0; r < 4; ++r) {
                    size_t idx = (size_t)(cm0 + r) * D_DIM + cn;
                    vals[r] = (1.f - lamf) * acc[i][j][r] + lamf * vmix[idx];
                }
                pk.x = f2b(vals[0]); pk.y = f2b(vals[1]);
                pk.z = f2b(vals[2]); pk.w = f2b(vals[3]);
                *(ushort4*)((unsigned short*)C + (size_t)cn * S_LEN + cm0) = pk;
            }
        }
    } else {   // EPI_F32
        #pragma unroll
        for (int i = 0; i < 2; ++i) {
            int cm0 = tm + wm + i * 16 + quad * 4;
            #pragma unroll
            for (int j = 0; j < 4; ++j) {
                int cn = tn + wn + j * 16 + lrow;
                #pragma unroll
                for (int r = 0; r < 4; ++r)
                    ((float*)C)[(size_t)(cm0 + r) * D_DIM + cn] = acc[i][j][r];
            }
        }
    }
}

// Out-projection GEMM, 64x64 tiles, K_STEP=64 (two 32-col panels/barrier):
// grid (16, 32) = 512 blocks = 2/CU. 4 waves 2x2, wave = 32x32, acc[2][2].
__global__ __launch_bounds__(256, 4)
void gemm_out(const unsigned short* __restrict__ A,
              const unsigned short* __restrict__ B,
              float* __restrict__ C)
{
    const int tn = blockIdx.x * 64;
    const int tm = blockIdx.y * 64;

    __shared__ unsigned short Asl[2][64 * 32];
    __shared__ unsigned short Bsl[2][64 * 32];

    const int t    = threadIdx.x;
    const int lane = t & 63;
    const int wave = t >> 6;
    const int wm   = (wave >> 1) * 32;
    const int wn   = (wave & 1) * 32;
    const int lrow = lane & 15;
    const int quad = lane >> 4;
    const int srow = t >> 2;
    const int scol = (t & 3) * 8;

    f32x4 acc[2][2];
    #pragma unroll
    for (int i = 0; i < 2; ++i)
        #pragma unroll
        for (int j = 0; j < 2; ++j) {
            f32x4 z = {0.f, 0.f, 0.f, 0.f};
            acc[i][j] = z;
        }

    for (int k0 = 0; k0 < D_DIM; k0 += 64) {
        #pragma unroll
        for (int ks = 0; ks < 2; ++ks) {
            const int kc = k0 + ks * 32 + scol;
            __builtin_amdgcn_global_load_lds(
                (gu8_t*)(A + (size_t)(tm + srow) * D_DIM + kc),
                (lu8_t*)&Asl[ks][t * 8], 16, 0, 0);
            __builtin_amdgcn_global_load_lds(
                (gu8_t*)(B + (size_t)(tn + srow) * D_DIM + kc),
                (lu8_t*)&Bsl[ks][t * 8], 16, 0, 0);
        }
        __syncthreads();
        #pragma unroll
        for (int ks = 0; ks < 2; ++ks) {
            bf16x8 af[2], bfr[2];
            #pragma unroll
            for (int i = 0; i < 2; ++i)
                af[i] = *(const bf16x8*)(&Asl[ks][(wm + i * 16 + lrow) * 32 + quad * 8]);
            #pragma unroll
            for (int j = 0; j < 2; ++j)
                bfr[j] = *(const bf16x8*)(&Bsl[ks][(wn + j * 16 + lrow) * 32 + quad * 8]);
            #pragma unroll
            for (int i = 0; i < 2; ++i)
                #pragma unroll
                for (int j = 0; j < 2; ++j)
                    acc[i][j] = __builtin_amdgcn_mfma_f32_16x16x32_bf16(af[i], bfr[j], acc[i][j], 0, 0, 0);
        }
        __syncthreads();
    }

    #pragma unroll
    for (int i = 0; i < 2; ++i) {
        int cm0 = tm + wm + i * 16 + quad * 4;
        #pragma unroll
        for (int j = 0; j < 2; ++j) {
            int cn = tn + wn + j * 16 + lrow;
            #pragma unroll
            for (int r = 0; r < 4; ++r)
                C[(size_t)(cm0 + r) * D_DIM + cn] = acc[i][j][r];
        }
    }
}

// MFMA flash attention, QBLK=128, key-split with CHUNK=5 key-tiles (was 6):
// 976 blocks <= 1024 resident slots (4/CU) -> all blocks co-resident, so the
// dispatch duration = the longest block = 5 iterations (was 6): critical path
// -17%. (Chunk-4 would need 1152 blocks > 1024 -> queuing; 5 is the resident
// optimum of this design.) Partials bf16. Swapped QK^T, fused nt-loops, P
// parked in the stale double-buffer half (all validated rounds 8-11).
__global__ __launch_bounds__(256, 4)
void attn_mfma(const unsigned short* Qb,
               const unsigned short* __restrict__ Kb,
               const unsigned short* __restrict__ Vtg,
               unsigned short* __restrict__ Opart, float* __restrict__ Lpart)
{
    // map bx -> (qb, c): qb = 128-row q-block (0..15), nchunks = ceil((2qb+2)/5),
    // big blocks dispatch first. Total bx = 61.
    const int bx = blockIdx.x;
    int qb = 0, c = 0;
    {
        int accum = 0;
        #pragma unroll
        for (int q = 15; q >= 0; --q) {
            int n = (2 * q + 6) / 5;                // ceil((2q+2)/5)
            if (bx >= accum && bx < accum + n) { qb = q; c = bx - accum; }
            accum += n;
        }
    }
    const int jmax = 2 * qb + 1;                    // key tiles 0..jmax
    const int jlo  = c * 5;
    const int jhi  = min(jlo + 4, jmax);
    const int h  = blockIdx.y;
    const int t  = threadIdx.x;
    const int w  = t >> 6;
    const int l  = t & 63;
    const int l15  = l & 15;
    const int quad = l >> 4;
    const int hco  = h * 64;
    const int slot = (qb * 7 + c) * NH + h;         // <= 1791

    __shared__ unsigned short Ks[2][64][72];    // double-buffered; stale half = P (waves 0-1)
    __shared__ unsigned short Vt[2][64][72];    // Vt[buf][d][key]; stale half = P (waves 2-3)

    // Q fragments: rows qb*128 + w*32 + g*16 + l15
    bf16x8 qf[2][2];
    #pragma unroll
    for (int g = 0; g < 2; ++g) {
        const unsigned short* qrow =
            Qb + (size_t)(qb * 128 + w * 32 + g * 16 + l15) * D_DIM + hco;
        qf[g][0] = *(const bf16x8*)(qrow + quad * 8);
        qf[g][1] = *(const bf16x8*)(qrow + 32 + quad * 8);
    }

    f32x4 oac[2][4];
    #pragma unroll
    for (int g = 0; g < 2; ++g)
        #pragma unroll
        for (int nt = 0; nt < 4; ++nt) { f32x4 z = {0.f,0.f,0.f,0.f}; oac[g][nt] = z; }
    float lsum0 = 0.f, lsum1 = 0.f;      // per-lane: keys {nt*16+quad*4+r}, q = l15

    const int rr = t >> 2;          // staging row (K: key row; Vt: d row)
    const int dc = (t & 3) * 16;    // 16-col group

    const unsigned short* kbase = Kb  + (size_t)rr * D_DIM + hco + dc;
    const unsigned short* vbase = Vtg + (size_t)(hco + rr) * S_LEN + dc;

    uint4 ka0, ka1, va0, va1;
    {
        const unsigned short* kp = kbase + (size_t)jlo * 64 * D_DIM;
        const unsigned short* vp = vbase + (size_t)jlo * 64;
        ka0 = *(const uint4*)kp;  ka1 = *(const uint4*)(kp + 8);
        va0 = *(const uint4*)vp;  va1 = *(const uint4*)(vp + 8);
    }

    const float C2 = -11.541560327111707f;              // -8 * log2(e)

    for (int j = jlo; j <= jhi; ++j) {
        const int buf = (j - jlo) & 1;
        // write this tile's LDS from prefetched regs (vmcnt wait auto-inserted)
        *(uint4*)&Ks[buf][rr][dc]     = ka0;
        *(uint4*)&Ks[buf][rr][dc + 8] = ka1;
        *(uint4*)&Vt[buf][rr][dc]     = va0;
        *(uint4*)&Vt[buf][rr][dc + 8] = va1;
        __syncthreads();                       // barrier 1: tile visible
        if (j < jhi) {                         // prefetch next tile into regs
            const unsigned short* kp = kbase + (size_t)(j + 1) * 64 * D_DIM;
            const unsigned short* vp = vbase + (size_t)(j + 1) * 64;
            ka0 = *(const uint4*)kp;  ka1 = *(const uint4*)(kp + 8);
            va0 = *(const uint4*)vp;  va1 = *(const uint4*)(vp + 8);
        }

        // wave-private P tile region in the STALE buffer half (32 rows/wave)
        unsigned short (*stale)[72] = (w < 2)
            ? (unsigned short (*)[72])&Ks[buf ^ 1][w * 32]
            : (unsigned short (*)[72])&Vt[buf ^ 1][(w - 2) * 32];
        const bool bulk = (j < 2 * qb);

        // ---- fused QK^T + softmax: kf read ONCE per nt, used by both groups.
        // S^T layout: key = nt*16 + quad*4 + r, q = l15.
        unsigned pw[2][4][2];                  // [g][nt][word] packed bf16 key-pairs
        float ls0 = 0.f, ls1 = 0.f;
        __builtin_amdgcn_s_setprio(1);
        #pragma unroll
        for (int nt = 0; nt < 4; ++nt) {
            bf16x8 kf0 = *(const bf16x8*)&Ks[buf][nt * 16 + l15][quad * 8];
            bf16x8 kf1 = *(const bf16x8*)&Ks[buf][nt * 16 + l15][32 + quad * 8];
            #pragma unroll
            for (int g = 0; g < 2; ++g) {
                f32x4 z = {0.f,0.f,0.f,0.f};
                z = __builtin_amdgcn_mfma_f32_16x16x32_bf16(kf0, qf[g][0], z, 0, 0, 0);
                z = __builtin_amdgcn_mfma_f32_16x16x32_bf16(kf1, qf[g][1], z, 0, 0, 0);
                float pe[4];
                if (bulk) {
                    #pragma unroll
                    for (int r = 0; r < 4; ++r) pe[r] = exp2f(z[r] + C2);
                } else {
                    const int q_g  = qb * 128 + w * 32 + g * 16 + l15;
                    const int key0 = j * 64 + nt * 16 + quad * 4;
                    #pragma unroll
                    for (int r = 0; r < 4; ++r) {
                        float s = z[r] + C2;
                        if (key0 + r > q_g) s = NEG_BIG;
                        pe[r] = exp2f(s);
                    }
                }
                float psum = (pe[0] + pe[1]) + (pe[2] + pe[3]);
                if (g == 0) ls0 += psum; else ls1 += psum;
                pw[g][nt][0] = pack2(pe[0], pe[1]);
                pw[g][nt][1] = pack2(pe[2], pe[3]);
            }
        }
        __builtin_amdgcn_s_setprio(0);
        lsum0 += ls0; lsum1 += ls1;

        // park P (both groups) in the wave-private stale region
        #pragma unroll
        for (int g = 0; g < 2; ++g)
            #pragma unroll
            for (int nt = 0; nt < 4; ++nt) {
                uint2 pk; pk.x = pw[g][nt][0]; pk.y = pw[g][nt][1];
                *(uint2*)&stale[g * 16 + l15][nt * 16 + quad * 4] = pk;
            }

        // P A-fragments (C-layout -> A-layout via the LDS hop)
        bf16x8 pf[2][2];
        #pragma unroll
        for (int g = 0; g < 2; ++g) {
            pf[g][0] = *(const bf16x8*)&stale[g * 16 + l15][quad * 8];
            pf[g][1] = *(const bf16x8*)&stale[g * 16 + l15][32 + quad * 8];
        }

        // ---- fused PV: vf read ONCE per nt, used by both groups.
        __builtin_amdgcn_s_setprio(1);
        #pragma unroll
        for (int nt = 0; nt < 4; ++nt) {
            bf16x8 vf0 = *(const bf16x8*)&Vt[buf][nt * 16 + l15][quad * 8];
            bf16x8 vf1 = *(const bf16x8*)&Vt[buf][nt * 16 + l15][32 + quad * 8];
            oac[0][nt] = __builtin_amdgcn_mfma_f32_16x16x32_bf16(pf[0][0], vf0, oac[0][nt], 0, 0, 0);
            oac[0][nt] = __builtin_amdgcn_mfma_f32_16x16x32_bf16(pf[0][1], vf1, oac[0][nt], 0, 0, 0);
            oac[1][nt] = __builtin_amdgcn_mfma_f32_16x16x32_bf16(pf[1][0], vf0, oac[1][nt], 0, 0, 0);
            oac[1][nt] = __builtin_amdgcn_mfma_f32_16x16x32_bf16(pf[1][1], vf1, oac[1][nt], 0, 0, 0);
        }
        __builtin_amdgcn_s_setprio(0);
        __syncthreads();   // barrier 2: P reads done before next staging hits stale half
    }

    // partials: l per q-row (reduce lane-scalar across quads) + unnormalized O (bf16)
    #pragma unroll
    for (int g = 0; g < 2; ++g) {
        float lr = (g == 0) ? lsum0 : lsum1;
        lr += __shfl_xor(lr, 16);
        lr += __shfl_xor(lr, 32);            // all quads hold l[q = l15]
        if (l < 16)
            Lpart[(size_t)slot * 128 + w * 32 + g * 16 + l15] = lr;
    }
    unsigned short* Op = Opart + (size_t)slot * 8192;
    #pragma unroll
    for (int g = 0; g < 2; ++g)
        #pragma unroll
        for (int nt = 0; nt < 4; ++nt)
            #pragma unroll
            for (int r = 0; r < 4; ++r)
                Op[(size_t)(w * 32 + g * 16 + quad * 4 + r) * 64 + nt * 16 + l15] = f2b(oac[g][nt][r]);
}

// sum <=7 bf16 key-chunk partials, normalize, cast to bf16.
// grid (16 qb, 16 h, 4 col-quarters) = 1024 blocks = 4/CU (was 2/CU).
// Thread = (row 0..127, 8-col granule): exactly one uint4 load per chunk.
__global__ __launch_bounds__(256)
void attn_combine(const unsigned short* __restrict__ Opart, const float* __restrict__ Lpart,
                  unsigned short* __restrict__ Ob)
{
    const int qb  = blockIdx.x;
    const int h   = blockIdx.y;
    const int zh  = blockIdx.z;
    const int t   = threadIdx.x;
    const int row = t >> 1;
    const int c0  = zh * 16 + (t & 1) * 8;
    const int nchunks = (2 * qb + 6) / 5;          // ceil((2qb+2)/5)
    float acc[8];
    #pragma unroll
    for (int i = 0; i < 8; ++i) acc[i] = 0.f;
    float lsum = 0.f;
    for (int c = 0; c < nchunks; ++c) {
        const size_t slot = (size_t)((qb * 7 + c) * NH + h);
        const unsigned short* Op = Opart + slot * 8192 + (size_t)row * 64 + c0;
        uint4 wv4 = *(const uint4*)Op;               // 8 bf16
        const unsigned wds[4] = { wv4.x, wv4.y, wv4.z, wv4.w };
        #pragma unroll
        for (int i2 = 0; i2 < 4; ++i2) {
            const unsigned wv = wds[i2];
            union { unsigned u; float f; } lo, hi;
            lo.u = wv << 16; hi.u = wv & 0xFFFF0000u;
            acc[2 * i2]     += lo.f;
            acc[2 * i2 + 1] += hi.f;
        }
        lsum += Lpart[slot * 128 + row];
    }
    const float inv = 1.f / lsum;   // > 0: diagonal key always contributes
    unsigned int pk[4];
    #pragma unroll
    for (int i = 0; i < 4; ++i)
        pk[i] = f2b(acc[2 * i] * inv) | ((unsigned)f2b(acc[2 * i + 1] * inv) << 16);
    unsigned short* dst = Ob + (size_t)(qb * 128 + row) * D_DIM + h * 64 + c0;
    *(uint4*)dst = make_uint4(pk[0], pk[1], pk[2], pk[3]);
}

extern "C" void kernel_launch(void* const* d_in, const int* in_sizes, int n_in,
                              void* d_out, int out_size, void* d_ws, size_t ws_size,
                              hipStream_t stream)
{
    const float* x    = (const float*)d_in[0];
    const float* v1   = (const float*)d_in[1];
    const float* Wq   = (const float*)d_in[2];
    const float* Wk   = (const float*)d_in[3];
    const float* Wv   = (const float*)d_in[4];
    const float* Wout = (const float*)d_in[5];
    const float* lam  = (const float*)d_in[6];
    float* out = (float*)d_out;

    const size_t SD = (size_t)S_LEN * D_DIM;
    const size_t DD = (size_t)D_DIM * D_DIM;
    // d_ws layout (256 MB): Qb 0-4M | Kb 4-8M | Vtg 8-12M | Opart(bf16) 12-40M |
    //                       Lpart 40-41M | xb 42-46M | Woutb 46-48M
    unsigned short* Qb  = (unsigned short*)d_ws;         // internal bf16, 4 MB
    unsigned short* Kb  = Qb + SD;                       // 4 MB
    unsigned short* Vtg = Kb + SD;                       // V transposed [D_DIM][S_LEN], 4 MB
    unsigned short* Ab  = Qb;                            // alias (attn output after combine)
    unsigned short* Opart = (unsigned short*)((char*)d_ws + (12u << 20));  // 1792 slots * 16 KB = 28 MB
    float* Lpart          = (float*)((char*)d_ws + (40u << 20));           // 896 KB
    unsigned short* xb    = (unsigned short*)((char*)d_ws + (42u << 20));  // 4 MB
    unsigned short* Woutb = (unsigned short*)((char*)d_ws + (46u << 20));  // 2 MB

    // bf16 weight scratch in d_out's y slot (first 6 MB of the 8 MB y region;
    // consumed by the QKV GEMM, then y is overwritten by the out-projection).
    // v1 slot (out+SD) is written directly by to_bf16's v1 branch.
    unsigned short* Wqb   = (unsigned short*)d_out;            // 2 MB
    unsigned short* Wkb   = Wqb + DD;                          // 2 MB
    unsigned short* Wvb   = Wkb + DD;                          // 2 MB

    // flat conversion/copy pass: 4096 blocks exact, no dead blocks
    to_bf16<<<dim3(4096), 256, 0, stream>>>(
        x, Wq, Wk, Wv, Wout, v1, xb, Wqb, Wkb, Wvb, Woutb, out + SD);

    // Q/K/V projections, 64x128 tiles, K_STEP=64: 768 blocks = 3/CU balanced.
    gemm64<<<dim3(D_DIM / 128, S_LEN / 64, 3), 256, 0, stream>>>(
        xb, Wqb, Wkb, Wvb, Qb, Kb, Vtg, v1, lam,
        EPI_NORMROPE_Q | (EPI_NORMROPE << 8) | (EPI_VMIX_T << 16));

    // key-split flash attention (QBLK=128, CHUNK=5, 976 blocks all-resident)
    attn_mfma<<<dim3(61, NH), 256, 0, stream>>>(Qb, Kb, Vtg, Opart, Lpart);
    attn_combine<<<dim3(S_LEN / 128, NH, 4), 256, 0, stream>>>(Opart, Lpart, Ab);

    // output projection: 64x64 tiles, K_STEP=64, 512 blocks = 2/CU
    gemm_out<<<dim3(D_DIM / 64, S_LEN / 64), 256, 0, stream>>>(Ab, Woutb, out);
}